// Round 4
// baseline (3520.923 us; speedup 1.0000x reference)
//
#include <hip/hip_runtime.h>
#include <hip/hip_bf16.h>

// ---------------- problem sizes ----------------
#define NB   4096
#define NEXP 16
#define DDIM 256
#define HDIM 1024
#define NCLS 1000

// ---------------- workspace layout (bytes) ----------------
// B  : conv2 out f32 [4096][64][8][8]   67,108,864 B  (offset 0)
//      (dead after conv3 -> P0/P1 FC split-K partials alias it)
// C  : conv3 out f32 [4096][2048]       33,554,432 B
#define OFF_B    ((size_t)0)
#define OFF_P0   ((size_t)0)           // f32 [4096][256] FC partial (K half 0)
#define OFF_P1   ((size_t)4194304)     // f32 [4096][256] FC partial (K half 1)
#define OFF_C    ((size_t)67108864)
#define OFF_FEAT ((size_t)100663296)   // f32 [4096][256]; ALSO wT3 (288 KB) before k_gate
#define OFF_MOE  ((size_t)104857600)   // f32 [4096][256]
#define OFF_CNT  ((size_t)109051904)   // int [16]
#define OFF_GSUM ((size_t)109051968)   // f32 [16]
#define OFF_LROW ((size_t)109052032)   // int [16][4096]
#define OFF_LG   ((size_t)109314176)   // f32 [16][4096]
// total ~109.5 MB (same as round 3)

// ================= fused conv1+conv2 per image =================
__global__ __launch_bounds__(512) void k_conv12(const float* __restrict__ x,
    const float* __restrict__ w1, const float* __restrict__ b1,
    const float* __restrict__ w2, const float* __restrict__ b2,
    float* __restrict__ outB) {
  __shared__ float xs[3][34][36];     // padded input image
  __shared__ float as[32][18][20];    // padded conv1 pooled output
  __shared__ float ws2[64*288];       // conv2 weights (72 KB)
  __shared__ float ws1[864];
  __shared__ float bs1[32];
  __shared__ float bs2[64];
  const int t = threadIdx.x;
  const int img = blockIdx.x;
  for (int i = t; i < 3*34*36; i += 512) ((float*)xs)[i] = 0.f;
  for (int i = t; i < 32*18*20; i += 512) ((float*)as)[i] = 0.f;
  __syncthreads();
  for (int i = t; i < 3072; i += 512) {
    int ic = i >> 10, rem = i & 1023, y = rem >> 5, xx = rem & 31;
    xs[ic][y+1][xx+1] = x[(size_t)img*3072 + i];
  }
  for (int i = t; i < 864; i += 512) ws1[i] = w1[i];
  for (int i = t; i < 64*288; i += 512) ws2[i] = w2[i];
  if (t < 32) bs1[t] = b1[t];
  else if (t >= 64 && t < 128) bs2[t-64] = b2[t-64];
  __syncthreads();
  // ---- conv1 + pool + relu -> as interior ----
  {
    const int p = t & 255, grp = t >> 8;
    const int px = p & 15, py = p >> 4;
    float win[3][4][4];
    #pragma unroll
    for (int ic = 0; ic < 3; ++ic)
      #pragma unroll
      for (int r = 0; r < 4; ++r) {
        float2 a  = *(const float2*)&xs[ic][2*py+r][2*px];
        float2 c2 = *(const float2*)&xs[ic][2*py+r][2*px+2];
        win[ic][r][0]=a.x; win[ic][r][1]=a.y; win[ic][r][2]=c2.x; win[ic][r][3]=c2.y;
      }
    for (int occ = grp*16; occ < grp*16 + 16; occ += 8) {
      float acc[8][4];
      #pragma unroll
      for (int j = 0; j < 8; ++j) { float bb = bs1[occ+j]; acc[j][0]=bb;acc[j][1]=bb;acc[j][2]=bb;acc[j][3]=bb; }
      #pragma unroll
      for (int ic = 0; ic < 3; ++ic) {
        #pragma unroll
        for (int j = 0; j < 8; ++j) {
          const float* wp = &ws1[(occ+j)*27 + ic*9];
          float wv[9];
          #pragma unroll
          for (int q = 0; q < 9; ++q) wv[q] = wp[q];
          #pragma unroll
          for (int ry = 0; ry < 2; ++ry)
            #pragma unroll
            for (int rx = 0; rx < 2; ++rx) {
              float s = acc[j][ry*2+rx];
              #pragma unroll
              for (int ky = 0; ky < 3; ++ky)
                #pragma unroll
                for (int kx = 0; kx < 3; ++kx)
                  s = fmaf(wv[ky*3+kx], win[ic][ry+ky][rx+kx], s);
              acc[j][ry*2+rx] = s;
            }
        }
      }
      #pragma unroll
      for (int j = 0; j < 8; ++j) {
        float m = fmaxf(fmaxf(acc[j][0],acc[j][1]), fmaxf(acc[j][2],acc[j][3]));
        as[occ+j][py+1][px+1] = fmaxf(m, 0.f);
      }
    }
  }
  __syncthreads();
  // ---- conv2 + pool + relu -> global ----
  {
    const int pix = t & 63, ocg = t >> 6;
    const int py = pix >> 3, px = pix & 7;
    float acc[8][4];
    #pragma unroll
    for (int j = 0; j < 8; ++j) { float bb = bs2[j*8+ocg]; acc[j][0]=bb;acc[j][1]=bb;acc[j][2]=bb;acc[j][3]=bb; }
    for (int ic = 0; ic < 32; ++ic) {
      float win[4][4];
      #pragma unroll
      for (int r = 0; r < 4; ++r) {
        float2 a  = *(const float2*)&as[ic][2*py+r][2*px];
        float2 c2 = *(const float2*)&as[ic][2*py+r][2*px+2];
        win[r][0]=a.x; win[r][1]=a.y; win[r][2]=c2.x; win[r][3]=c2.y;
      }
      #pragma unroll
      for (int j = 0; j < 8; ++j) {
        const float* wp = &ws2[(j*8+ocg)*288 + ic*9];
        float wv[9];
        #pragma unroll
        for (int q = 0; q < 9; ++q) wv[q] = wp[q];
        #pragma unroll
        for (int ry = 0; ry < 2; ++ry)
          #pragma unroll
          for (int rx = 0; rx < 2; ++rx) {
            float s = acc[j][ry*2+rx];
            #pragma unroll
            for (int ky = 0; ky < 3; ++ky)
              #pragma unroll
              for (int kx = 0; kx < 3; ++kx)
                s = fmaf(wv[ky*3+kx], win[ry+ky][rx+kx], s);
            acc[j][ry*2+rx] = s;
          }
      }
    }
    const size_t obase = (size_t)img*4096 + (size_t)(py*8 + px);
    #pragma unroll
    for (int j = 0; j < 8; ++j) {
      float m = fmaxf(fmaxf(acc[j][0],acc[j][1]), fmaxf(acc[j][2],acc[j][3]));
      outB[obase + (size_t)(j*8+ocg)*64] = fmaxf(m, 0.f);
    }
  }
}

// ================= weight transpose for conv3: w[oc][ic][k] -> wT[(ic*9+k)*128 + oc]
__global__ __launch_bounds__(256) void k_wt3(const float* __restrict__ w, float* __restrict__ wT) {
  int i = blockIdx.x*256 + threadIdx.x;   // i over 64*9*128
  if (i >= 64*9*128) return;
  int oc = i & 127, rem = i >> 7;         // rem = ic*9 + k
  int k = rem % 9, ic = rem / 9;
  wT[i] = w[(oc*64 + ic)*9 + k];
}

// ================= conv3 v2: f32 [4096,64,8,8] -> conv3x3(128)+pool2+relu -> f32 [4096,2048]
// grid (4096, 2) x 256 thr. Lane = pre-pool pixel (8x8); wave = 16 oc; weights via
// wave-uniform float4 loads from L2-resident wT. LDS = input only (33 KB) -> 4 blocks/CU.
__global__ __launch_bounds__(256) void k_conv3(const float* __restrict__ inB,
    const float* __restrict__ wT, const float* __restrict__ b,
    float* __restrict__ outC) {
  __shared__ float is[64][10][13];   // padded input, 33,280 B
  const int t = threadIdx.x;
  const int img = blockIdx.x, och = blockIdx.y;
  for (int i = t; i < 64*10*13; i += 256) ((float*)is)[i] = 0.f;
  __syncthreads();
  for (int i = t; i < 4096; i += 256) {
    int ic = i >> 6, rem = i & 63, y = rem >> 3, xx = rem & 7;
    is[ic][y+1][xx+1] = inB[(size_t)img*4096 + i];
  }
  __syncthreads();
  const int wv = t >> 6, l = t & 63;
  const int y = l >> 3, x = l & 7;
  const int oc0 = och*64 + wv*16;        // wave-uniform
  float acc[16];
  #pragma unroll
  for (int i = 0; i < 16; ++i) acc[i] = 0.f;
  for (int ic = 0; ic < 64; ++ic) {
    float win[9];
    #pragma unroll
    for (int ky = 0; ky < 3; ++ky)
      #pragma unroll
      for (int kx = 0; kx < 3; ++kx)
        win[ky*3+kx] = is[ic][y+ky][x+kx];
    const float* wp = wT + (size_t)ic*9*128 + oc0;
    #pragma unroll
    for (int k = 0; k < 9; ++k) {
      float4 w0 = *(const float4*)(wp + k*128);
      float4 w1 = *(const float4*)(wp + k*128 + 4);
      float4 w2 = *(const float4*)(wp + k*128 + 8);
      float4 w3 = *(const float4*)(wp + k*128 + 12);
      float wf = win[k];
      acc[0]  = fmaf(wf, w0.x, acc[0]);  acc[1]  = fmaf(wf, w0.y, acc[1]);
      acc[2]  = fmaf(wf, w0.z, acc[2]);  acc[3]  = fmaf(wf, w0.w, acc[3]);
      acc[4]  = fmaf(wf, w1.x, acc[4]);  acc[5]  = fmaf(wf, w1.y, acc[5]);
      acc[6]  = fmaf(wf, w1.z, acc[6]);  acc[7]  = fmaf(wf, w1.w, acc[7]);
      acc[8]  = fmaf(wf, w2.x, acc[8]);  acc[9]  = fmaf(wf, w2.y, acc[9]);
      acc[10] = fmaf(wf, w2.z, acc[10]); acc[11] = fmaf(wf, w2.w, acc[11]);
      acc[12] = fmaf(wf, w3.x, acc[12]); acc[13] = fmaf(wf, w3.y, acc[13]);
      acc[14] = fmaf(wf, w3.z, acc[14]); acc[15] = fmaf(wf, w3.w, acc[15]);
    }
  }
  // 2x2 max-pool across lanes, + bias, relu, store (bias-after-max is exact)
  #pragma unroll
  for (int j = 0; j < 16; ++j) {
    float v = acc[j];
    v = fmaxf(v, __shfl_xor(v, 1, 64));
    v = fmaxf(v, __shfl_xor(v, 8, 64));
    acc[j] = v;
  }
  if (((x | y) & 1) == 0) {
    const int pidx = (y >> 1)*4 + (x >> 1);
    #pragma unroll
    for (int j = 0; j < 16; ++j) {
      float v = fmaxf(acc[j] + b[oc0 + j], 0.f);
      outC[(size_t)img*2048 + (size_t)(oc0 + j)*16 + pidx] = v;
    }
  }
}

// ================= FC GEMM: [4096,2048] @ [2048,256], split-K=2, 64x64 tiles, 4x4 micro-tile
__global__ __launch_bounds__(256) void k_fc(const float* __restrict__ C,
    const float* __restrict__ fcw, float* __restrict__ P0, float* __restrict__ P1) {
  __shared__ float As[32][68];   // A^T tile: As[k][row], padded
  __shared__ float Bs[32][68];   // B tile:   Bs[k][col], padded
  const int t = threadIdx.x;
  const int r0 = blockIdx.x * 64;
  const int nc = blockIdx.y * 64;
  const int kbase = blockIdx.z * 1024;
  float* __restrict__ P = blockIdx.z ? P1 : P0;
  const int tx = t & 15, ty = t >> 4;
  float acc[4][4];
  #pragma unroll
  for (int i = 0; i < 4; ++i)
    #pragma unroll
    for (int j = 0; j < 4; ++j) acc[i][j] = 0.f;
  const int ia0 = t*2, ia1 = t*2 + 1;
  for (int c = 0; c < 32; ++c) {
    const int k0 = kbase + c*32;
    __syncthreads();
    #pragma unroll
    for (int j = 0; j < 2; ++j) {
      int idx = (j ? ia1 : ia0);
      int row = idx >> 3, kq = idx & 7;
      float4 v = *(const float4*)&C[(size_t)(r0+row)*2048 + k0 + kq*4];
      As[kq*4+0][row] = v.x; As[kq*4+1][row] = v.y;
      As[kq*4+2][row] = v.z; As[kq*4+3][row] = v.w;
    }
    #pragma unroll
    for (int j = 0; j < 2; ++j) {
      int idx = (j ? ia1 : ia0);
      int krow = idx >> 4, c4 = idx & 15;
      float4 v = *(const float4*)&fcw[(size_t)(k0+krow)*256 + nc + c4*4];
      *(float4*)&Bs[krow][c4*4] = v;
    }
    __syncthreads();
    #pragma unroll 8
    for (int k = 0; k < 32; ++k) {
      float4 av = *(const float4*)&As[k][ty*4];
      float4 bv = *(const float4*)&Bs[k][tx*4];
      float a[4] = {av.x, av.y, av.z, av.w};
      float bbv[4] = {bv.x, bv.y, bv.z, bv.w};
      #pragma unroll
      for (int i = 0; i < 4; ++i)
        #pragma unroll
        for (int j = 0; j < 4; ++j)
          acc[i][j] = fmaf(a[i], bbv[j], acc[i][j]);
    }
  }
  #pragma unroll
  for (int i = 0; i < 4; ++i) {
    float4 v = make_float4(acc[i][0], acc[i][1], acc[i][2], acc[i][3]);
    *(float4*)&P[(size_t)(r0 + ty*4 + i)*256 + nc + tx*4] = v;
  }
}

// ================= gate: feat = P0+P1+fcb; logits; top-2 softmax; expert lists
__global__ __launch_bounds__(256) void k_gate(const float* __restrict__ P0,
    const float* __restrict__ P1, const float* __restrict__ fcb,
    const float* __restrict__ gw, const float* __restrict__ gb,
    float* __restrict__ feat, int* __restrict__ cnt, float* __restrict__ gsum,
    int* __restrict__ lrow, float* __restrict__ lg) {
  __shared__ float ft[16][256];
  __shared__ float lgs[16][16];
  __shared__ float gwl[4096];
  const int t = threadIdx.x;
  const int r0 = blockIdx.x * 16;
  for (int i = t; i < 4096; i += 256) gwl[i] = gw[i];
  float bb = fcb[t];
  #pragma unroll
  for (int r = 0; r < 16; ++r) {
    size_t off = (size_t)(r0+r)*256 + t;
    float v = P0[off] + P1[off] + bb;
    ft[r][t] = v;
    feat[off] = v;
  }
  __syncthreads();
  {
    int r = t >> 4, e = t & 15;
    float s = gb[e];
    for (int k = 0; k < 256; ++k) s = fmaf(ft[r][k], gwl[k*16 + e], s);
    lgs[r][e] = s;
  }
  __syncthreads();
  if (t < 16) {
    int r = t;
    float v1 = -3.402823e38f, v2 = -3.402823e38f;
    int i1 = 0, i2 = 0;
    for (int e = 0; e < 16; ++e) {
      float v = lgs[r][e];
      if (v > v1)      { v2 = v1; i2 = i1; v1 = v; i1 = e; }
      else if (v > v2) { v2 = v;  i2 = e; }
    }
    float ex = __expf(v2 - v1);
    float g1 = 1.f / (1.f + ex);
    float g2 = ex  / (1.f + ex);
    int row = r0 + r;
    int p1 = atomicAdd(&cnt[i1], 1); lrow[i1*4096 + p1] = row; lg[i1*4096 + p1] = g1;
    int p2 = atomicAdd(&cnt[i2], 1); lrow[i2*4096 + p2] = row; lg[i2*4096 + p2] = g2;
    atomicAdd(&gsum[i1], g1);
    atomicAdd(&gsum[i2], g2);
  }
}

// ================= MoE: per-expert grouped rows, 16-row tiles, sparse top-2 (exact)
__global__ __launch_bounds__(256) void k_moe(const float* __restrict__ feat,
    const float* __restrict__ ew1, const float* __restrict__ eb1,
    const float* __restrict__ ew2, const float* __restrict__ eb2,
    const int* __restrict__ cnt, const int* __restrict__ lrow, const float* __restrict__ lgw,
    float* __restrict__ moe) {
  const int e = blockIdx.y;
  const int n_e = cnt[e];
  const int start = blockIdx.x * 16;
  if (start >= n_e) return;
  const int n = min(16, n_e - start);
  __shared__ float fs[16][256];
  __shared__ float t1[16][64];
  __shared__ int   rws[16];
  __shared__ float gws2[16];
  const int t = threadIdx.x;
  if (t < 16) {
    if (t < n) { rws[t] = lrow[e*4096 + start + t]; gws2[t] = lgw[e*4096 + start + t]; }
    else       { rws[t] = 0; gws2[t] = 0.f; }
  }
  __syncthreads();
  for (int i = t; i < 16*256; i += 256) {
    int r = i >> 8, k = i & 255;
    fs[r][k] = (r < n) ? feat[(size_t)rws[r]*256 + k] : 0.f;
  }
  float eo[16];
  #pragma unroll
  for (int r = 0; r < 16; ++r) eo[r] = 0.f;
  const float* w1 = ew1 + (size_t)e*262144;
  const float* w2 = ew2 + (size_t)e*262144;
  const int h = t & 63, rg = t >> 6;
  for (int hc = 0; hc < 1024; hc += 64) {
    float a[4];
    {
      float bb = eb1[e*1024 + hc + h];
      a[0]=bb; a[1]=bb; a[2]=bb; a[3]=bb;
    }
    __syncthreads();
    #pragma unroll 4
    for (int k = 0; k < 256; ++k) {
      float wv = w1[(size_t)k*1024 + hc + h];
      #pragma unroll
      for (int rr = 0; rr < 4; ++rr) a[rr] = fmaf(fs[rg*4 + rr][k], wv, a[rr]);
    }
    #pragma unroll
    for (int rr = 0; rr < 4; ++rr) t1[rg*4 + rr][h] = fmaxf(a[rr], 0.f);
    __syncthreads();
    #pragma unroll 4
    for (int hh = 0; hh < 64; ++hh) {
      float wv = w2[(size_t)(hc+hh)*256 + t];
      #pragma unroll
      for (int r = 0; r < 16; ++r) eo[r] = fmaf(t1[r][hh], wv, eo[r]);
    }
  }
  float b2 = eb2[e*256 + t];
  for (int r = 0; r < n; ++r)
    atomicAdd(&moe[(size_t)rws[r]*256 + t], gws2[r] * (eo[r] + b2));
}

// ================= load-balance loss
__global__ void k_lb(const float* __restrict__ gsum, float* __restrict__ out_lb) {
  int t = threadIdx.x;
  float term = 0.f;
  if (t < 16) {
    float D = gsum[t] * (1.f/4096.f);
    term = D * logf(D + 1e-8f);
  }
  #pragma unroll
  for (int o = 8; o > 0; o >>= 1) term += __shfl_down(term, o, 64);
  if (t == 0) *out_lb = term;
}

// ================= LayerNorm(moe + feat) in-place into moe
__global__ __launch_bounds__(256) void k_ln(const float* __restrict__ feat,
    float* __restrict__ moe, const float* __restrict__ g, const float* __restrict__ bp) {
  const int r = blockIdx.x, t = threadIdx.x;
  float v = moe[(size_t)r*256 + t] + feat[(size_t)r*256 + t];
  float s = v, q = v * v;
  #pragma unroll
  for (int o = 32; o > 0; o >>= 1) {
    s += __shfl_down(s, o, 64);
    q += __shfl_down(q, o, 64);
  }
  __shared__ float ss[4], qq[4];
  int wv = t >> 6;
  if ((t & 63) == 0) { ss[wv] = s; qq[wv] = q; }
  __syncthreads();
  float S = ss[0]+ss[1]+ss[2]+ss[3];
  float Q = qq[0]+qq[1]+qq[2]+qq[3];
  float mu  = S * (1.f/256.f);
  float var = Q * (1.f/256.f) - mu*mu;
  float inv = rsqrtf(var + 1e-5f);
  moe[(size_t)r*256 + t] = (v - mu) * inv * g[t] + bp[t];
}

// ================= output GEMM: [4096,256] @ [256,1000] + b
__global__ __launch_bounds__(256) void k_out(const float* __restrict__ y,
    const float* __restrict__ ow, const float* __restrict__ ob,
    float* __restrict__ out) {
  __shared__ float ys[32][256];
  const int t = threadIdx.x;
  const int r0 = blockIdx.x * 32;
  const int c = blockIdx.y * 256 + t;
  for (int i = t; i < 32*256; i += 256) {
    int r = i >> 8, k = i & 255;
    ys[r][k] = y[(size_t)(r0+r)*256 + k];
  }
  __syncthreads();
  if (c >= NCLS) return;
  float acc[32];
  {
    float bb = ob[c];
    #pragma unroll
    for (int r = 0; r < 32; ++r) acc[r] = bb;
  }
  #pragma unroll 4
  for (int k = 0; k < 256; ++k) {
    float wv = ow[(size_t)k*NCLS + c];
    #pragma unroll
    for (int r = 0; r < 32; ++r) acc[r] = fmaf(ys[r][k], wv, acc[r]);
  }
  for (int r = 0; r < 32; ++r) out[(size_t)(r0+r)*NCLS + c] = acc[r];
}

// ================= launch =================
extern "C" void kernel_launch(void* const* d_in, const int* in_sizes, int n_in,
                              void* d_out, int out_size, void* d_ws, size_t ws_size,
                              hipStream_t stream) {
  const float* x   = (const float*)d_in[0];
  const float* c1w = (const float*)d_in[1];
  const float* c1b = (const float*)d_in[2];
  const float* c2w = (const float*)d_in[3];
  const float* c2b = (const float*)d_in[4];
  const float* c3w = (const float*)d_in[5];
  const float* c3b = (const float*)d_in[6];
  const float* fcw = (const float*)d_in[7];
  const float* fcb = (const float*)d_in[8];
  const float* gw  = (const float*)d_in[9];
  const float* gb  = (const float*)d_in[10];
  const float* ew1 = (const float*)d_in[11];
  const float* eb1 = (const float*)d_in[12];
  const float* ew2 = (const float*)d_in[13];
  const float* eb2 = (const float*)d_in[14];
  const float* lng = (const float*)d_in[15];
  const float* lnb = (const float*)d_in[16];
  const float* ow  = (const float*)d_in[17];
  const float* ob  = (const float*)d_in[18];
  char* ws = (char*)d_ws;
  float* Bb   = (float*)(ws + OFF_B);
  float* P0   = (float*)(ws + OFF_P0);   // aliases Bb (dead after conv3)
  float* P1   = (float*)(ws + OFF_P1);
  float* C    = (float*)(ws + OFF_C);
  float* wT3  = (float*)(ws + OFF_FEAT); // aliases feat (feat written after conv3)
  float* feat = (float*)(ws + OFF_FEAT);
  float* moe  = (float*)(ws + OFF_MOE);
  int*   cnt  = (int*)(ws + OFF_CNT);
  float* gsum = (float*)(ws + OFF_GSUM);
  int*   lrow = (int*)(ws + OFF_LROW);
  float* lgv  = (float*)(ws + OFF_LG);
  float* outp = (float*)d_out;

  // zero moe accumulator + counts + gate sums (contiguous region)
  hipMemsetAsync(ws + OFF_MOE, 0, 4194304 + 128, stream);

  hipLaunchKernelGGL(k_conv12, dim3(4096),    dim3(512), 0, stream, x, c1w, c1b, c2w, c2b, Bb);
  hipLaunchKernelGGL(k_wt3,    dim3(288),     dim3(256), 0, stream, c3w, wT3);
  hipLaunchKernelGGL(k_conv3,  dim3(4096, 2), dim3(256), 0, stream, Bb, wT3, c3b, C);
  hipLaunchKernelGGL(k_fc,     dim3(64, 4, 2),dim3(256), 0, stream, C, fcw, P0, P1);
  hipLaunchKernelGGL(k_gate,   dim3(256),     dim3(256), 0, stream, P0, P1, fcb, gw, gb,
                     feat, cnt, gsum, lrow, lgv);
  hipLaunchKernelGGL(k_moe,    dim3(256, 16), dim3(256), 0, stream, feat, ew1, eb1, ew2, eb2,
                     cnt, lrow, lgv, moe);
  hipLaunchKernelGGL(k_lb,     dim3(1),       dim3(64),  0, stream, gsum, outp + (size_t)NB*NCLS);
  hipLaunchKernelGGL(k_ln,     dim3(4096),    dim3(256), 0, stream, feat, moe, lng, lnb);
  hipLaunchKernelGGL(k_out,    dim3(128, 4),  dim3(256), 0, stream, moe, ow, ob, outp);
}

// Round 5
// 1977.894 us; speedup vs baseline: 1.7801x; 1.7801x over previous
//
#include <hip/hip_runtime.h>
#include <hip/hip_bf16.h>

// ---------------- problem sizes ----------------
#define NB   4096
#define NEXP 16
#define DDIM 256
#define HDIM 1024
#define NCLS 1000

// ---------------- workspace layout (bytes) ----------------
#define OFF_B    ((size_t)0)
#define OFF_P0   ((size_t)0)           // f32 [4096][256] FC partial (K half 0)
#define OFF_P1   ((size_t)4194304)     // f32 [4096][256] FC partial (K half 1)
#define OFF_C    ((size_t)67108864)
#define OFF_FEAT ((size_t)100663296)   // f32 [4096][256]; ALSO wT3 (288 KB) before k_gate
#define OFF_MOE  ((size_t)104857600)   // f32 [4096][256]
#define OFF_CNT  ((size_t)109051904)   // int [16]
#define OFF_GSUM ((size_t)109051968)   // f32 [16]
#define OFF_LROW ((size_t)109052032)   // int [16][4096]
#define OFF_LG   ((size_t)109314176)   // f32 [16][4096]

// ================= fused conv1+conv2 per image =================
__global__ __launch_bounds__(512) void k_conv12(const float* __restrict__ x,
    const float* __restrict__ w1, const float* __restrict__ b1,
    const float* __restrict__ w2, const float* __restrict__ b2,
    float* __restrict__ outB) {
  __shared__ float xs[3][34][36];     // padded input image
  __shared__ float as[32][18][20];    // padded conv1 pooled output
  __shared__ float ws2[64*288];       // conv2 weights (72 KB)
  __shared__ float ws1[864];
  __shared__ float bs1[32];
  __shared__ float bs2[64];
  const int t = threadIdx.x;
  const int img = blockIdx.x;
  for (int i = t; i < 3*34*36; i += 512) ((float*)xs)[i] = 0.f;
  for (int i = t; i < 32*18*20; i += 512) ((float*)as)[i] = 0.f;
  __syncthreads();
  for (int i = t; i < 3072; i += 512) {
    int ic = i >> 10, rem = i & 1023, y = rem >> 5, xx = rem & 31;
    xs[ic][y+1][xx+1] = x[(size_t)img*3072 + i];
  }
  for (int i = t; i < 864; i += 512) ws1[i] = w1[i];
  for (int i = t; i < 64*288; i += 512) ws2[i] = w2[i];
  if (t < 32) bs1[t] = b1[t];
  else if (t >= 64 && t < 128) bs2[t-64] = b2[t-64];
  __syncthreads();
  // ---- conv1 + pool + relu -> as interior ----
  {
    const int p = t & 255, grp = t >> 8;
    const int px = p & 15, py = p >> 4;
    float win[3][4][4];
    #pragma unroll
    for (int ic = 0; ic < 3; ++ic)
      #pragma unroll
      for (int r = 0; r < 4; ++r) {
        float2 a  = *(const float2*)&xs[ic][2*py+r][2*px];
        float2 c2 = *(const float2*)&xs[ic][2*py+r][2*px+2];
        win[ic][r][0]=a.x; win[ic][r][1]=a.y; win[ic][r][2]=c2.x; win[ic][r][3]=c2.y;
      }
    for (int occ = grp*16; occ < grp*16 + 16; occ += 8) {
      float acc[8][4];
      #pragma unroll
      for (int j = 0; j < 8; ++j) { float bb = bs1[occ+j]; acc[j][0]=bb;acc[j][1]=bb;acc[j][2]=bb;acc[j][3]=bb; }
      #pragma unroll
      for (int ic = 0; ic < 3; ++ic) {
        #pragma unroll
        for (int j = 0; j < 8; ++j) {
          const float* wp = &ws1[(occ+j)*27 + ic*9];
          float wv[9];
          #pragma unroll
          for (int q = 0; q < 9; ++q) wv[q] = wp[q];
          #pragma unroll
          for (int ry = 0; ry < 2; ++ry)
            #pragma unroll
            for (int rx = 0; rx < 2; ++rx) {
              float s = acc[j][ry*2+rx];
              #pragma unroll
              for (int ky = 0; ky < 3; ++ky)
                #pragma unroll
                for (int kx = 0; kx < 3; ++kx)
                  s = fmaf(wv[ky*3+kx], win[ic][ry+ky][rx+kx], s);
              acc[j][ry*2+rx] = s;
            }
        }
      }
      #pragma unroll
      for (int j = 0; j < 8; ++j) {
        float m = fmaxf(fmaxf(acc[j][0],acc[j][1]), fmaxf(acc[j][2],acc[j][3]));
        as[occ+j][py+1][px+1] = fmaxf(m, 0.f);
      }
    }
  }
  __syncthreads();
  // ---- conv2 + pool + relu -> global ----
  {
    const int pix = t & 63, ocg = t >> 6;
    const int py = pix >> 3, px = pix & 7;
    float acc[8][4];
    #pragma unroll
    for (int j = 0; j < 8; ++j) { float bb = bs2[j*8+ocg]; acc[j][0]=bb;acc[j][1]=bb;acc[j][2]=bb;acc[j][3]=bb; }
    for (int ic = 0; ic < 32; ++ic) {
      float win[4][4];
      #pragma unroll
      for (int r = 0; r < 4; ++r) {
        float2 a  = *(const float2*)&as[ic][2*py+r][2*px];
        float2 c2 = *(const float2*)&as[ic][2*py+r][2*px+2];
        win[r][0]=a.x; win[r][1]=a.y; win[r][2]=c2.x; win[r][3]=c2.y;
      }
      #pragma unroll
      for (int j = 0; j < 8; ++j) {
        const float* wp = &ws2[(j*8+ocg)*288 + ic*9];
        float wv[9];
        #pragma unroll
        for (int q = 0; q < 9; ++q) wv[q] = wp[q];
        #pragma unroll
        for (int ry = 0; ry < 2; ++ry)
          #pragma unroll
          for (int rx = 0; rx < 2; ++rx) {
            float s = acc[j][ry*2+rx];
            #pragma unroll
            for (int ky = 0; ky < 3; ++ky)
              #pragma unroll
              for (int kx = 0; kx < 3; ++kx)
                s = fmaf(wv[ky*3+kx], win[ry+ky][rx+kx], s);
            acc[j][ry*2+rx] = s;
          }
      }
    }
    const size_t obase = (size_t)img*4096 + (size_t)(py*8 + px);
    #pragma unroll
    for (int j = 0; j < 8; ++j) {
      float m = fmaxf(fmaxf(acc[j][0],acc[j][1]), fmaxf(acc[j][2],acc[j][3]));
      outB[obase + (size_t)(j*8+ocg)*64] = fmaxf(m, 0.f);
    }
  }
}

// ================= weight transpose for conv3: w[oc][ic][k] -> wT[(ic*9+k)*128 + oc]
__global__ __launch_bounds__(256) void k_wt3(const float* __restrict__ w, float* __restrict__ wT) {
  int i = blockIdx.x*256 + threadIdx.x;   // i over 64*9*128
  if (i >= 64*9*128) return;
  int oc = i & 127, rem = i >> 7;         // rem = ic*9 + k
  int k = rem % 9, ic = rem / 9;
  wT[i] = w[(oc*64 + ic)*9 + k];
}

// ================= conv3 v3: lane=oc, weights in VGPR (coalesced, double-buffered),
// input uniform-broadcast from LDS. Block = 1 img, 4 waves = (oc-half) x (pixel-half).
// Per ic per wave: 9 weight loads + 12 uniform ds_read_b128 -> 264 static FMAs.
__global__ __launch_bounds__(256) void k_conv3(const float* __restrict__ inB,
    const float* __restrict__ wT, const float* __restrict__ b,
    float* __restrict__ outC) {
  __shared__ float is[4096];   // [ic][8][8], 16 KB
  const int t = threadIdx.x;
  const int img = blockIdx.x;
  // stage whole image (4096 floats) coalesced
  {
    const float4* src = (const float4*)(inB + (size_t)img*4096);
    float4* dst = (float4*)is;
    #pragma unroll
    for (int j = 0; j < 4; ++j) dst[j*256 + t] = src[j*256 + t];
  }
  __syncthreads();
  const int lane = t & 63, wv = t >> 6;
  const int oc = (wv & 1)*64 + lane;   // coalesced weight lane
  const int h  = wv >> 1;              // pixel half: rows h*4 .. h*4+3
  const int rowbase = h*4 - 1;         // global row of inr row 0

  float acc[32];
  #pragma unroll
  for (int i = 0; i < 32; ++i) acc[i] = 0.f;

  float wn[9];
  #pragma unroll
  for (int k = 0; k < 9; ++k) wn[k] = wT[k*128 + oc];   // ic = 0

  for (int ic = 0; ic < 64; ++ic) {
    float wk[9];
    #pragma unroll
    for (int k = 0; k < 9; ++k) wk[k] = wn[k];
    if (ic < 63) {
      #pragma unroll
      for (int k = 0; k < 9; ++k) wn[k] = wT[(size_t)((ic+1)*9 + k)*128 + oc];
    }
    // input rows rowbase..rowbase+5 (6 rows x 8), uniform broadcast; halo rows = 0
    float inr[48];
    #pragma unroll
    for (int j = 0; j < 6; ++j) {
      int g = rowbase + j;               // wave-uniform
      if (g >= 0 && g <= 7) {
        float4 v0 = *(const float4*)&is[ic*64 + g*8];
        float4 v1 = *(const float4*)&is[ic*64 + g*8 + 4];
        inr[j*8+0]=v0.x; inr[j*8+1]=v0.y; inr[j*8+2]=v0.z; inr[j*8+3]=v0.w;
        inr[j*8+4]=v1.x; inr[j*8+5]=v1.y; inr[j*8+6]=v1.z; inr[j*8+7]=v1.w;
      } else {
        #pragma unroll
        for (int q = 0; q < 8; ++q) inr[j*8+q] = 0.f;
      }
    }
    // 264 static FMAs (cols compile-time pruned; halo rows are zeros)
    #pragma unroll
    for (int ky = -1; ky <= 1; ++ky)
      #pragma unroll
      for (int kx = -1; kx <= 1; ++kx) {
        float wkk = wk[(ky+1)*3 + (kx+1)];
        #pragma unroll
        for (int pyl = 0; pyl < 4; ++pyl) {
          const int ir = pyl + 1 + ky;   // local inr row
          #pragma unroll
          for (int px = 0; px < 8; ++px) {
            if (px+kx < 0 || px+kx > 7) continue;
            acc[pyl*8+px] = fmaf(wkk, inr[ir*8 + px+kx], acc[pyl*8+px]);
          }
        }
      }
  }
  // 2x2 pool + bias + relu, store [img][oc][16]
  const float bb = b[oc];
  #pragma unroll
  for (int pr = 0; pr < 2; ++pr)
    #pragma unroll
    for (int pc = 0; pc < 4; ++pc) {
      float v = fmaxf(fmaxf(acc[(2*pr)*8 + 2*pc],   acc[(2*pr)*8 + 2*pc+1]),
                      fmaxf(acc[(2*pr+1)*8 + 2*pc], acc[(2*pr+1)*8 + 2*pc+1]));
      outC[(size_t)img*2048 + (size_t)oc*16 + (h*2+pr)*4 + pc] = fmaxf(v + bb, 0.f);
    }
}

// ================= FC GEMM: [4096,2048] @ [2048,256], split-K=2, 64x64 tiles, 4x4 micro-tile
__global__ __launch_bounds__(256) void k_fc(const float* __restrict__ C,
    const float* __restrict__ fcw, float* __restrict__ P0, float* __restrict__ P1) {
  __shared__ float As[32][68];   // A^T tile: As[k][row], padded
  __shared__ float Bs[32][68];   // B tile:   Bs[k][col], padded
  const int t = threadIdx.x;
  const int r0 = blockIdx.x * 64;
  const int nc = blockIdx.y * 64;
  const int kbase = blockIdx.z * 1024;
  float* __restrict__ P = blockIdx.z ? P1 : P0;
  const int tx = t & 15, ty = t >> 4;
  float acc[4][4];
  #pragma unroll
  for (int i = 0; i < 4; ++i)
    #pragma unroll
    for (int j = 0; j < 4; ++j) acc[i][j] = 0.f;
  const int ia0 = t*2, ia1 = t*2 + 1;
  for (int c = 0; c < 32; ++c) {
    const int k0 = kbase + c*32;
    __syncthreads();
    #pragma unroll
    for (int j = 0; j < 2; ++j) {
      int idx = (j ? ia1 : ia0);
      int row = idx >> 3, kq = idx & 7;
      float4 v = *(const float4*)&C[(size_t)(r0+row)*2048 + k0 + kq*4];
      As[kq*4+0][row] = v.x; As[kq*4+1][row] = v.y;
      As[kq*4+2][row] = v.z; As[kq*4+3][row] = v.w;
    }
    #pragma unroll
    for (int j = 0; j < 2; ++j) {
      int idx = (j ? ia1 : ia0);
      int krow = idx >> 4, c4 = idx & 15;
      float4 v = *(const float4*)&fcw[(size_t)(k0+krow)*256 + nc + c4*4];
      *(float4*)&Bs[krow][c4*4] = v;
    }
    __syncthreads();
    #pragma unroll 8
    for (int k = 0; k < 32; ++k) {
      float4 av = *(const float4*)&As[k][ty*4];
      float4 bv = *(const float4*)&Bs[k][tx*4];
      float a[4] = {av.x, av.y, av.z, av.w};
      float bbv[4] = {bv.x, bv.y, bv.z, bv.w};
      #pragma unroll
      for (int i = 0; i < 4; ++i)
        #pragma unroll
        for (int j = 0; j < 4; ++j)
          acc[i][j] = fmaf(a[i], bbv[j], acc[i][j]);
    }
  }
  #pragma unroll
  for (int i = 0; i < 4; ++i) {
    float4 v = make_float4(acc[i][0], acc[i][1], acc[i][2], acc[i][3]);
    *(float4*)&P[(size_t)(r0 + ty*4 + i)*256 + nc + tx*4] = v;
  }
}

// ================= gate: feat = P0+P1+fcb; logits; top-2 softmax; expert lists
__global__ __launch_bounds__(256) void k_gate(const float* __restrict__ P0,
    const float* __restrict__ P1, const float* __restrict__ fcb,
    const float* __restrict__ gw, const float* __restrict__ gb,
    float* __restrict__ feat, int* __restrict__ cnt, float* __restrict__ gsum,
    int* __restrict__ lrow, float* __restrict__ lg) {
  __shared__ float ft[16][256];
  __shared__ float lgs[16][16];
  __shared__ float gwl[4096];
  const int t = threadIdx.x;
  const int r0 = blockIdx.x * 16;
  for (int i = t; i < 4096; i += 256) gwl[i] = gw[i];
  float bb = fcb[t];
  #pragma unroll
  for (int r = 0; r < 16; ++r) {
    size_t off = (size_t)(r0+r)*256 + t;
    float v = P0[off] + P1[off] + bb;
    ft[r][t] = v;
    feat[off] = v;
  }
  __syncthreads();
  {
    int r = t >> 4, e = t & 15;
    float s = gb[e];
    for (int k = 0; k < 256; ++k) s = fmaf(ft[r][k], gwl[k*16 + e], s);
    lgs[r][e] = s;
  }
  __syncthreads();
  if (t < 16) {
    int r = t;
    float v1 = -3.402823e38f, v2 = -3.402823e38f;
    int i1 = 0, i2 = 0;
    for (int e = 0; e < 16; ++e) {
      float v = lgs[r][e];
      if (v > v1)      { v2 = v1; i2 = i1; v1 = v; i1 = e; }
      else if (v > v2) { v2 = v;  i2 = e; }
    }
    float ex = __expf(v2 - v1);
    float g1 = 1.f / (1.f + ex);
    float g2 = ex  / (1.f + ex);
    int row = r0 + r;
    int p1 = atomicAdd(&cnt[i1], 1); lrow[i1*4096 + p1] = row; lg[i1*4096 + p1] = g1;
    int p2 = atomicAdd(&cnt[i2], 1); lrow[i2*4096 + p2] = row; lg[i2*4096 + p2] = g2;
    atomicAdd(&gsum[i1], g1);
    atomicAdd(&gsum[i2], g2);
  }
}

// ================= MoE: per-expert grouped rows, 16-row tiles, sparse top-2 (exact)
__global__ __launch_bounds__(256) void k_moe(const float* __restrict__ feat,
    const float* __restrict__ ew1, const float* __restrict__ eb1,
    const float* __restrict__ ew2, const float* __restrict__ eb2,
    const int* __restrict__ cnt, const int* __restrict__ lrow, const float* __restrict__ lgw,
    float* __restrict__ moe) {
  const int e = blockIdx.y;
  const int n_e = cnt[e];
  const int start = blockIdx.x * 16;
  if (start >= n_e) return;
  const int n = min(16, n_e - start);
  __shared__ float fs[16][256];
  __shared__ float t1[16][64];
  __shared__ int   rws[16];
  __shared__ float gws2[16];
  const int t = threadIdx.x;
  if (t < 16) {
    if (t < n) { rws[t] = lrow[e*4096 + start + t]; gws2[t] = lgw[e*4096 + start + t]; }
    else       { rws[t] = 0; gws2[t] = 0.f; }
  }
  __syncthreads();
  for (int i = t; i < 16*256; i += 256) {
    int r = i >> 8, k = i & 255;
    fs[r][k] = (r < n) ? feat[(size_t)rws[r]*256 + k] : 0.f;
  }
  float eo[16];
  #pragma unroll
  for (int r = 0; r < 16; ++r) eo[r] = 0.f;
  const float* w1 = ew1 + (size_t)e*262144;
  const float* w2 = ew2 + (size_t)e*262144;
  const int h = t & 63, rg = t >> 6;
  for (int hc = 0; hc < 1024; hc += 64) {
    float a[4];
    {
      float bb = eb1[e*1024 + hc + h];
      a[0]=bb; a[1]=bb; a[2]=bb; a[3]=bb;
    }
    __syncthreads();
    #pragma unroll 4
    for (int k = 0; k < 256; ++k) {
      float wv = w1[(size_t)k*1024 + hc + h];
      #pragma unroll
      for (int rr = 0; rr < 4; ++rr) a[rr] = fmaf(fs[rg*4 + rr][k], wv, a[rr]);
    }
    #pragma unroll
    for (int rr = 0; rr < 4; ++rr) t1[rg*4 + rr][h] = fmaxf(a[rr], 0.f);
    __syncthreads();
    #pragma unroll 4
    for (int hh = 0; hh < 64; ++hh) {
      float wv = w2[(size_t)(hc+hh)*256 + t];
      #pragma unroll
      for (int r = 0; r < 16; ++r) eo[r] = fmaf(t1[r][hh], wv, eo[r]);
    }
  }
  float b2 = eb2[e*256 + t];
  for (int r = 0; r < n; ++r)
    atomicAdd(&moe[(size_t)rws[r]*256 + t], gws2[r] * (eo[r] + b2));
}

// ================= load-balance loss
__global__ void k_lb(const float* __restrict__ gsum, float* __restrict__ out_lb) {
  int t = threadIdx.x;
  float term = 0.f;
  if (t < 16) {
    float D = gsum[t] * (1.f/4096.f);
    term = D * logf(D + 1e-8f);
  }
  #pragma unroll
  for (int o = 8; o > 0; o >>= 1) term += __shfl_down(term, o, 64);
  if (t == 0) *out_lb = term;
}

// ================= LayerNorm(moe + feat) in-place into moe
__global__ __launch_bounds__(256) void k_ln(const float* __restrict__ feat,
    float* __restrict__ moe, const float* __restrict__ g, const float* __restrict__ bp) {
  const int r = blockIdx.x, t = threadIdx.x;
  float v = moe[(size_t)r*256 + t] + feat[(size_t)r*256 + t];
  float s = v, q = v * v;
  #pragma unroll
  for (int o = 32; o > 0; o >>= 1) {
    s += __shfl_down(s, o, 64);
    q += __shfl_down(q, o, 64);
  }
  __shared__ float ss[4], qq[4];
  int wv = t >> 6;
  if ((t & 63) == 0) { ss[wv] = s; qq[wv] = q; }
  __syncthreads();
  float S = ss[0]+ss[1]+ss[2]+ss[3];
  float Q = qq[0]+qq[1]+qq[2]+qq[3];
  float mu  = S * (1.f/256.f);
  float var = Q * (1.f/256.f) - mu*mu;
  float inv = rsqrtf(var + 1e-5f);
  moe[(size_t)r*256 + t] = (v - mu) * inv * g[t] + bp[t];
}

// ================= output GEMM: [4096,256] @ [256,1000] + b
__global__ __launch_bounds__(256) void k_out(const float* __restrict__ y,
    const float* __restrict__ ow, const float* __restrict__ ob,
    float* __restrict__ out) {
  __shared__ float ys[32][256];
  const int t = threadIdx.x;
  const int r0 = blockIdx.x * 32;
  const int c = blockIdx.y * 256 + t;
  for (int i = t; i < 32*256; i += 256) {
    int r = i >> 8, k = i & 255;
    ys[r][k] = y[(size_t)(r0+r)*256 + k];
  }
  __syncthreads();
  if (c >= NCLS) return;
  float acc[32];
  {
    float bb = ob[c];
    #pragma unroll
    for (int r = 0; r < 32; ++r) acc[r] = bb;
  }
  #pragma unroll 4
  for (int k = 0; k < 256; ++k) {
    float wv = ow[(size_t)k*NCLS + c];
    #pragma unroll
    for (int r = 0; r < 32; ++r) acc[r] = fmaf(ys[r][k], wv, acc[r]);
  }
  for (int r = 0; r < 32; ++r) out[(size_t)(r0+r)*NCLS + c] = acc[r];
}

// ================= launch =================
extern "C" void kernel_launch(void* const* d_in, const int* in_sizes, int n_in,
                              void* d_out, int out_size, void* d_ws, size_t ws_size,
                              hipStream_t stream) {
  const float* x   = (const float*)d_in[0];
  const float* c1w = (const float*)d_in[1];
  const float* c1b = (const float*)d_in[2];
  const float* c2w = (const float*)d_in[3];
  const float* c2b = (const float*)d_in[4];
  const float* c3w = (const float*)d_in[5];
  const float* c3b = (const float*)d_in[6];
  const float* fcw = (const float*)d_in[7];
  const float* fcb = (const float*)d_in[8];
  const float* gw  = (const float*)d_in[9];
  const float* gb  = (const float*)d_in[10];
  const float* ew1 = (const float*)d_in[11];
  const float* eb1 = (const float*)d_in[12];
  const float* ew2 = (const float*)d_in[13];
  const float* eb2 = (const float*)d_in[14];
  const float* lng = (const float*)d_in[15];
  const float* lnb = (const float*)d_in[16];
  const float* ow  = (const float*)d_in[17];
  const float* ob  = (const float*)d_in[18];
  char* ws = (char*)d_ws;
  float* Bb   = (float*)(ws + OFF_B);
  float* P0   = (float*)(ws + OFF_P0);   // aliases Bb (dead after conv3)
  float* P1   = (float*)(ws + OFF_P1);
  float* C    = (float*)(ws + OFF_C);
  float* wT3  = (float*)(ws + OFF_FEAT); // aliases feat (feat written after conv3)
  float* feat = (float*)(ws + OFF_FEAT);
  float* moe  = (float*)(ws + OFF_MOE);
  int*   cnt  = (int*)(ws + OFF_CNT);
  float* gsum = (float*)(ws + OFF_GSUM);
  int*   lrow = (int*)(ws + OFF_LROW);
  float* lgv  = (float*)(ws + OFF_LG);
  float* outp = (float*)d_out;

  // zero moe accumulator + counts + gate sums (contiguous region)
  hipMemsetAsync(ws + OFF_MOE, 0, 4194304 + 128, stream);

  hipLaunchKernelGGL(k_conv12, dim3(4096),    dim3(512), 0, stream, x, c1w, c1b, c2w, c2b, Bb);
  hipLaunchKernelGGL(k_wt3,    dim3(288),     dim3(256), 0, stream, c3w, wT3);
  hipLaunchKernelGGL(k_conv3,  dim3(4096),    dim3(256), 0, stream, Bb, wT3, c3b, C);
  hipLaunchKernelGGL(k_fc,     dim3(64, 4, 2),dim3(256), 0, stream, C, fcw, P0, P1);
  hipLaunchKernelGGL(k_gate,   dim3(256),     dim3(256), 0, stream, P0, P1, fcb, gw, gb,
                     feat, cnt, gsum, lrow, lgv);
  hipLaunchKernelGGL(k_moe,    dim3(256, 16), dim3(256), 0, stream, feat, ew1, eb1, ew2, eb2,
                     cnt, lrow, lgv, moe);
  hipLaunchKernelGGL(k_lb,     dim3(1),       dim3(64),  0, stream, gsum, outp + (size_t)NB*NCLS);
  hipLaunchKernelGGL(k_ln,     dim3(4096),    dim3(256), 0, stream, feat, moe, lng, lnb);
  hipLaunchKernelGGL(k_out,    dim3(128, 4),  dim3(256), 0, stream, moe, ow, ob, outp);
}

// Round 6
// 1975.291 us; speedup vs baseline: 1.7825x; 1.0013x over previous
//
#include <hip/hip_runtime.h>
#include <hip/hip_bf16.h>

// ---------------- problem sizes ----------------
#define NB   4096
#define NEXP 16
#define DDIM 256
#define HDIM 1024
#define NCLS 1000

// ---------------- workspace layout (bytes) ----------------
#define OFF_B    ((size_t)0)
#define OFF_P0   ((size_t)0)           // f32 [4096][256] FC partial (K half 0)
#define OFF_P1   ((size_t)4194304)     // f32 [4096][256] FC partial (K half 1)
#define OFF_C    ((size_t)67108864)    // conv3 out f32 [4096][2048]; ALSO wT2 (74 KB) before conv12
#define OFF_FEAT ((size_t)100663296)   // f32 [4096][256]; ALSO wT3 (288 KB) before k_gate
#define OFF_MOE  ((size_t)104857600)   // f32 [4096][256]
#define OFF_CNT  ((size_t)109051904)   // int [16]
#define OFF_GSUM ((size_t)109051968)   // f32 [16]
#define OFF_LROW ((size_t)109052032)   // int [16][4096]
#define OFF_LG   ((size_t)109314176)   // f32 [16][4096]

// ================= weight transpose for conv2: w[oc][ic][k] -> wT2[(ic*9+k)*64 + oc]
__global__ __launch_bounds__(256) void k_wt2(const float* __restrict__ w, float* __restrict__ wT) {
  int i = blockIdx.x*256 + threadIdx.x;   // i over 32*9*64 = 18432
  if (i >= 32*9*64) return;
  int oc = i & 63, rem = i >> 6;          // rem = ic*9 + k
  int k = rem % 9, ic = rem / 9;
  wT[i] = w[(oc*32 + ic)*9 + k];
}

// ================= fused conv1+conv2 per image (v2: conv2 lane=oc, VGPR weights) ====
__global__ __launch_bounds__(512) void k_conv12(const float* __restrict__ x,
    const float* __restrict__ w1, const float* __restrict__ b1,
    const float* __restrict__ wT2, const float* __restrict__ b2,
    float* __restrict__ outB) {
  __shared__ float xs[3][34][36];     // padded input image (14.7 KB)
  __shared__ float as[32][18][20];    // padded conv1 pooled output (46 KB); reused for store stage
  __shared__ float ws1[864];
  __shared__ float bs1[32];
  __shared__ float bs2[64];
  const int t = threadIdx.x;
  const int img = blockIdx.x;
  for (int i = t; i < 3*34*36; i += 512) ((float*)xs)[i] = 0.f;
  for (int i = t; i < 32*18*20; i += 512) ((float*)as)[i] = 0.f;
  __syncthreads();
  for (int i = t; i < 3072; i += 512) {
    int ic = i >> 10, rem = i & 1023, y = rem >> 5, xx = rem & 31;
    xs[ic][y+1][xx+1] = x[(size_t)img*3072 + i];
  }
  for (int i = t; i < 864; i += 512) ws1[i] = w1[i];
  if (t < 32) bs1[t] = b1[t];
  else if (t >= 64 && t < 128) bs2[t-64] = b2[t-64];
  __syncthreads();
  // ---- conv1 + pool + relu -> as interior (thread = pixel x 16 ocs) ----
  {
    const int p = t & 255, grp = t >> 8;
    const int px = p & 15, py = p >> 4;
    float win[3][4][4];
    #pragma unroll
    for (int ic = 0; ic < 3; ++ic)
      #pragma unroll
      for (int r = 0; r < 4; ++r) {
        float2 a  = *(const float2*)&xs[ic][2*py+r][2*px];
        float2 c2 = *(const float2*)&xs[ic][2*py+r][2*px+2];
        win[ic][r][0]=a.x; win[ic][r][1]=a.y; win[ic][r][2]=c2.x; win[ic][r][3]=c2.y;
      }
    for (int occ = grp*16; occ < grp*16 + 16; occ += 8) {
      float acc[8][4];
      #pragma unroll
      for (int j = 0; j < 8; ++j) { float bb = bs1[occ+j]; acc[j][0]=bb;acc[j][1]=bb;acc[j][2]=bb;acc[j][3]=bb; }
      #pragma unroll
      for (int ic = 0; ic < 3; ++ic) {
        #pragma unroll
        for (int j = 0; j < 8; ++j) {
          const float* wp = &ws1[(occ+j)*27 + ic*9];
          float wv[9];
          #pragma unroll
          for (int q = 0; q < 9; ++q) wv[q] = wp[q];   // wave-uniform broadcast
          #pragma unroll
          for (int ry = 0; ry < 2; ++ry)
            #pragma unroll
            for (int rx = 0; rx < 2; ++rx) {
              float s = acc[j][ry*2+rx];
              #pragma unroll
              for (int ky = 0; ky < 3; ++ky)
                #pragma unroll
                for (int kx = 0; kx < 3; ++kx)
                  s = fmaf(wv[ky*3+kx], win[ic][ry+ky][rx+kx], s);
              acc[j][ry*2+rx] = s;
            }
        }
      }
      #pragma unroll
      for (int j = 0; j < 8; ++j) {
        float m = fmaxf(fmaxf(acc[j][0],acc[j][1]), fmaxf(acc[j][2],acc[j][3]));
        as[occ+j][py+1][px+1] = fmaxf(m, 0.f);
      }
    }
  }
  __syncthreads();
  // ---- conv2 (lane=oc, wave=row-pair) + pool + relu -> LDS stage -> coalesced store ----
  {
    const int lane = t & 63, wv = t >> 6;    // lane -> oc, wv -> pre-pool rows 2wv..2wv+1
    float acc[32];
    #pragma unroll
    for (int i = 0; i < 32; ++i) acc[i] = 0.f;
    float wn[9];
    #pragma unroll
    for (int k = 0; k < 9; ++k) wn[k] = wT2[k*64 + lane];   // ic = 0
    for (int ic = 0; ic < 32; ++ic) {
      float wk[9];
      #pragma unroll
      for (int k = 0; k < 9; ++k) wk[k] = wn[k];
      if (ic < 31) {
        #pragma unroll
        for (int k = 0; k < 9; ++k) wn[k] = wT2[((ic+1)*9 + k)*64 + lane];
      }
      // 4 padded input rows (2wv .. 2wv+3), 18 cols, wave-uniform LDS broadcast
      float inr[72];
      #pragma unroll
      for (int j = 0; j < 4; ++j) {
        const float* rp = &as[ic][2*wv + j][0];
        float4 a0 = *(const float4*)rp;
        float4 a1 = *(const float4*)(rp+4);
        float4 a2 = *(const float4*)(rp+8);
        float4 a3 = *(const float4*)(rp+12);
        float2 a4 = *(const float2*)(rp+16);
        inr[j*18+0]=a0.x;  inr[j*18+1]=a0.y;  inr[j*18+2]=a0.z;  inr[j*18+3]=a0.w;
        inr[j*18+4]=a1.x;  inr[j*18+5]=a1.y;  inr[j*18+6]=a1.z;  inr[j*18+7]=a1.w;
        inr[j*18+8]=a2.x;  inr[j*18+9]=a2.y;  inr[j*18+10]=a2.z; inr[j*18+11]=a2.w;
        inr[j*18+12]=a3.x; inr[j*18+13]=a3.y; inr[j*18+14]=a3.z; inr[j*18+15]=a3.w;
        inr[j*18+16]=a4.x; inr[j*18+17]=a4.y;
      }
      // 288 static FMAs (padding zeros handle borders)
      #pragma unroll
      for (int ky = 0; ky < 3; ++ky)
        #pragma unroll
        for (int kx = 0; kx < 3; ++kx) {
          float wkk = wk[ky*3+kx];
          #pragma unroll
          for (int pr = 0; pr < 2; ++pr)
            #pragma unroll
            for (int c = 0; c < 16; ++c)
              acc[pr*16+c] = fmaf(wkk, inr[(pr+ky)*18 + c+kx], acc[pr*16+c]);
        }
    }
    __syncthreads();   // all waves done reading `as`; reuse it as store stage
    float* pool_s = &as[0][0][0];   // [64 oc][65] padded
    const float bb = bs2[lane];
    #pragma unroll
    for (int pc = 0; pc < 8; ++pc) {
      float v = fmaxf(fmaxf(acc[2*pc], acc[2*pc+1]),
                      fmaxf(acc[16+2*pc], acc[16+2*pc+1]));
      pool_s[lane*65 + wv*8 + pc] = fmaxf(v + bb, 0.f);
    }
    __syncthreads();
    const float* ps = pool_s;
    float* op = outB + (size_t)img*4096;
    #pragma unroll
    for (int j = 0; j < 8; ++j) {
      int i = j*512 + t;
      op[i] = ps[(i >> 6)*65 + (i & 63)];
    }
  }
}

// ================= weight transpose for conv3: w[oc][ic][k] -> wT[(ic*9+k)*128 + oc]
__global__ __launch_bounds__(256) void k_wt3(const float* __restrict__ w, float* __restrict__ wT) {
  int i = blockIdx.x*256 + threadIdx.x;   // i over 64*9*128
  if (i >= 64*9*128) return;
  int oc = i & 127, rem = i >> 7;         // rem = ic*9 + k
  int k = rem % 9, ic = rem / 9;
  wT[i] = w[(oc*64 + ic)*9 + k];
}

// ================= conv3 v3: lane=oc, weights in VGPR, input uniform-broadcast from LDS
__global__ __launch_bounds__(256) void k_conv3(const float* __restrict__ inB,
    const float* __restrict__ wT, const float* __restrict__ b,
    float* __restrict__ outC) {
  __shared__ float is[4096];   // [ic][8][8], 16 KB
  const int t = threadIdx.x;
  const int img = blockIdx.x;
  {
    const float4* src = (const float4*)(inB + (size_t)img*4096);
    float4* dst = (float4*)is;
    #pragma unroll
    for (int j = 0; j < 4; ++j) dst[j*256 + t] = src[j*256 + t];
  }
  __syncthreads();
  const int lane = t & 63, wv = t >> 6;
  const int oc = (wv & 1)*64 + lane;   // coalesced weight lane
  const int h  = wv >> 1;              // pixel half: rows h*4 .. h*4+3
  const int rowbase = h*4 - 1;

  float acc[32];
  #pragma unroll
  for (int i = 0; i < 32; ++i) acc[i] = 0.f;

  float wn[9];
  #pragma unroll
  for (int k = 0; k < 9; ++k) wn[k] = wT[k*128 + oc];   // ic = 0

  for (int ic = 0; ic < 64; ++ic) {
    float wk[9];
    #pragma unroll
    for (int k = 0; k < 9; ++k) wk[k] = wn[k];
    if (ic < 63) {
      #pragma unroll
      for (int k = 0; k < 9; ++k) wn[k] = wT[(size_t)((ic+1)*9 + k)*128 + oc];
    }
    float inr[48];
    #pragma unroll
    for (int j = 0; j < 6; ++j) {
      int g = rowbase + j;               // wave-uniform
      if (g >= 0 && g <= 7) {
        float4 v0 = *(const float4*)&is[ic*64 + g*8];
        float4 v1 = *(const float4*)&is[ic*64 + g*8 + 4];
        inr[j*8+0]=v0.x; inr[j*8+1]=v0.y; inr[j*8+2]=v0.z; inr[j*8+3]=v0.w;
        inr[j*8+4]=v1.x; inr[j*8+5]=v1.y; inr[j*8+6]=v1.z; inr[j*8+7]=v1.w;
      } else {
        #pragma unroll
        for (int q = 0; q < 8; ++q) inr[j*8+q] = 0.f;
      }
    }
    #pragma unroll
    for (int ky = -1; ky <= 1; ++ky)
      #pragma unroll
      for (int kx = -1; kx <= 1; ++kx) {
        float wkk = wk[(ky+1)*3 + (kx+1)];
        #pragma unroll
        for (int pyl = 0; pyl < 4; ++pyl) {
          const int ir = pyl + 1 + ky;
          #pragma unroll
          for (int px = 0; px < 8; ++px) {
            if (px+kx < 0 || px+kx > 7) continue;
            acc[pyl*8+px] = fmaf(wkk, inr[ir*8 + px+kx], acc[pyl*8+px]);
          }
        }
      }
  }
  const float bb = b[oc];
  #pragma unroll
  for (int pr = 0; pr < 2; ++pr)
    #pragma unroll
    for (int pc = 0; pc < 4; ++pc) {
      float v = fmaxf(fmaxf(acc[(2*pr)*8 + 2*pc],   acc[(2*pr)*8 + 2*pc+1]),
                      fmaxf(acc[(2*pr+1)*8 + 2*pc], acc[(2*pr+1)*8 + 2*pc+1]));
      outC[(size_t)img*2048 + (size_t)oc*16 + (h*2+pr)*4 + pc] = fmaxf(v + bb, 0.f);
    }
}

// ================= FC GEMM: [4096,2048] @ [2048,256], split-K=2, 64x64 tiles, 4x4 micro-tile
__global__ __launch_bounds__(256) void k_fc(const float* __restrict__ C,
    const float* __restrict__ fcw, float* __restrict__ P0, float* __restrict__ P1) {
  __shared__ float As[32][68];   // A^T tile: As[k][row], padded
  __shared__ float Bs[32][68];   // B tile:   Bs[k][col], padded
  const int t = threadIdx.x;
  const int r0 = blockIdx.x * 64;
  const int nc = blockIdx.y * 64;
  const int kbase = blockIdx.z * 1024;
  float* __restrict__ P = blockIdx.z ? P1 : P0;
  const int tx = t & 15, ty = t >> 4;
  float acc[4][4];
  #pragma unroll
  for (int i = 0; i < 4; ++i)
    #pragma unroll
    for (int j = 0; j < 4; ++j) acc[i][j] = 0.f;
  const int ia0 = t*2, ia1 = t*2 + 1;
  for (int c = 0; c < 32; ++c) {
    const int k0 = kbase + c*32;
    __syncthreads();
    #pragma unroll
    for (int j = 0; j < 2; ++j) {
      int idx = (j ? ia1 : ia0);
      int row = idx >> 3, kq = idx & 7;
      float4 v = *(const float4*)&C[(size_t)(r0+row)*2048 + k0 + kq*4];
      As[kq*4+0][row] = v.x; As[kq*4+1][row] = v.y;
      As[kq*4+2][row] = v.z; As[kq*4+3][row] = v.w;
    }
    #pragma unroll
    for (int j = 0; j < 2; ++j) {
      int idx = (j ? ia1 : ia0);
      int krow = idx >> 4, c4 = idx & 15;
      float4 v = *(const float4*)&fcw[(size_t)(k0+krow)*256 + nc + c4*4];
      *(float4*)&Bs[krow][c4*4] = v;
    }
    __syncthreads();
    #pragma unroll 8
    for (int k = 0; k < 32; ++k) {
      float4 av = *(const float4*)&As[k][ty*4];
      float4 bv = *(const float4*)&Bs[k][tx*4];
      float a[4] = {av.x, av.y, av.z, av.w};
      float bbv[4] = {bv.x, bv.y, bv.z, bv.w};
      #pragma unroll
      for (int i = 0; i < 4; ++i)
        #pragma unroll
        for (int j = 0; j < 4; ++j)
          acc[i][j] = fmaf(a[i], bbv[j], acc[i][j]);
    }
  }
  #pragma unroll
  for (int i = 0; i < 4; ++i) {
    float4 v = make_float4(acc[i][0], acc[i][1], acc[i][2], acc[i][3]);
    *(float4*)&P[(size_t)(r0 + ty*4 + i)*256 + nc + tx*4] = v;
  }
}

// ================= gate: feat = P0+P1+fcb; logits; top-2 softmax; expert lists
__global__ __launch_bounds__(256) void k_gate(const float* __restrict__ P0,
    const float* __restrict__ P1, const float* __restrict__ fcb,
    const float* __restrict__ gw, const float* __restrict__ gb,
    float* __restrict__ feat, int* __restrict__ cnt, float* __restrict__ gsum,
    int* __restrict__ lrow, float* __restrict__ lg) {
  __shared__ float ft[16][256];
  __shared__ float lgs[16][16];
  __shared__ float gwl[4096];
  const int t = threadIdx.x;
  const int r0 = blockIdx.x * 16;
  for (int i = t; i < 4096; i += 256) gwl[i] = gw[i];
  float bb = fcb[t];
  #pragma unroll
  for (int r = 0; r < 16; ++r) {
    size_t off = (size_t)(r0+r)*256 + t;
    float v = P0[off] + P1[off] + bb;
    ft[r][t] = v;
    feat[off] = v;
  }
  __syncthreads();
  {
    int r = t >> 4, e = t & 15;
    float s = gb[e];
    for (int k = 0; k < 256; ++k) s = fmaf(ft[r][k], gwl[k*16 + e], s);
    lgs[r][e] = s;
  }
  __syncthreads();
  if (t < 16) {
    int r = t;
    float v1 = -3.402823e38f, v2 = -3.402823e38f;
    int i1 = 0, i2 = 0;
    for (int e = 0; e < 16; ++e) {
      float v = lgs[r][e];
      if (v > v1)      { v2 = v1; i2 = i1; v1 = v; i1 = e; }
      else if (v > v2) { v2 = v;  i2 = e; }
    }
    float ex = __expf(v2 - v1);
    float g1 = 1.f / (1.f + ex);
    float g2 = ex  / (1.f + ex);
    int row = r0 + r;
    int p1 = atomicAdd(&cnt[i1], 1); lrow[i1*4096 + p1] = row; lg[i1*4096 + p1] = g1;
    int p2 = atomicAdd(&cnt[i2], 1); lrow[i2*4096 + p2] = row; lg[i2*4096 + p2] = g2;
    atomicAdd(&gsum[i1], g1);
    atomicAdd(&gsum[i2], g2);
  }
}

// ================= MoE: per-expert grouped rows, 16-row tiles, sparse top-2 (exact)
__global__ __launch_bounds__(256) void k_moe(const float* __restrict__ feat,
    const float* __restrict__ ew1, const float* __restrict__ eb1,
    const float* __restrict__ ew2, const float* __restrict__ eb2,
    const int* __restrict__ cnt, const int* __restrict__ lrow, const float* __restrict__ lgw,
    float* __restrict__ moe) {
  const int e = blockIdx.y;
  const int n_e = cnt[e];
  const int start = blockIdx.x * 16;
  if (start >= n_e) return;
  const int n = min(16, n_e - start);
  __shared__ float fs[16][256];
  __shared__ float t1[16][64];
  __shared__ int   rws[16];
  __shared__ float gws2[16];
  const int t = threadIdx.x;
  if (t < 16) {
    if (t < n) { rws[t] = lrow[e*4096 + start + t]; gws2[t] = lgw[e*4096 + start + t]; }
    else       { rws[t] = 0; gws2[t] = 0.f; }
  }
  __syncthreads();
  for (int i = t; i < 16*256; i += 256) {
    int r = i >> 8, k = i & 255;
    fs[r][k] = (r < n) ? feat[(size_t)rws[r]*256 + k] : 0.f;
  }
  float eo[16];
  #pragma unroll
  for (int r = 0; r < 16; ++r) eo[r] = 0.f;
  const float* w1 = ew1 + (size_t)e*262144;
  const float* w2 = ew2 + (size_t)e*262144;
  const int h = t & 63, rg = t >> 6;
  for (int hc = 0; hc < 1024; hc += 64) {
    float a[4];
    {
      float bb = eb1[e*1024 + hc + h];
      a[0]=bb; a[1]=bb; a[2]=bb; a[3]=bb;
    }
    __syncthreads();
    #pragma unroll 4
    for (int k = 0; k < 256; ++k) {
      float wv = w1[(size_t)k*1024 + hc + h];
      #pragma unroll
      for (int rr = 0; rr < 4; ++rr) a[rr] = fmaf(fs[rg*4 + rr][k], wv, a[rr]);
    }
    #pragma unroll
    for (int rr = 0; rr < 4; ++rr) t1[rg*4 + rr][h] = fmaxf(a[rr], 0.f);
    __syncthreads();
    #pragma unroll 4
    for (int hh = 0; hh < 64; ++hh) {
      float wv = w2[(size_t)(hc+hh)*256 + t];
      #pragma unroll
      for (int r = 0; r < 16; ++r) eo[r] = fmaf(t1[r][hh], wv, eo[r]);
    }
  }
  float b2 = eb2[e*256 + t];
  for (int r = 0; r < n; ++r)
    atomicAdd(&moe[(size_t)rws[r]*256 + t], gws2[r] * (eo[r] + b2));
}

// ================= load-balance loss
__global__ void k_lb(const float* __restrict__ gsum, float* __restrict__ out_lb) {
  int t = threadIdx.x;
  float term = 0.f;
  if (t < 16) {
    float D = gsum[t] * (1.f/4096.f);
    term = D * logf(D + 1e-8f);
  }
  #pragma unroll
  for (int o = 8; o > 0; o >>= 1) term += __shfl_down(term, o, 64);
  if (t == 0) *out_lb = term;
}

// ================= LayerNorm(moe + feat) in-place into moe
__global__ __launch_bounds__(256) void k_ln(const float* __restrict__ feat,
    float* __restrict__ moe, const float* __restrict__ g, const float* __restrict__ bp) {
  const int r = blockIdx.x, t = threadIdx.x;
  float v = moe[(size_t)r*256 + t] + feat[(size_t)r*256 + t];
  float s = v, q = v * v;
  #pragma unroll
  for (int o = 32; o > 0; o >>= 1) {
    s += __shfl_down(s, o, 64);
    q += __shfl_down(q, o, 64);
  }
  __shared__ float ss[4], qq[4];
  int wv = t >> 6;
  if ((t & 63) == 0) { ss[wv] = s; qq[wv] = q; }
  __syncthreads();
  float S = ss[0]+ss[1]+ss[2]+ss[3];
  float Q = qq[0]+qq[1]+qq[2]+qq[3];
  float mu  = S * (1.f/256.f);
  float var = Q * (1.f/256.f) - mu*mu;
  float inv = rsqrtf(var + 1e-5f);
  moe[(size_t)r*256 + t] = (v - mu) * inv * g[t] + bp[t];
}

// ================= output GEMM: [4096,256] @ [256,1000] + b
__global__ __launch_bounds__(256) void k_out(const float* __restrict__ y,
    const float* __restrict__ ow, const float* __restrict__ ob,
    float* __restrict__ out) {
  __shared__ float ys[32][256];
  const int t = threadIdx.x;
  const int r0 = blockIdx.x * 32;
  const int c = blockIdx.y * 256 + t;
  for (int i = t; i < 32*256; i += 256) {
    int r = i >> 8, k = i & 255;
    ys[r][k] = y[(size_t)(r0+r)*256 + k];
  }
  __syncthreads();
  if (c >= NCLS) return;
  float acc[32];
  {
    float bb = ob[c];
    #pragma unroll
    for (int r = 0; r < 32; ++r) acc[r] = bb;
  }
  #pragma unroll 4
  for (int k = 0; k < 256; ++k) {
    float wv = ow[(size_t)k*NCLS + c];
    #pragma unroll
    for (int r = 0; r < 32; ++r) acc[r] = fmaf(ys[r][k], wv, acc[r]);
  }
  for (int r = 0; r < 32; ++r) out[(size_t)(r0+r)*NCLS + c] = acc[r];
}

// ================= launch =================
extern "C" void kernel_launch(void* const* d_in, const int* in_sizes, int n_in,
                              void* d_out, int out_size, void* d_ws, size_t ws_size,
                              hipStream_t stream) {
  const float* x   = (const float*)d_in[0];
  const float* c1w = (const float*)d_in[1];
  const float* c1b = (const float*)d_in[2];
  const float* c2w = (const float*)d_in[3];
  const float* c2b = (const float*)d_in[4];
  const float* c3w = (const float*)d_in[5];
  const float* c3b = (const float*)d_in[6];
  const float* fcw = (const float*)d_in[7];
  const float* fcb = (const float*)d_in[8];
  const float* gw  = (const float*)d_in[9];
  const float* gb  = (const float*)d_in[10];
  const float* ew1 = (const float*)d_in[11];
  const float* eb1 = (const float*)d_in[12];
  const float* ew2 = (const float*)d_in[13];
  const float* eb2 = (const float*)d_in[14];
  const float* lng = (const float*)d_in[15];
  const float* lnb = (const float*)d_in[16];
  const float* ow  = (const float*)d_in[17];
  const float* ob  = (const float*)d_in[18];
  char* ws = (char*)d_ws;
  float* Bb   = (float*)(ws + OFF_B);
  float* P0   = (float*)(ws + OFF_P0);   // aliases Bb (dead after conv3)
  float* P1   = (float*)(ws + OFF_P1);
  float* C    = (float*)(ws + OFF_C);
  float* wT2  = (float*)(ws + OFF_C);    // aliases C (C written after conv12)
  float* wT3  = (float*)(ws + OFF_FEAT); // aliases feat (feat written after conv3)
  float* feat = (float*)(ws + OFF_FEAT);
  float* moe  = (float*)(ws + OFF_MOE);
  int*   cnt  = (int*)(ws + OFF_CNT);
  float* gsum = (float*)(ws + OFF_GSUM);
  int*   lrow = (int*)(ws + OFF_LROW);
  float* lgv  = (float*)(ws + OFF_LG);
  float* outp = (float*)d_out;

  // zero moe accumulator + counts + gate sums (contiguous region)
  hipMemsetAsync(ws + OFF_MOE, 0, 4194304 + 128, stream);

  hipLaunchKernelGGL(k_wt2,    dim3(72),      dim3(256), 0, stream, c2w, wT2);
  hipLaunchKernelGGL(k_conv12, dim3(4096),    dim3(512), 0, stream, x, c1w, c1b, wT2, c2b, Bb);
  hipLaunchKernelGGL(k_wt3,    dim3(288),     dim3(256), 0, stream, c3w, wT3);
  hipLaunchKernelGGL(k_conv3,  dim3(4096),    dim3(256), 0, stream, Bb, wT3, c3b, C);
  hipLaunchKernelGGL(k_fc,     dim3(64, 4, 2),dim3(256), 0, stream, C, fcw, P0, P1);
  hipLaunchKernelGGL(k_gate,   dim3(256),     dim3(256), 0, stream, P0, P1, fcb, gw, gb,
                     feat, cnt, gsum, lrow, lgv);
  hipLaunchKernelGGL(k_moe,    dim3(256, 16), dim3(256), 0, stream, feat, ew1, eb1, ew2, eb2,
                     cnt, lrow, lgv, moe);
  hipLaunchKernelGGL(k_lb,     dim3(1),       dim3(64),  0, stream, gsum, outp + (size_t)NB*NCLS);
  hipLaunchKernelGGL(k_ln,     dim3(4096),    dim3(256), 0, stream, feat, moe, lng, lnb);
  hipLaunchKernelGGL(k_out,    dim3(128, 4),  dim3(256), 0, stream, moe, ow, ob, outp);
}

// Round 7
// 1617.195 us; speedup vs baseline: 2.1772x; 1.2214x over previous
//
#include <hip/hip_runtime.h>
#include <hip/hip_bf16.h>

typedef short bf16x8 __attribute__((ext_vector_type(8)));
typedef float f32x4 __attribute__((ext_vector_type(4)));

// ---------------- problem sizes ----------------
#define NB   4096
#define NEXP 16
#define DDIM 256
#define HDIM 1024
#define NCLS 1000

// ---------------- workspace layout (bytes) ----------------
#define OFF_B    ((size_t)0)
#define OFF_P0   ((size_t)0)           // f32 [4096][256] FC partial (K half 0)
#define OFF_P1   ((size_t)4194304)     // f32 [4096][256] FC partial (K half 1)
#define OFF_C    ((size_t)67108864)    // conv3 out f32 [4096][2048]; ALSO wT2 (74 KB) before conv12
#define OFF_FEAT ((size_t)100663296)   // f32 [4096][256]; ALSO wAh/wAl (288 KB) before k_gate
#define OFF_WAL  ((size_t)100810752)   // OFF_FEAT + 147456
#define OFF_MOE  ((size_t)104857600)   // f32 [4096][256]
#define OFF_CNT  ((size_t)109051904)   // int [16]
#define OFF_GSUM ((size_t)109051968)   // f32 [16]
#define OFF_LROW ((size_t)109052032)   // int [16][4096]
#define OFF_LG   ((size_t)109314176)   // f32 [16][4096]

__device__ inline unsigned short f2bf(float v) {
  __hip_bfloat16 h = __float2bfloat16(v);
  return *(unsigned short*)&h;
}
__device__ inline float bf2f(unsigned short u) {
  union { unsigned int i; float f; } c; c.i = ((unsigned int)u) << 16; return c.f;
}

// ================= weight transpose for conv2: w[oc][ic][k] -> wT2[(ic*9+k)*64 + oc]
__global__ __launch_bounds__(256) void k_wt2(const float* __restrict__ w, float* __restrict__ wT) {
  int i = blockIdx.x*256 + threadIdx.x;   // i over 32*9*64 = 18432
  if (i >= 32*9*64) return;
  int oc = i & 63, rem = i >> 6;          // rem = ic*9 + k
  int k = rem % 9, ic = rem / 9;
  wT[i] = w[(oc*32 + ic)*9 + k];
}

// ================= fused conv1+conv2 per image (conv2 lane=oc, VGPR weights) ====
__global__ __launch_bounds__(512) void k_conv12(const float* __restrict__ x,
    const float* __restrict__ w1, const float* __restrict__ b1,
    const float* __restrict__ wT2, const float* __restrict__ b2,
    float* __restrict__ outB) {
  __shared__ float xs[3][34][36];     // padded input image (14.7 KB)
  __shared__ float as[32][18][20];    // padded conv1 pooled output (46 KB); reused for store stage
  __shared__ float ws1[864];
  __shared__ float bs1[32];
  __shared__ float bs2[64];
  const int t = threadIdx.x;
  const int img = blockIdx.x;
  for (int i = t; i < 3*34*36; i += 512) ((float*)xs)[i] = 0.f;
  for (int i = t; i < 32*18*20; i += 512) ((float*)as)[i] = 0.f;
  __syncthreads();
  for (int i = t; i < 3072; i += 512) {
    int ic = i >> 10, rem = i & 1023, y = rem >> 5, xx = rem & 31;
    xs[ic][y+1][xx+1] = x[(size_t)img*3072 + i];
  }
  for (int i = t; i < 864; i += 512) ws1[i] = w1[i];
  if (t < 32) bs1[t] = b1[t];
  else if (t >= 64 && t < 128) bs2[t-64] = b2[t-64];
  __syncthreads();
  // ---- conv1 + pool + relu -> as interior (thread = pixel x 16 ocs) ----
  {
    const int p = t & 255, grp = t >> 8;
    const int px = p & 15, py = p >> 4;
    float win[3][4][4];
    #pragma unroll
    for (int ic = 0; ic < 3; ++ic)
      #pragma unroll
      for (int r = 0; r < 4; ++r) {
        float2 a  = *(const float2*)&xs[ic][2*py+r][2*px];
        float2 c2 = *(const float2*)&xs[ic][2*py+r][2*px+2];
        win[ic][r][0]=a.x; win[ic][r][1]=a.y; win[ic][r][2]=c2.x; win[ic][r][3]=c2.y;
      }
    for (int occ = grp*16; occ < grp*16 + 16; occ += 8) {
      float acc[8][4];
      #pragma unroll
      for (int j = 0; j < 8; ++j) { float bb = bs1[occ+j]; acc[j][0]=bb;acc[j][1]=bb;acc[j][2]=bb;acc[j][3]=bb; }
      #pragma unroll
      for (int ic = 0; ic < 3; ++ic) {
        #pragma unroll
        for (int j = 0; j < 8; ++j) {
          const float* wp = &ws1[(occ+j)*27 + ic*9];
          float wv[9];
          #pragma unroll
          for (int q = 0; q < 9; ++q) wv[q] = wp[q];   // wave-uniform broadcast
          #pragma unroll
          for (int ry = 0; ry < 2; ++ry)
            #pragma unroll
            for (int rx = 0; rx < 2; ++rx) {
              float s = acc[j][ry*2+rx];
              #pragma unroll
              for (int ky = 0; ky < 3; ++ky)
                #pragma unroll
                for (int kx = 0; kx < 3; ++kx)
                  s = fmaf(wv[ky*3+kx], win[ic][ry+ky][rx+kx], s);
              acc[j][ry*2+rx] = s;
            }
        }
      }
      #pragma unroll
      for (int j = 0; j < 8; ++j) {
        float m = fmaxf(fmaxf(acc[j][0],acc[j][1]), fmaxf(acc[j][2],acc[j][3]));
        as[occ+j][py+1][px+1] = fmaxf(m, 0.f);
      }
    }
  }
  __syncthreads();
  // ---- conv2 (lane=oc, wave=row-pair) + pool + relu -> LDS stage -> coalesced store ----
  {
    const int lane = t & 63, wv = t >> 6;
    float acc[32];
    #pragma unroll
    for (int i = 0; i < 32; ++i) acc[i] = 0.f;
    float wn[9];
    #pragma unroll
    for (int k = 0; k < 9; ++k) wn[k] = wT2[k*64 + lane];   // ic = 0
    for (int ic = 0; ic < 32; ++ic) {
      float wk[9];
      #pragma unroll
      for (int k = 0; k < 9; ++k) wk[k] = wn[k];
      if (ic < 31) {
        #pragma unroll
        for (int k = 0; k < 9; ++k) wn[k] = wT2[((ic+1)*9 + k)*64 + lane];
      }
      float inr[72];
      #pragma unroll
      for (int j = 0; j < 4; ++j) {
        const float* rp = &as[ic][2*wv + j][0];
        float4 a0 = *(const float4*)rp;
        float4 a1 = *(const float4*)(rp+4);
        float4 a2 = *(const float4*)(rp+8);
        float4 a3 = *(const float4*)(rp+12);
        float2 a4 = *(const float2*)(rp+16);
        inr[j*18+0]=a0.x;  inr[j*18+1]=a0.y;  inr[j*18+2]=a0.z;  inr[j*18+3]=a0.w;
        inr[j*18+4]=a1.x;  inr[j*18+5]=a1.y;  inr[j*18+6]=a1.z;  inr[j*18+7]=a1.w;
        inr[j*18+8]=a2.x;  inr[j*18+9]=a2.y;  inr[j*18+10]=a2.z; inr[j*18+11]=a2.w;
        inr[j*18+12]=a3.x; inr[j*18+13]=a3.y; inr[j*18+14]=a3.z; inr[j*18+15]=a3.w;
        inr[j*18+16]=a4.x; inr[j*18+17]=a4.y;
      }
      #pragma unroll
      for (int ky = 0; ky < 3; ++ky)
        #pragma unroll
        for (int kx = 0; kx < 3; ++kx) {
          float wkk = wk[ky*3+kx];
          #pragma unroll
          for (int pr = 0; pr < 2; ++pr)
            #pragma unroll
            for (int c = 0; c < 16; ++c)
              acc[pr*16+c] = fmaf(wkk, inr[(pr+ky)*18 + c+kx], acc[pr*16+c]);
        }
    }
    __syncthreads();
    float* pool_s = &as[0][0][0];   // [64 oc][65] padded
    const float bb = bs2[lane];
    #pragma unroll
    for (int pc = 0; pc < 8; ++pc) {
      float v = fmaxf(fmaxf(acc[2*pc], acc[2*pc+1]),
                      fmaxf(acc[16+2*pc], acc[16+2*pc+1]));
      pool_s[lane*65 + wv*8 + pc] = fmaxf(v + bb, 0.f);
    }
    __syncthreads();
    const float* ps = pool_s;
    float* op = outB + (size_t)img*4096;
    #pragma unroll
    for (int j = 0; j < 8; ++j) {
      int i = j*512 + t;
      op[i] = ps[(i >> 6)*65 + (i & 63)];
    }
  }
}

// ================= conv3 weight prep: c3w[oc][ic][tap] -> wAh/wAl[tap][oc][ic] bf16 hi/lo
__global__ __launch_bounds__(256) void k_wt3b(const float* __restrict__ w,
    unsigned short* __restrict__ wAh, unsigned short* __restrict__ wAl) {
  int i = blockIdx.x*256 + threadIdx.x;   // over 9*128*64 = 73728
  if (i >= 9*128*64) return;
  int ic = i & 63, rem = i >> 6;
  int oc = rem & 127, tap = rem >> 7;
  float v = w[(oc*64 + ic)*9 + tap];
  unsigned short h = f2bf(v);
  wAh[i] = h;
  wAl[i] = f2bf(v - bf2f(h));
}

// ================= conv3 v4: bf16x2 split MFMA implicit GEMM ==================
// Per image: D[oc=128][pix=64] = sum over 9 taps x 64 ic, via mfma_f32_16x16x32_bf16.
// A = weights [tap][oc][ic] (hi/lo, 16B/lane global loads); B = shifted input from
// LDS [10][10][64ic] bf16 hi/lo with 16B-slot XOR swizzle (2-way bank = free).
// 4 waves: wave owns 2 oc-tiles x 4 pixel-tiles. (ah+al)x(bh+bl) all 4 terms -> ~2^-18 error.
__global__ __launch_bounds__(256) void k_conv3(const float* __restrict__ inB,
    const unsigned short* __restrict__ wAh, const unsigned short* __restrict__ wAl,
    const float* __restrict__ bias, float* __restrict__ outC) {
  __shared__ unsigned short ish[2][6400];   // [hi/lo][(py*10+px)*64+ic, swizzled] 25.6 KB
  const int t = threadIdx.x;
  const int img = blockIdx.x;
  // zero both arrays (6400 u32 total)
  {
    unsigned int* z = (unsigned int*)&ish[0][0];
    #pragma unroll
    for (int j = 0; j < 25; ++j) z[t + 256*j] = 0u;
  }
  __syncthreads();
  // fill interior hi/lo (4096 elems, 16/thread), swizzled
  {
    const float* src = inB + (size_t)img*4096;
    #pragma unroll
    for (int j = 0; j < 16; ++j) {
      int f = t + 256*j;                 // f = ic*64 + p
      int ic = f >> 6, p = f & 63;
      int pl = ((p >> 3) + 1)*10 + (p & 7) + 1;   // padded pixel index
      float v = src[f];
      unsigned short h = f2bf(v);
      unsigned short l = f2bf(v - bf2f(h));
      int u = pl*64 + ic;
      int us = (((u >> 3) ^ (pl & 7)) << 3) | (u & 7);
      ish[0][us] = h; ish[1][us] = l;
    }
  }
  __syncthreads();

  const int lane = t & 63, wid = t >> 6;
  const int lr = lane & 15, lq = lane >> 4;
  const int mt0 = wid*2;                 // this wave's oc tiles: mt0, mt0+1
  const int yb = lr >> 3, xb = lr & 7;   // B-side pixel within tile: y=2nt+yb, x=xb

  f32x4 acc[2][4];
  #pragma unroll
  for (int i = 0; i < 2; ++i)
    #pragma unroll
    for (int j = 0; j < 4; ++j) acc[i][j] = (f32x4){0.f,0.f,0.f,0.f};

  for (int tap = 0; tap < 9; ++tap) {
    const int dy = tap/3, dx = tap - dy*3;
    #pragma unroll
    for (int kc = 0; kc < 2; ++kc) {
      const int kb = kc*32 + lq*8;       // ic base for this lane
      const int wbase = ((tap << 7) << 6) + kb;   // tap*128*64 + kb
      bf16x8 a0h = *(const bf16x8*)&wAh[wbase + ((mt0*16 + lr) << 6)];
      bf16x8 a0l = *(const bf16x8*)&wAl[wbase + ((mt0*16 + lr) << 6)];
      bf16x8 a1h = *(const bf16x8*)&wAh[wbase + (((mt0+1)*16 + lr) << 6)];
      bf16x8 a1l = *(const bf16x8*)&wAl[wbase + (((mt0+1)*16 + lr) << 6)];
      #pragma unroll
      for (int nt = 0; nt < 4; ++nt) {
        const int pl = (2*nt + yb + dy)*10 + xb + dx;   // padded pixel
        const int u = pl*64 + kb;
        const int us = (((u >> 3) ^ (pl & 7)) << 3);    // (u&7)==0
        bf16x8 bh = *(const bf16x8*)&ish[0][us];
        bf16x8 bl = *(const bf16x8*)&ish[1][us];
        acc[0][nt] = __builtin_amdgcn_mfma_f32_16x16x32_bf16(a0h, bh, acc[0][nt], 0, 0, 0);
        acc[0][nt] = __builtin_amdgcn_mfma_f32_16x16x32_bf16(a0h, bl, acc[0][nt], 0, 0, 0);
        acc[0][nt] = __builtin_amdgcn_mfma_f32_16x16x32_bf16(a0l, bh, acc[0][nt], 0, 0, 0);
        acc[0][nt] = __builtin_amdgcn_mfma_f32_16x16x32_bf16(a0l, bl, acc[0][nt], 0, 0, 0);
        acc[1][nt] = __builtin_amdgcn_mfma_f32_16x16x32_bf16(a1h, bh, acc[1][nt], 0, 0, 0);
        acc[1][nt] = __builtin_amdgcn_mfma_f32_16x16x32_bf16(a1h, bl, acc[1][nt], 0, 0, 0);
        acc[1][nt] = __builtin_amdgcn_mfma_f32_16x16x32_bf16(a1l, bh, acc[1][nt], 0, 0, 0);
        acc[1][nt] = __builtin_amdgcn_mfma_f32_16x16x32_bf16(a1l, bl, acc[1][nt], 0, 0, 0);
      }
    }
  }
  __syncthreads();   // done reading ish -> reuse as output stage
  float* stg = (float*)&ish[0][0];   // [128 oc][17]
  // pool 2x2 across lanes (x-pair lane^1, y-pair lane^8), bias, relu
  #pragma unroll
  for (int mtl = 0; mtl < 2; ++mtl)
    #pragma unroll
    for (int nt = 0; nt < 4; ++nt)
      #pragma unroll
      for (int r = 0; r < 4; ++r) {
        float v = acc[mtl][nt][r];
        v = fmaxf(v, __shfl_xor(v, 1, 64));
        v = fmaxf(v, __shfl_xor(v, 8, 64));
        if ((lane & 9) == 0) {
          int oc = (mt0 + mtl)*16 + lq*4 + r;        // C/D: row=(lane>>4)*4+reg
          int pix = nt*4 + (xb >> 1);                // pooled row=nt, col=x/2
          stg[oc*17 + pix] = fmaxf(v + bias[oc], 0.f);
        }
      }
  __syncthreads();
  float* dst = outC + (size_t)img*2048;
  #pragma unroll
  for (int j = 0; j < 8; ++j) {
    int i = t + 256*j;
    dst[i] = stg[(i >> 4)*17 + (i & 15)];
  }
}

// ================= FC GEMM: [4096,2048] @ [2048,256], split-K=2, 64x64 tiles, 4x4 micro-tile
__global__ __launch_bounds__(256) void k_fc(const float* __restrict__ C,
    const float* __restrict__ fcw, float* __restrict__ P0, float* __restrict__ P1) {
  __shared__ float As[32][68];
  __shared__ float Bs[32][68];
  const int t = threadIdx.x;
  const int r0 = blockIdx.x * 64;
  const int nc = blockIdx.y * 64;
  const int kbase = blockIdx.z * 1024;
  float* __restrict__ P = blockIdx.z ? P1 : P0;
  const int tx = t & 15, ty = t >> 4;
  float acc[4][4];
  #pragma unroll
  for (int i = 0; i < 4; ++i)
    #pragma unroll
    for (int j = 0; j < 4; ++j) acc[i][j] = 0.f;
  const int ia0 = t*2, ia1 = t*2 + 1;
  for (int c = 0; c < 32; ++c) {
    const int k0 = kbase + c*32;
    __syncthreads();
    #pragma unroll
    for (int j = 0; j < 2; ++j) {
      int idx = (j ? ia1 : ia0);
      int row = idx >> 3, kq = idx & 7;
      float4 v = *(const float4*)&C[(size_t)(r0+row)*2048 + k0 + kq*4];
      As[kq*4+0][row] = v.x; As[kq*4+1][row] = v.y;
      As[kq*4+2][row] = v.z; As[kq*4+3][row] = v.w;
    }
    #pragma unroll
    for (int j = 0; j < 2; ++j) {
      int idx = (j ? ia1 : ia0);
      int krow = idx >> 4, c4 = idx & 15;
      float4 v = *(const float4*)&fcw[(size_t)(k0+krow)*256 + nc + c4*4];
      *(float4*)&Bs[krow][c4*4] = v;
    }
    __syncthreads();
    #pragma unroll 8
    for (int k = 0; k < 32; ++k) {
      float4 av = *(const float4*)&As[k][ty*4];
      float4 bv = *(const float4*)&Bs[k][tx*4];
      float a[4] = {av.x, av.y, av.z, av.w};
      float bbv[4] = {bv.x, bv.y, bv.z, bv.w};
      #pragma unroll
      for (int i = 0; i < 4; ++i)
        #pragma unroll
        for (int j = 0; j < 4; ++j)
          acc[i][j] = fmaf(a[i], bbv[j], acc[i][j]);
    }
  }
  #pragma unroll
  for (int i = 0; i < 4; ++i) {
    float4 v = make_float4(acc[i][0], acc[i][1], acc[i][2], acc[i][3]);
    *(float4*)&P[(size_t)(r0 + ty*4 + i)*256 + nc + tx*4] = v;
  }
}

// ================= gate: feat = P0+P1+fcb; logits; top-2 softmax; expert lists
__global__ __launch_bounds__(256) void k_gate(const float* __restrict__ P0,
    const float* __restrict__ P1, const float* __restrict__ fcb,
    const float* __restrict__ gw, const float* __restrict__ gb,
    float* __restrict__ feat, int* __restrict__ cnt, float* __restrict__ gsum,
    int* __restrict__ lrow, float* __restrict__ lg) {
  __shared__ float ft[16][256];
  __shared__ float lgs[16][16];
  __shared__ float gwl[4096];
  const int t = threadIdx.x;
  const int r0 = blockIdx.x * 16;
  for (int i = t; i < 4096; i += 256) gwl[i] = gw[i];
  float bb = fcb[t];
  #pragma unroll
  for (int r = 0; r < 16; ++r) {
    size_t off = (size_t)(r0+r)*256 + t;
    float v = P0[off] + P1[off] + bb;
    ft[r][t] = v;
    feat[off] = v;
  }
  __syncthreads();
  {
    int r = t >> 4, e = t & 15;
    float s = gb[e];
    for (int k = 0; k < 256; ++k) s = fmaf(ft[r][k], gwl[k*16 + e], s);
    lgs[r][e] = s;
  }
  __syncthreads();
  if (t < 16) {
    int r = t;
    float v1 = -3.402823e38f, v2 = -3.402823e38f;
    int i1 = 0, i2 = 0;
    for (int e = 0; e < 16; ++e) {
      float v = lgs[r][e];
      if (v > v1)      { v2 = v1; i2 = i1; v1 = v; i1 = e; }
      else if (v > v2) { v2 = v;  i2 = e; }
    }
    float ex = __expf(v2 - v1);
    float g1 = 1.f / (1.f + ex);
    float g2 = ex  / (1.f + ex);
    int row = r0 + r;
    int p1 = atomicAdd(&cnt[i1], 1); lrow[i1*4096 + p1] = row; lg[i1*4096 + p1] = g1;
    int p2 = atomicAdd(&cnt[i2], 1); lrow[i2*4096 + p2] = row; lg[i2*4096 + p2] = g2;
    atomicAdd(&gsum[i1], g1);
    atomicAdd(&gsum[i2], g2);
  }
}

// ================= MoE: per-expert grouped rows, 16-row tiles, sparse top-2 (exact)
__global__ __launch_bounds__(256) void k_moe(const float* __restrict__ feat,
    const float* __restrict__ ew1, const float* __restrict__ eb1,
    const float* __restrict__ ew2, const float* __restrict__ eb2,
    const int* __restrict__ cnt, const int* __restrict__ lrow, const float* __restrict__ lgw,
    float* __restrict__ moe) {
  const int e = blockIdx.y;
  const int n_e = cnt[e];
  const int start = blockIdx.x * 16;
  if (start >= n_e) return;
  const int n = min(16, n_e - start);
  __shared__ float fs[16][256];
  __shared__ float t1[16][64];
  __shared__ int   rws[16];
  __shared__ float gws2[16];
  const int t = threadIdx.x;
  if (t < 16) {
    if (t < n) { rws[t] = lrow[e*4096 + start + t]; gws2[t] = lgw[e*4096 + start + t]; }
    else       { rws[t] = 0; gws2[t] = 0.f; }
  }
  __syncthreads();
  for (int i = t; i < 16*256; i += 256) {
    int r = i >> 8, k = i & 255;
    fs[r][k] = (r < n) ? feat[(size_t)rws[r]*256 + k] : 0.f;
  }
  float eo[16];
  #pragma unroll
  for (int r = 0; r < 16; ++r) eo[r] = 0.f;
  const float* w1 = ew1 + (size_t)e*262144;
  const float* w2 = ew2 + (size_t)e*262144;
  const int h = t & 63, rg = t >> 6;
  for (int hc = 0; hc < 1024; hc += 64) {
    float a[4];
    {
      float bb = eb1[e*1024 + hc + h];
      a[0]=bb; a[1]=bb; a[2]=bb; a[3]=bb;
    }
    __syncthreads();
    #pragma unroll 4
    for (int k = 0; k < 256; ++k) {
      float wv = w1[(size_t)k*1024 + hc + h];
      #pragma unroll
      for (int rr = 0; rr < 4; ++rr) a[rr] = fmaf(fs[rg*4 + rr][k], wv, a[rr]);
    }
    #pragma unroll
    for (int rr = 0; rr < 4; ++rr) t1[rg*4 + rr][h] = fmaxf(a[rr], 0.f);
    __syncthreads();
    #pragma unroll 4
    for (int hh = 0; hh < 64; ++hh) {
      float wv = w2[(size_t)(hc+hh)*256 + t];
      #pragma unroll
      for (int r = 0; r < 16; ++r) eo[r] = fmaf(t1[r][hh], wv, eo[r]);
    }
  }
  float b2 = eb2[e*256 + t];
  for (int r = 0; r < n; ++r)
    atomicAdd(&moe[(size_t)rws[r]*256 + t], gws2[r] * (eo[r] + b2));
}

// ================= load-balance loss
__global__ void k_lb(const float* __restrict__ gsum, float* __restrict__ out_lb) {
  int t = threadIdx.x;
  float term = 0.f;
  if (t < 16) {
    float D = gsum[t] * (1.f/4096.f);
    term = D * logf(D + 1e-8f);
  }
  #pragma unroll
  for (int o = 8; o > 0; o >>= 1) term += __shfl_down(term, o, 64);
  if (t == 0) *out_lb = term;
}

// ================= LayerNorm(moe + feat) in-place into moe
__global__ __launch_bounds__(256) void k_ln(const float* __restrict__ feat,
    float* __restrict__ moe, const float* __restrict__ g, const float* __restrict__ bp) {
  const int r = blockIdx.x, t = threadIdx.x;
  float v = moe[(size_t)r*256 + t] + feat[(size_t)r*256 + t];
  float s = v, q = v * v;
  #pragma unroll
  for (int o = 32; o > 0; o >>= 1) {
    s += __shfl_down(s, o, 64);
    q += __shfl_down(q, o, 64);
  }
  __shared__ float ss[4], qq[4];
  int wv = t >> 6;
  if ((t & 63) == 0) { ss[wv] = s; qq[wv] = q; }
  __syncthreads();
  float S = ss[0]+ss[1]+ss[2]+ss[3];
  float Q = qq[0]+qq[1]+qq[2]+qq[3];
  float mu  = S * (1.f/256.f);
  float var = Q * (1.f/256.f) - mu*mu;
  float inv = rsqrtf(var + 1e-5f);
  moe[(size_t)r*256 + t] = (v - mu) * inv * g[t] + bp[t];
}

// ================= output GEMM: [4096,256] @ [256,1000] + b
__global__ __launch_bounds__(256) void k_out(const float* __restrict__ y,
    const float* __restrict__ ow, const float* __restrict__ ob,
    float* __restrict__ out) {
  __shared__ float ys[32][256];
  const int t = threadIdx.x;
  const int r0 = blockIdx.x * 32;
  const int c = blockIdx.y * 256 + t;
  for (int i = t; i < 32*256; i += 256) {
    int r = i >> 8, k = i & 255;
    ys[r][k] = y[(size_t)(r0+r)*256 + k];
  }
  __syncthreads();
  if (c >= NCLS) return;
  float acc[32];
  {
    float bb = ob[c];
    #pragma unroll
    for (int r = 0; r < 32; ++r) acc[r] = bb;
  }
  #pragma unroll 4
  for (int k = 0; k < 256; ++k) {
    float wv = ow[(size_t)k*NCLS + c];
    #pragma unroll
    for (int r = 0; r < 32; ++r) acc[r] = fmaf(ys[r][k], wv, acc[r]);
  }
  for (int r = 0; r < 32; ++r) out[(size_t)(r0+r)*NCLS + c] = acc[r];
}

// ================= launch =================
extern "C" void kernel_launch(void* const* d_in, const int* in_sizes, int n_in,
                              void* d_out, int out_size, void* d_ws, size_t ws_size,
                              hipStream_t stream) {
  const float* x   = (const float*)d_in[0];
  const float* c1w = (const float*)d_in[1];
  const float* c1b = (const float*)d_in[2];
  const float* c2w = (const float*)d_in[3];
  const float* c2b = (const float*)d_in[4];
  const float* c3w = (const float*)d_in[5];
  const float* c3b = (const float*)d_in[6];
  const float* fcw = (const float*)d_in[7];
  const float* fcb = (const float*)d_in[8];
  const float* gw  = (const float*)d_in[9];
  const float* gb  = (const float*)d_in[10];
  const float* ew1 = (const float*)d_in[11];
  const float* eb1 = (const float*)d_in[12];
  const float* ew2 = (const float*)d_in[13];
  const float* eb2 = (const float*)d_in[14];
  const float* lng = (const float*)d_in[15];
  const float* lnb = (const float*)d_in[16];
  const float* ow  = (const float*)d_in[17];
  const float* ob  = (const float*)d_in[18];
  char* ws = (char*)d_ws;
  float* Bb   = (float*)(ws + OFF_B);
  float* P0   = (float*)(ws + OFF_P0);
  float* P1   = (float*)(ws + OFF_P1);
  float* C    = (float*)(ws + OFF_C);
  float* wT2  = (float*)(ws + OFF_C);      // aliases C (C written after conv12)
  unsigned short* wAh = (unsigned short*)(ws + OFF_FEAT);  // aliases feat (written later)
  unsigned short* wAl = (unsigned short*)(ws + OFF_WAL);
  float* feat = (float*)(ws + OFF_FEAT);
  float* moe  = (float*)(ws + OFF_MOE);
  int*   cnt  = (int*)(ws + OFF_CNT);
  float* gsum = (float*)(ws + OFF_GSUM);
  int*   lrow = (int*)(ws + OFF_LROW);
  float* lgv  = (float*)(ws + OFF_LG);
  float* outp = (float*)d_out;

  hipMemsetAsync(ws + OFF_MOE, 0, 4194304 + 128, stream);

  hipLaunchKernelGGL(k_wt2,    dim3(72),      dim3(256), 0, stream, c2w, wT2);
  hipLaunchKernelGGL(k_wt3b,   dim3(288),     dim3(256), 0, stream, c3w, wAh, wAl);
  hipLaunchKernelGGL(k_conv12, dim3(4096),    dim3(512), 0, stream, x, c1w, c1b, wT2, c2b, Bb);
  hipLaunchKernelGGL(k_conv3,  dim3(4096),    dim3(256), 0, stream, Bb, wAh, wAl, c3b, C);
  hipLaunchKernelGGL(k_fc,     dim3(64, 4, 2),dim3(256), 0, stream, C, fcw, P0, P1);
  hipLaunchKernelGGL(k_gate,   dim3(256),     dim3(256), 0, stream, P0, P1, fcb, gw, gb,
                     feat, cnt, gsum, lrow, lgv);
  hipLaunchKernelGGL(k_moe,    dim3(256, 16), dim3(256), 0, stream, feat, ew1, eb1, ew2, eb2,
                     cnt, lrow, lgv, moe);
  hipLaunchKernelGGL(k_lb,     dim3(1),       dim3(64),  0, stream, gsum, outp + (size_t)NB*NCLS);
  hipLaunchKernelGGL(k_ln,     dim3(4096),    dim3(256), 0, stream, feat, moe, lng, lnb);
  hipLaunchKernelGGL(k_out,    dim3(128, 4),  dim3(256), 0, stream, moe, ow, ob, outp);
}

// Round 8
// 1160.863 us; speedup vs baseline: 3.0330x; 1.3931x over previous
//
#include <hip/hip_runtime.h>
#include <hip/hip_bf16.h>

typedef short bf16x8 __attribute__((ext_vector_type(8)));
typedef float f32x4 __attribute__((ext_vector_type(4)));

// ---------------- problem sizes ----------------
#define NB   4096
#define NEXP 16
#define DDIM 256
#define HDIM 1024
#define NCLS 1000

// ---------------- workspace layout (bytes) ----------------
#define OFF_B    ((size_t)0)
#define OFF_P0   ((size_t)0)           // f32 [4096][256] FC partial (K half 0)
#define OFF_P1   ((size_t)4194304)     // f32 [4096][256] FC partial (K half 1)
#define OFF_C    ((size_t)67108864)    // conv3 out f32 [4096][2048]; ALSO wBh/wBl (74 KB) before conv12
#define OFF_WBL  ((size_t)67145728)    // OFF_C + 36864
#define OFF_FEAT ((size_t)100663296)   // f32 [4096][256]; ALSO wAh/wAl (288 KB) before k_gate
#define OFF_WAL  ((size_t)100810752)   // OFF_FEAT + 147456
#define OFF_MOE  ((size_t)104857600)   // f32 [4096][256]
#define OFF_CNT  ((size_t)109051904)   // int [16]
#define OFF_GSUM ((size_t)109051968)   // f32 [16]
#define OFF_LROW ((size_t)109052032)   // int [16][4096]
#define OFF_LG   ((size_t)109314176)   // f32 [16][4096]

__device__ inline unsigned short f2bf(float v) {
  __hip_bfloat16 h = __float2bfloat16(v);
  return *(unsigned short*)&h;
}
__device__ inline float bf2f(unsigned short u) {
  union { unsigned int i; float f; } c; c.i = ((unsigned int)u) << 16; return c.f;
}

// ====== conv2 weight prep: c2w[oc][ic][tap] -> wBh/wBl[tap][oc][ic] bf16 hi/lo ======
__global__ __launch_bounds__(256) void k_wt2b(const float* __restrict__ w,
    unsigned short* __restrict__ wBh, unsigned short* __restrict__ wBl) {
  int i = blockIdx.x*256 + threadIdx.x;   // over 9*64*32 = 18432
  if (i >= 9*64*32) return;
  int ic = i & 31, rem = i >> 5;
  int oc = rem & 63, tap = rem >> 6;
  float v = w[(oc*32 + ic)*9 + tap];
  unsigned short h = f2bf(v);
  wBh[i] = h;
  wBl[i] = f2bf(v - bf2f(h));
}

// ================= fused conv1(vector) + conv2(bf16x2 MFMA) per image =================
// conv1 -> pooled relu output written as bf16 hi/lo into swizzled LDS [18*18 pad][32 ic].
// conv2: D[64 oc][256 pix] = sum over 9 taps (K=32 ic each) via mfma_f32_16x16x32_bf16.
// 8 waves = 2 oc-tile-pairs x 4 row-quads; A prefetched 1 tap ahead from L2.
__global__ __launch_bounds__(512, 4) void k_conv12(const float* __restrict__ x,
    const float* __restrict__ w1, const float* __restrict__ b1,
    const unsigned short* __restrict__ wBh, const unsigned short* __restrict__ wBl,
    const float* __restrict__ b2, float* __restrict__ outB) {
  __shared__ float xs[3][34][36];           // padded input image (14.7 KB)
  __shared__ unsigned short ishB[2][10368]; // [hi/lo][pl*32+ic swizzled] (41.5 KB); reused for store stage
  __shared__ float ws1[864];
  __shared__ float bs1[32];
  __shared__ float bs2[64];
  const int t = threadIdx.x;
  const int img = blockIdx.x;
  for (int i = t; i < 3*34*36; i += 512) ((float*)xs)[i] = 0.f;
  {
    unsigned int* z = (unsigned int*)&ishB[0][0];
    for (int i = t; i < 10368; i += 512) z[i] = 0u;
  }
  __syncthreads();
  for (int i = t; i < 3072; i += 512) {
    int ic = i >> 10, rem = i & 1023, y = rem >> 5, xx = rem & 31;
    xs[ic][y+1][xx+1] = x[(size_t)img*3072 + i];
  }
  for (int i = t; i < 864; i += 512) ws1[i] = w1[i];
  if (t < 32) bs1[t] = b1[t];
  else if (t >= 64 && t < 128) bs2[t-64] = b2[t-64];
  __syncthreads();
  // ---- conv1 + pool + relu -> ishB hi/lo swizzled (thread = pixel x 16 ocs) ----
  {
    const int p = t & 255, grp = t >> 8;
    const int px = p & 15, py = p >> 4;
    const int pl = (py+1)*18 + (px+1);      // padded pixel index
    float win[3][4][4];
    #pragma unroll
    for (int ic = 0; ic < 3; ++ic)
      #pragma unroll
      for (int r = 0; r < 4; ++r) {
        float2 a  = *(const float2*)&xs[ic][2*py+r][2*px];
        float2 c2 = *(const float2*)&xs[ic][2*py+r][2*px+2];
        win[ic][r][0]=a.x; win[ic][r][1]=a.y; win[ic][r][2]=c2.x; win[ic][r][3]=c2.y;
      }
    for (int occ = grp*16; occ < grp*16 + 16; occ += 8) {
      float acc[8][4];
      #pragma unroll
      for (int j = 0; j < 8; ++j) { float bb = bs1[occ+j]; acc[j][0]=bb;acc[j][1]=bb;acc[j][2]=bb;acc[j][3]=bb; }
      #pragma unroll
      for (int ic = 0; ic < 3; ++ic) {
        #pragma unroll
        for (int j = 0; j < 8; ++j) {
          const float* wp = &ws1[(occ+j)*27 + ic*9];
          float wv[9];
          #pragma unroll
          for (int q = 0; q < 9; ++q) wv[q] = wp[q];   // wave-uniform broadcast
          #pragma unroll
          for (int ry = 0; ry < 2; ++ry)
            #pragma unroll
            for (int rx = 0; rx < 2; ++rx) {
              float s = acc[j][ry*2+rx];
              #pragma unroll
              for (int ky = 0; ky < 3; ++ky)
                #pragma unroll
                for (int kx = 0; kx < 3; ++kx)
                  s = fmaf(wv[ky*3+kx], win[ic][ry+ky][rx+kx], s);
              acc[j][ry*2+rx] = s;
            }
        }
      }
      #pragma unroll
      for (int j = 0; j < 8; ++j) {
        float m = fmaxf(fmaxf(acc[j][0],acc[j][1]), fmaxf(acc[j][2],acc[j][3]));
        m = fmaxf(m, 0.f);
        unsigned short h = f2bf(m);
        unsigned short l = f2bf(m - bf2f(h));
        int ic2 = occ + j;
        int sl = pl*4 + ((ic2 >> 3) ^ ((pl >> 1) & 3));
        int us = (sl << 3) | (ic2 & 7);
        ishB[0][us] = h; ishB[1][us] = l;
      }
    }
  }
  __syncthreads();
  // ---- conv2 bf16x2 MFMA + fused pool + relu ----
  {
    const int lane = t & 63, wvv = t >> 6;
    const int lr = lane & 15, lq = lane >> 4;
    const int mtp = (wvv & 1)*2;     // oc tiles mtp, mtp+1
    const int rq = wvv >> 1;         // rows rq*4 .. rq*4+3
    f32x4 acc[2][4];
    #pragma unroll
    for (int i = 0; i < 2; ++i)
      #pragma unroll
      for (int j = 0; j < 4; ++j) acc[i][j] = (f32x4){0.f,0.f,0.f,0.f};
    bf16x8 nAh[2], nAl[2];
    #pragma unroll
    for (int m = 0; m < 2; ++m) {
      int off = (((mtp+m)*16 + lr) << 5) + lq*8;     // tap 0
      nAh[m] = *(const bf16x8*)&wBh[off];
      nAl[m] = *(const bf16x8*)&wBl[off];
    }
    #pragma unroll
    for (int tap = 0; tap < 9; ++tap) {
      bf16x8 ah0 = nAh[0], al0 = nAl[0], ah1 = nAh[1], al1 = nAl[1];
      if (tap < 8) {
        #pragma unroll
        for (int m = 0; m < 2; ++m) {
          int off = (((tap+1)*64 + (mtp+m)*16 + lr) << 5) + lq*8;
          nAh[m] = *(const bf16x8*)&wBh[off];
          nAl[m] = *(const bf16x8*)&wBl[off];
        }
      }
      const int dy = tap/3, dx = tap - dy*3;
      #pragma unroll
      for (int j = 0; j < 4; ++j) {
        int pl = (rq*4 + j + dy)*18 + lr + dx;
        int sl = pl*4 + (lq ^ ((pl >> 1) & 3));
        bf16x8 bh = *(const bf16x8*)&ishB[0][sl << 3];
        bf16x8 bl = *(const bf16x8*)&ishB[1][sl << 3];
        acc[0][j] = __builtin_amdgcn_mfma_f32_16x16x32_bf16(ah0, bh, acc[0][j], 0, 0, 0);
        acc[1][j] = __builtin_amdgcn_mfma_f32_16x16x32_bf16(ah1, bh, acc[1][j], 0, 0, 0);
        acc[0][j] = __builtin_amdgcn_mfma_f32_16x16x32_bf16(ah0, bl, acc[0][j], 0, 0, 0);
        acc[1][j] = __builtin_amdgcn_mfma_f32_16x16x32_bf16(ah1, bl, acc[1][j], 0, 0, 0);
        acc[0][j] = __builtin_amdgcn_mfma_f32_16x16x32_bf16(al0, bh, acc[0][j], 0, 0, 0);
        acc[1][j] = __builtin_amdgcn_mfma_f32_16x16x32_bf16(al1, bh, acc[1][j], 0, 0, 0);
        acc[0][j] = __builtin_amdgcn_mfma_f32_16x16x32_bf16(al0, bl, acc[0][j], 0, 0, 0);
        acc[1][j] = __builtin_amdgcn_mfma_f32_16x16x32_bf16(al1, bl, acc[1][j], 0, 0, 0);
      }
    }
    __syncthreads();   // done reading ishB -> reuse as output stage
    float* ps = (float*)&ishB[0][0];   // [64 oc][65] padded
    #pragma unroll
    for (int m = 0; m < 2; ++m)
      #pragma unroll
      for (int k = 0; k < 2; ++k)
        #pragma unroll
        for (int r = 0; r < 4; ++r) {
          float v = fmaxf(acc[m][2*k][r], acc[m][2*k+1][r]);   // row pair (same lane)
          v = fmaxf(v, __shfl_xor(v, 1, 64));                  // col pair
          if ((lr & 1) == 0) {
            int oc = (mtp + m)*16 + lq*4 + r;    // C/D: row=(lane>>4)*4+reg
            int Y = rq*2 + k, X = lr >> 1;
            ps[oc*65 + Y*8 + X] = fmaxf(v + bs2[oc], 0.f);
          }
        }
    __syncthreads();
    float* op = outB + (size_t)img*4096;
    #pragma unroll
    for (int jj = 0; jj < 8; ++jj) {
      int i = jj*512 + t;
      op[i] = ps[(i >> 6)*65 + (i & 63)];
    }
  }
}

// ================= conv3 weight prep: c3w[oc][ic][tap] -> wAh/wAl[tap][oc][ic] bf16 hi/lo
__global__ __launch_bounds__(256) void k_wt3b(const float* __restrict__ w,
    unsigned short* __restrict__ wAh, unsigned short* __restrict__ wAl) {
  int i = blockIdx.x*256 + threadIdx.x;   // over 9*128*64 = 73728
  if (i >= 9*128*64) return;
  int ic = i & 63, rem = i >> 6;
  int oc = rem & 127, tap = rem >> 7;
  float v = w[(oc*64 + ic)*9 + tap];
  unsigned short h = f2bf(v);
  wAh[i] = h;
  wAl[i] = f2bf(v - bf2f(h));
}

// ================= conv3 v4: bf16x2 split MFMA implicit GEMM ==================
__global__ __launch_bounds__(256) void k_conv3(const float* __restrict__ inB,
    const unsigned short* __restrict__ wAh, const unsigned short* __restrict__ wAl,
    const float* __restrict__ bias, float* __restrict__ outC) {
  __shared__ unsigned short ish[2][6400];   // [hi/lo][(py*10+px)*64+ic, swizzled] 25.6 KB
  const int t = threadIdx.x;
  const int img = blockIdx.x;
  {
    unsigned int* z = (unsigned int*)&ish[0][0];
    #pragma unroll
    for (int j = 0; j < 25; ++j) z[t + 256*j] = 0u;
  }
  __syncthreads();
  {
    const float* src = inB + (size_t)img*4096;
    #pragma unroll
    for (int j = 0; j < 16; ++j) {
      int f = t + 256*j;                 // f = ic*64 + p
      int ic = f >> 6, p = f & 63;
      int pl = ((p >> 3) + 1)*10 + (p & 7) + 1;
      float v = src[f];
      unsigned short h = f2bf(v);
      unsigned short l = f2bf(v - bf2f(h));
      int u = pl*64 + ic;
      int us = (((u >> 3) ^ (pl & 7)) << 3) | (u & 7);
      ish[0][us] = h; ish[1][us] = l;
    }
  }
  __syncthreads();

  const int lane = t & 63, wid = t >> 6;
  const int lr = lane & 15, lq = lane >> 4;
  const int mt0 = wid*2;
  const int yb = lr >> 3, xb = lr & 7;

  f32x4 acc[2][4];
  #pragma unroll
  for (int i = 0; i < 2; ++i)
    #pragma unroll
    for (int j = 0; j < 4; ++j) acc[i][j] = (f32x4){0.f,0.f,0.f,0.f};

  for (int tap = 0; tap < 9; ++tap) {
    const int dy = tap/3, dx = tap - dy*3;
    #pragma unroll
    for (int kc = 0; kc < 2; ++kc) {
      const int kb = kc*32 + lq*8;
      const int wbase = ((tap << 7) << 6) + kb;
      bf16x8 a0h = *(const bf16x8*)&wAh[wbase + ((mt0*16 + lr) << 6)];
      bf16x8 a0l = *(const bf16x8*)&wAl[wbase + ((mt0*16 + lr) << 6)];
      bf16x8 a1h = *(const bf16x8*)&wAh[wbase + (((mt0+1)*16 + lr) << 6)];
      bf16x8 a1l = *(const bf16x8*)&wAl[wbase + (((mt0+1)*16 + lr) << 6)];
      #pragma unroll
      for (int nt = 0; nt < 4; ++nt) {
        const int pl = (2*nt + yb + dy)*10 + xb + dx;
        const int u = pl*64 + kb;
        const int us = (((u >> 3) ^ (pl & 7)) << 3);
        bf16x8 bh = *(const bf16x8*)&ish[0][us];
        bf16x8 bl = *(const bf16x8*)&ish[1][us];
        acc[0][nt] = __builtin_amdgcn_mfma_f32_16x16x32_bf16(a0h, bh, acc[0][nt], 0, 0, 0);
        acc[0][nt] = __builtin_amdgcn_mfma_f32_16x16x32_bf16(a0h, bl, acc[0][nt], 0, 0, 0);
        acc[0][nt] = __builtin_amdgcn_mfma_f32_16x16x32_bf16(a0l, bh, acc[0][nt], 0, 0, 0);
        acc[0][nt] = __builtin_amdgcn_mfma_f32_16x16x32_bf16(a0l, bl, acc[0][nt], 0, 0, 0);
        acc[1][nt] = __builtin_amdgcn_mfma_f32_16x16x32_bf16(a1h, bh, acc[1][nt], 0, 0, 0);
        acc[1][nt] = __builtin_amdgcn_mfma_f32_16x16x32_bf16(a1h, bl, acc[1][nt], 0, 0, 0);
        acc[1][nt] = __builtin_amdgcn_mfma_f32_16x16x32_bf16(a1l, bh, acc[1][nt], 0, 0, 0);
        acc[1][nt] = __builtin_amdgcn_mfma_f32_16x16x32_bf16(a1l, bl, acc[1][nt], 0, 0, 0);
      }
    }
  }
  __syncthreads();
  float* stg = (float*)&ish[0][0];   // [128 oc][17]
  #pragma unroll
  for (int mtl = 0; mtl < 2; ++mtl)
    #pragma unroll
    for (int nt = 0; nt < 4; ++nt)
      #pragma unroll
      for (int r = 0; r < 4; ++r) {
        float v = acc[mtl][nt][r];
        v = fmaxf(v, __shfl_xor(v, 1, 64));
        v = fmaxf(v, __shfl_xor(v, 8, 64));
        if ((lane & 9) == 0) {
          int oc = (mt0 + mtl)*16 + lq*4 + r;
          int pix = nt*4 + (xb >> 1);
          stg[oc*17 + pix] = fmaxf(v + bias[oc], 0.f);
        }
      }
  __syncthreads();
  float* dst = outC + (size_t)img*2048;
  #pragma unroll
  for (int j = 0; j < 8; ++j) {
    int i = t + 256*j;
    dst[i] = stg[(i >> 4)*17 + (i & 15)];
  }
}

// ================= FC GEMM: [4096,2048] @ [2048,256], split-K=2, 64x64 tiles, 4x4 micro-tile
__global__ __launch_bounds__(256) void k_fc(const float* __restrict__ C,
    const float* __restrict__ fcw, float* __restrict__ P0, float* __restrict__ P1) {
  __shared__ float As[32][68];
  __shared__ float Bs[32][68];
  const int t = threadIdx.x;
  const int r0 = blockIdx.x * 64;
  const int nc = blockIdx.y * 64;
  const int kbase = blockIdx.z * 1024;
  float* __restrict__ P = blockIdx.z ? P1 : P0;
  const int tx = t & 15, ty = t >> 4;
  float acc[4][4];
  #pragma unroll
  for (int i = 0; i < 4; ++i)
    #pragma unroll
    for (int j = 0; j < 4; ++j) acc[i][j] = 0.f;
  const int ia0 = t*2, ia1 = t*2 + 1;
  for (int c = 0; c < 32; ++c) {
    const int k0 = kbase + c*32;
    __syncthreads();
    #pragma unroll
    for (int j = 0; j < 2; ++j) {
      int idx = (j ? ia1 : ia0);
      int row = idx >> 3, kq = idx & 7;
      float4 v = *(const float4*)&C[(size_t)(r0+row)*2048 + k0 + kq*4];
      As[kq*4+0][row] = v.x; As[kq*4+1][row] = v.y;
      As[kq*4+2][row] = v.z; As[kq*4+3][row] = v.w;
    }
    #pragma unroll
    for (int j = 0; j < 2; ++j) {
      int idx = (j ? ia1 : ia0);
      int krow = idx >> 4, c4 = idx & 15;
      float4 v = *(const float4*)&fcw[(size_t)(k0+krow)*256 + nc + c4*4];
      *(float4*)&Bs[krow][c4*4] = v;
    }
    __syncthreads();
    #pragma unroll 8
    for (int k = 0; k < 32; ++k) {
      float4 av = *(const float4*)&As[k][ty*4];
      float4 bv = *(const float4*)&Bs[k][tx*4];
      float a[4] = {av.x, av.y, av.z, av.w};
      float bbv[4] = {bv.x, bv.y, bv.z, bv.w};
      #pragma unroll
      for (int i = 0; i < 4; ++i)
        #pragma unroll
        for (int j = 0; j < 4; ++j)
          acc[i][j] = fmaf(a[i], bbv[j], acc[i][j]);
    }
  }
  #pragma unroll
  for (int i = 0; i < 4; ++i) {
    float4 v = make_float4(acc[i][0], acc[i][1], acc[i][2], acc[i][3]);
    *(float4*)&P[(size_t)(r0 + ty*4 + i)*256 + nc + tx*4] = v;
  }
}

// ================= gate: feat = P0+P1+fcb; logits; top-2 softmax; expert lists
__global__ __launch_bounds__(256) void k_gate(const float* __restrict__ P0,
    const float* __restrict__ P1, const float* __restrict__ fcb,
    const float* __restrict__ gw, const float* __restrict__ gb,
    float* __restrict__ feat, int* __restrict__ cnt, float* __restrict__ gsum,
    int* __restrict__ lrow, float* __restrict__ lg) {
  __shared__ float ft[16][256];
  __shared__ float lgs[16][16];
  __shared__ float gwl[4096];
  const int t = threadIdx.x;
  const int r0 = blockIdx.x * 16;
  for (int i = t; i < 4096; i += 256) gwl[i] = gw[i];
  float bb = fcb[t];
  #pragma unroll
  for (int r = 0; r < 16; ++r) {
    size_t off = (size_t)(r0+r)*256 + t;
    float v = P0[off] + P1[off] + bb;
    ft[r][t] = v;
    feat[off] = v;
  }
  __syncthreads();
  {
    int r = t >> 4, e = t & 15;
    float s = gb[e];
    for (int k = 0; k < 256; ++k) s = fmaf(ft[r][k], gwl[k*16 + e], s);
    lgs[r][e] = s;
  }
  __syncthreads();
  if (t < 16) {
    int r = t;
    float v1 = -3.402823e38f, v2 = -3.402823e38f;
    int i1 = 0, i2 = 0;
    for (int e = 0; e < 16; ++e) {
      float v = lgs[r][e];
      if (v > v1)      { v2 = v1; i2 = i1; v1 = v; i1 = e; }
      else if (v > v2) { v2 = v;  i2 = e; }
    }
    float ex = __expf(v2 - v1);
    float g1 = 1.f / (1.f + ex);
    float g2 = ex  / (1.f + ex);
    int row = r0 + r;
    int p1 = atomicAdd(&cnt[i1], 1); lrow[i1*4096 + p1] = row; lg[i1*4096 + p1] = g1;
    int p2 = atomicAdd(&cnt[i2], 1); lrow[i2*4096 + p2] = row; lg[i2*4096 + p2] = g2;
    atomicAdd(&gsum[i1], g1);
    atomicAdd(&gsum[i2], g2);
  }
}

// ================= MoE: per-expert grouped rows, 16-row tiles, sparse top-2 (exact)
__global__ __launch_bounds__(256) void k_moe(const float* __restrict__ feat,
    const float* __restrict__ ew1, const float* __restrict__ eb1,
    const float* __restrict__ ew2, const float* __restrict__ eb2,
    const int* __restrict__ cnt, const int* __restrict__ lrow, const float* __restrict__ lgw,
    float* __restrict__ moe) {
  const int e = blockIdx.y;
  const int n_e = cnt[e];
  const int start = blockIdx.x * 16;
  if (start >= n_e) return;
  const int n = min(16, n_e - start);
  __shared__ float fs[16][256];
  __shared__ float t1[16][64];
  __shared__ int   rws[16];
  __shared__ float gws2[16];
  const int t = threadIdx.x;
  if (t < 16) {
    if (t < n) { rws[t] = lrow[e*4096 + start + t]; gws2[t] = lgw[e*4096 + start + t]; }
    else       { rws[t] = 0; gws2[t] = 0.f; }
  }
  __syncthreads();
  for (int i = t; i < 16*256; i += 256) {
    int r = i >> 8, k = i & 255;
    fs[r][k] = (r < n) ? feat[(size_t)rws[r]*256 + k] : 0.f;
  }
  float eo[16];
  #pragma unroll
  for (int r = 0; r < 16; ++r) eo[r] = 0.f;
  const float* w1 = ew1 + (size_t)e*262144;
  const float* w2 = ew2 + (size_t)e*262144;
  const int h = t & 63, rg = t >> 6;
  for (int hc = 0; hc < 1024; hc += 64) {
    float a[4];
    {
      float bb = eb1[e*1024 + hc + h];
      a[0]=bb; a[1]=bb; a[2]=bb; a[3]=bb;
    }
    __syncthreads();
    #pragma unroll 4
    for (int k = 0; k < 256; ++k) {
      float wv = w1[(size_t)k*1024 + hc + h];
      #pragma unroll
      for (int rr = 0; rr < 4; ++rr) a[rr] = fmaf(fs[rg*4 + rr][k], wv, a[rr]);
    }
    #pragma unroll
    for (int rr = 0; rr < 4; ++rr) t1[rg*4 + rr][h] = fmaxf(a[rr], 0.f);
    __syncthreads();
    #pragma unroll 4
    for (int hh = 0; hh < 64; ++hh) {
      float wv = w2[(size_t)(hc+hh)*256 + t];
      #pragma unroll
      for (int r = 0; r < 16; ++r) eo[r] = fmaf(t1[r][hh], wv, eo[r]);
    }
  }
  float b2 = eb2[e*256 + t];
  for (int r = 0; r < n; ++r)
    atomicAdd(&moe[(size_t)rws[r]*256 + t], gws2[r] * (eo[r] + b2));
}

// ================= load-balance loss
__global__ void k_lb(const float* __restrict__ gsum, float* __restrict__ out_lb) {
  int t = threadIdx.x;
  float term = 0.f;
  if (t < 16) {
    float D = gsum[t] * (1.f/4096.f);
    term = D * logf(D + 1e-8f);
  }
  #pragma unroll
  for (int o = 8; o > 0; o >>= 1) term += __shfl_down(term, o, 64);
  if (t == 0) *out_lb = term;
}

// ================= LayerNorm(moe + feat) in-place into moe
__global__ __launch_bounds__(256) void k_ln(const float* __restrict__ feat,
    float* __restrict__ moe, const float* __restrict__ g, const float* __restrict__ bp) {
  const int r = blockIdx.x, t = threadIdx.x;
  float v = moe[(size_t)r*256 + t] + feat[(size_t)r*256 + t];
  float s = v, q = v * v;
  #pragma unroll
  for (int o = 32; o > 0; o >>= 1) {
    s += __shfl_down(s, o, 64);
    q += __shfl_down(q, o, 64);
  }
  __shared__ float ss[4], qq[4];
  int wv = t >> 6;
  if ((t & 63) == 0) { ss[wv] = s; qq[wv] = q; }
  __syncthreads();
  float S = ss[0]+ss[1]+ss[2]+ss[3];
  float Q = qq[0]+qq[1]+qq[2]+qq[3];
  float mu  = S * (1.f/256.f);
  float var = Q * (1.f/256.f) - mu*mu;
  float inv = rsqrtf(var + 1e-5f);
  moe[(size_t)r*256 + t] = (v - mu) * inv * g[t] + bp[t];
}

// ================= output GEMM: [4096,256] @ [256,1000] + b
__global__ __launch_bounds__(256) void k_out(const float* __restrict__ y,
    const float* __restrict__ ow, const float* __restrict__ ob,
    float* __restrict__ out) {
  __shared__ float ys[32][256];
  const int t = threadIdx.x;
  const int r0 = blockIdx.x * 32;
  const int c = blockIdx.y * 256 + t;
  for (int i = t; i < 32*256; i += 256) {
    int r = i >> 8, k = i & 255;
    ys[r][k] = y[(size_t)(r0+r)*256 + k];
  }
  __syncthreads();
  if (c >= NCLS) return;
  float acc[32];
  {
    float bb = ob[c];
    #pragma unroll
    for (int r = 0; r < 32; ++r) acc[r] = bb;
  }
  #pragma unroll 4
  for (int k = 0; k < 256; ++k) {
    float wv = ow[(size_t)k*NCLS + c];
    #pragma unroll
    for (int r = 0; r < 32; ++r) acc[r] = fmaf(ys[r][k], wv, acc[r]);
  }
  for (int r = 0; r < 32; ++r) out[(size_t)(r0+r)*NCLS + c] = acc[r];
}

// ================= launch =================
extern "C" void kernel_launch(void* const* d_in, const int* in_sizes, int n_in,
                              void* d_out, int out_size, void* d_ws, size_t ws_size,
                              hipStream_t stream) {
  const float* x   = (const float*)d_in[0];
  const float* c1w = (const float*)d_in[1];
  const float* c1b = (const float*)d_in[2];
  const float* c2w = (const float*)d_in[3];
  const float* c2b = (const float*)d_in[4];
  const float* c3w = (const float*)d_in[5];
  const float* c3b = (const float*)d_in[6];
  const float* fcw = (const float*)d_in[7];
  const float* fcb = (const float*)d_in[8];
  const float* gw  = (const float*)d_in[9];
  const float* gb  = (const float*)d_in[10];
  const float* ew1 = (const float*)d_in[11];
  const float* eb1 = (const float*)d_in[12];
  const float* ew2 = (const float*)d_in[13];
  const float* eb2 = (const float*)d_in[14];
  const float* lng = (const float*)d_in[15];
  const float* lnb = (const float*)d_in[16];
  const float* ow  = (const float*)d_in[17];
  const float* ob  = (const float*)d_in[18];
  char* ws = (char*)d_ws;
  float* Bb   = (float*)(ws + OFF_B);
  float* P0   = (float*)(ws + OFF_P0);
  float* P1   = (float*)(ws + OFF_P1);
  float* C    = (float*)(ws + OFF_C);
  unsigned short* wBh = (unsigned short*)(ws + OFF_C);     // aliases C (C written after conv12)
  unsigned short* wBl = (unsigned short*)(ws + OFF_WBL);
  unsigned short* wAh = (unsigned short*)(ws + OFF_FEAT);  // aliases feat (written later)
  unsigned short* wAl = (unsigned short*)(ws + OFF_WAL);
  float* feat = (float*)(ws + OFF_FEAT);
  float* moe  = (float*)(ws + OFF_MOE);
  int*   cnt  = (int*)(ws + OFF_CNT);
  float* gsum = (float*)(ws + OFF_GSUM);
  int*   lrow = (int*)(ws + OFF_LROW);
  float* lgv  = (float*)(ws + OFF_LG);
  float* outp = (float*)d_out;

  hipMemsetAsync(ws + OFF_MOE, 0, 4194304 + 128, stream);

  hipLaunchKernelGGL(k_wt2b,   dim3(72),      dim3(256), 0, stream, c2w, wBh, wBl);
  hipLaunchKernelGGL(k_wt3b,   dim3(288),     dim3(256), 0, stream, c3w, wAh, wAl);
  hipLaunchKernelGGL(k_conv12, dim3(4096),    dim3(512), 0, stream, x, c1w, c1b, wBh, wBl, c2b, Bb);
  hipLaunchKernelGGL(k_conv3,  dim3(4096),    dim3(256), 0, stream, Bb, wAh, wAl, c3b, C);
  hipLaunchKernelGGL(k_fc,     dim3(64, 4, 2),dim3(256), 0, stream, C, fcw, P0, P1);
  hipLaunchKernelGGL(k_gate,   dim3(256),     dim3(256), 0, stream, P0, P1, fcb, gw, gb,
                     feat, cnt, gsum, lrow, lgv);
  hipLaunchKernelGGL(k_moe,    dim3(256, 16), dim3(256), 0, stream, feat, ew1, eb1, ew2, eb2,
                     cnt, lrow, lgv, moe);
  hipLaunchKernelGGL(k_lb,     dim3(1),       dim3(64),  0, stream, gsum, outp + (size_t)NB*NCLS);
  hipLaunchKernelGGL(k_ln,     dim3(4096),    dim3(256), 0, stream, feat, moe, lng, lnb);
  hipLaunchKernelGGL(k_out,    dim3(128, 4),  dim3(256), 0, stream, moe, ow, ob, outp);
}

// Round 9
// 947.998 us; speedup vs baseline: 3.7141x; 1.2245x over previous
//
#include <hip/hip_runtime.h>
#include <hip/hip_bf16.h>

typedef short bf16x8 __attribute__((ext_vector_type(8)));
typedef float f32x4 __attribute__((ext_vector_type(4)));

// ---------------- problem sizes ----------------
#define NB   4096
#define NEXP 16
#define DDIM 256
#define HDIM 1024
#define NCLS 1000

// ---------------- workspace layout (bytes) ----------------
#define OFF_B    ((size_t)0)
#define OFF_P0   ((size_t)0)           // f32 [4096][256] FC partial (K half 0)
#define OFF_P1   ((size_t)4194304)     // f32 [4096][256] FC partial (K half 1)
// MoE transposed/split weights (written after conv3, when Bb is dead; after P0/P1):
#define OFF_W1TH ((size_t)8388608)     // bf16 [16][1024 h][256 k]  8 MB
#define OFF_W1TL ((size_t)16777216)
#define OFF_W2TH ((size_t)25165824)    // bf16 [16][256 d][1024 h]  8 MB
#define OFF_W2TL ((size_t)33554432)
#define OFF_C    ((size_t)67108864)    // conv3 out f32 [4096][2048]; ALSO wBh/wBl (74 KB) before conv12
#define OFF_WBL  ((size_t)67145728)    // OFF_C + 36864
#define OFF_FEAT ((size_t)100663296)   // f32 [4096][256]; ALSO wAh/wAl (288 KB) before k_gate
#define OFF_WAL  ((size_t)100810752)   // OFF_FEAT + 147456
#define OFF_MOE  ((size_t)104857600)   // f32 [4096][256]
#define OFF_CNT  ((size_t)109051904)   // int [16]
#define OFF_GSUM ((size_t)109051968)   // f32 [16]
#define OFF_LROW ((size_t)109052032)   // int [16][4096]
#define OFF_LG   ((size_t)109314176)   // f32 [16][4096]

__device__ inline unsigned short f2bf(float v) {
  __hip_bfloat16 h = __float2bfloat16(v);
  return *(unsigned short*)&h;
}
__device__ inline float bf2f(unsigned short u) {
  union { unsigned int i; float f; } c; c.i = ((unsigned int)u) << 16; return c.f;
}

// ====== conv2 weight prep: c2w[oc][ic][tap] -> wBh/wBl[tap][oc][ic] bf16 hi/lo ======
__global__ __launch_bounds__(256) void k_wt2b(const float* __restrict__ w,
    unsigned short* __restrict__ wBh, unsigned short* __restrict__ wBl) {
  int i = blockIdx.x*256 + threadIdx.x;   // over 9*64*32 = 18432
  if (i >= 9*64*32) return;
  int ic = i & 31, rem = i >> 5;
  int oc = rem & 63, tap = rem >> 6;
  float v = w[(oc*32 + ic)*9 + tap];
  unsigned short h = f2bf(v);
  wBh[i] = h;
  wBl[i] = f2bf(v - bf2f(h));
}

// ====== generic per-expert transpose + bf16 hi/lo split: in[e][R][C] -> out[e][C][R]
__global__ __launch_bounds__(256) void k_tsp(const float* __restrict__ in,
    unsigned short* __restrict__ oh, unsigned short* __restrict__ ol, int R, int C) {
  __shared__ float tile[64][65];
  const int t = threadIdx.x;
  const int e = blockIdx.z;
  const size_t eb = (size_t)e * R * C;
  const int c0 = blockIdx.x*64, r0 = blockIdx.y*64;
  const int cc = t & 63, r4 = t >> 6;
  #pragma unroll
  for (int j = 0; j < 16; ++j) {
    int rr = r4 + j*4;
    tile[rr][cc] = in[eb + (size_t)(r0+rr)*C + c0 + cc];
  }
  __syncthreads();
  #pragma unroll
  for (int j = 0; j < 16; ++j) {
    int oc2 = r4 + j*4;
    float v = tile[cc][oc2];
    unsigned short h = f2bf(v);
    size_t o = eb + (size_t)(c0+oc2)*R + r0 + cc;
    oh[o] = h;
    ol[o] = f2bf(v - bf2f(h));
  }
}

// ================= fused conv1(vector) + conv2(bf16x2 MFMA) per image =================
__global__ __launch_bounds__(512, 4) void k_conv12(const float* __restrict__ x,
    const float* __restrict__ w1, const float* __restrict__ b1,
    const unsigned short* __restrict__ wBh, const unsigned short* __restrict__ wBl,
    const float* __restrict__ b2, float* __restrict__ outB) {
  __shared__ float xs[3][34][36];           // padded input image (14.7 KB)
  __shared__ unsigned short ishB[2][10368]; // [hi/lo][pl*32+ic swizzled] (41.5 KB); reused for store stage
  __shared__ float ws1[864];
  __shared__ float bs1[32];
  __shared__ float bs2[64];
  const int t = threadIdx.x;
  const int img = blockIdx.x;
  for (int i = t; i < 3*34*36; i += 512) ((float*)xs)[i] = 0.f;
  {
    unsigned int* z = (unsigned int*)&ishB[0][0];
    for (int i = t; i < 10368; i += 512) z[i] = 0u;
  }
  __syncthreads();
  for (int i = t; i < 3072; i += 512) {
    int ic = i >> 10, rem = i & 1023, y = rem >> 5, xx = rem & 31;
    xs[ic][y+1][xx+1] = x[(size_t)img*3072 + i];
  }
  for (int i = t; i < 864; i += 512) ws1[i] = w1[i];
  if (t < 32) bs1[t] = b1[t];
  else if (t >= 64 && t < 128) bs2[t-64] = b2[t-64];
  __syncthreads();
  // ---- conv1 + pool + relu -> ishB hi/lo swizzled ----
  {
    const int p = t & 255, grp = t >> 8;
    const int px = p & 15, py = p >> 4;
    const int pl = (py+1)*18 + (px+1);
    float win[3][4][4];
    #pragma unroll
    for (int ic = 0; ic < 3; ++ic)
      #pragma unroll
      for (int r = 0; r < 4; ++r) {
        float2 a  = *(const float2*)&xs[ic][2*py+r][2*px];
        float2 c2 = *(const float2*)&xs[ic][2*py+r][2*px+2];
        win[ic][r][0]=a.x; win[ic][r][1]=a.y; win[ic][r][2]=c2.x; win[ic][r][3]=c2.y;
      }
    for (int occ = grp*16; occ < grp*16 + 16; occ += 8) {
      float acc[8][4];
      #pragma unroll
      for (int j = 0; j < 8; ++j) { float bb = bs1[occ+j]; acc[j][0]=bb;acc[j][1]=bb;acc[j][2]=bb;acc[j][3]=bb; }
      #pragma unroll
      for (int ic = 0; ic < 3; ++ic) {
        #pragma unroll
        for (int j = 0; j < 8; ++j) {
          const float* wp = &ws1[(occ+j)*27 + ic*9];
          float wv[9];
          #pragma unroll
          for (int q = 0; q < 9; ++q) wv[q] = wp[q];
          #pragma unroll
          for (int ry = 0; ry < 2; ++ry)
            #pragma unroll
            for (int rx = 0; rx < 2; ++rx) {
              float s = acc[j][ry*2+rx];
              #pragma unroll
              for (int ky = 0; ky < 3; ++ky)
                #pragma unroll
                for (int kx = 0; kx < 3; ++kx)
                  s = fmaf(wv[ky*3+kx], win[ic][ry+ky][rx+kx], s);
              acc[j][ry*2+rx] = s;
            }
        }
      }
      #pragma unroll
      for (int j = 0; j < 8; ++j) {
        float m = fmaxf(fmaxf(acc[j][0],acc[j][1]), fmaxf(acc[j][2],acc[j][3]));
        m = fmaxf(m, 0.f);
        unsigned short h = f2bf(m);
        unsigned short l = f2bf(m - bf2f(h));
        int ic2 = occ + j;
        int sl = pl*4 + ((ic2 >> 3) ^ ((pl >> 1) & 3));
        int us = (sl << 3) | (ic2 & 7);
        ishB[0][us] = h; ishB[1][us] = l;
      }
    }
  }
  __syncthreads();
  // ---- conv2 bf16x2 MFMA + fused pool + relu ----
  {
    const int lane = t & 63, wvv = t >> 6;
    const int lr = lane & 15, lq = lane >> 4;
    const int mtp = (wvv & 1)*2;
    const int rq = wvv >> 1;
    f32x4 acc[2][4];
    #pragma unroll
    for (int i = 0; i < 2; ++i)
      #pragma unroll
      for (int j = 0; j < 4; ++j) acc[i][j] = (f32x4){0.f,0.f,0.f,0.f};
    bf16x8 nAh[2], nAl[2];
    #pragma unroll
    for (int m = 0; m < 2; ++m) {
      int off = (((mtp+m)*16 + lr) << 5) + lq*8;
      nAh[m] = *(const bf16x8*)&wBh[off];
      nAl[m] = *(const bf16x8*)&wBl[off];
    }
    #pragma unroll
    for (int tap = 0; tap < 9; ++tap) {
      bf16x8 ah0 = nAh[0], al0 = nAl[0], ah1 = nAh[1], al1 = nAl[1];
      if (tap < 8) {
        #pragma unroll
        for (int m = 0; m < 2; ++m) {
          int off = (((tap+1)*64 + (mtp+m)*16 + lr) << 5) + lq*8;
          nAh[m] = *(const bf16x8*)&wBh[off];
          nAl[m] = *(const bf16x8*)&wBl[off];
        }
      }
      const int dy = tap/3, dx = tap - dy*3;
      #pragma unroll
      for (int j = 0; j < 4; ++j) {
        int pl = (rq*4 + j + dy)*18 + lr + dx;
        int sl = pl*4 + (lq ^ ((pl >> 1) & 3));
        bf16x8 bh = *(const bf16x8*)&ishB[0][sl << 3];
        bf16x8 bl = *(const bf16x8*)&ishB[1][sl << 3];
        acc[0][j] = __builtin_amdgcn_mfma_f32_16x16x32_bf16(ah0, bh, acc[0][j], 0, 0, 0);
        acc[1][j] = __builtin_amdgcn_mfma_f32_16x16x32_bf16(ah1, bh, acc[1][j], 0, 0, 0);
        acc[0][j] = __builtin_amdgcn_mfma_f32_16x16x32_bf16(ah0, bl, acc[0][j], 0, 0, 0);
        acc[1][j] = __builtin_amdgcn_mfma_f32_16x16x32_bf16(ah1, bl, acc[1][j], 0, 0, 0);
        acc[0][j] = __builtin_amdgcn_mfma_f32_16x16x32_bf16(al0, bh, acc[0][j], 0, 0, 0);
        acc[1][j] = __builtin_amdgcn_mfma_f32_16x16x32_bf16(al1, bh, acc[1][j], 0, 0, 0);
        acc[0][j] = __builtin_amdgcn_mfma_f32_16x16x32_bf16(al0, bl, acc[0][j], 0, 0, 0);
        acc[1][j] = __builtin_amdgcn_mfma_f32_16x16x32_bf16(al1, bl, acc[1][j], 0, 0, 0);
      }
    }
    __syncthreads();
    float* ps = (float*)&ishB[0][0];   // [64 oc][65] padded
    #pragma unroll
    for (int m = 0; m < 2; ++m)
      #pragma unroll
      for (int k = 0; k < 2; ++k)
        #pragma unroll
        for (int r = 0; r < 4; ++r) {
          float v = fmaxf(acc[m][2*k][r], acc[m][2*k+1][r]);
          v = fmaxf(v, __shfl_xor(v, 1, 64));
          if ((lr & 1) == 0) {
            int oc = (mtp + m)*16 + lq*4 + r;
            int Y = rq*2 + k, X = lr >> 1;
            ps[oc*65 + Y*8 + X] = fmaxf(v + bs2[oc], 0.f);
          }
        }
    __syncthreads();
    float* op = outB + (size_t)img*4096;
    #pragma unroll
    for (int jj = 0; jj < 8; ++jj) {
      int i = jj*512 + t;
      op[i] = ps[(i >> 6)*65 + (i & 63)];
    }
  }
}

// ================= conv3 weight prep: c3w[oc][ic][tap] -> wAh/wAl[tap][oc][ic] bf16 hi/lo
__global__ __launch_bounds__(256) void k_wt3b(const float* __restrict__ w,
    unsigned short* __restrict__ wAh, unsigned short* __restrict__ wAl) {
  int i = blockIdx.x*256 + threadIdx.x;   // over 9*128*64 = 73728
  if (i >= 9*128*64) return;
  int ic = i & 63, rem = i >> 6;
  int oc = rem & 127, tap = rem >> 7;
  float v = w[(oc*64 + ic)*9 + tap];
  unsigned short h = f2bf(v);
  wAh[i] = h;
  wAl[i] = f2bf(v - bf2f(h));
}

// ================= conv3 v4: bf16x2 split MFMA implicit GEMM ==================
__global__ __launch_bounds__(256) void k_conv3(const float* __restrict__ inB,
    const unsigned short* __restrict__ wAh, const unsigned short* __restrict__ wAl,
    const float* __restrict__ bias, float* __restrict__ outC) {
  __shared__ unsigned short ish[2][6400];
  const int t = threadIdx.x;
  const int img = blockIdx.x;
  {
    unsigned int* z = (unsigned int*)&ish[0][0];
    #pragma unroll
    for (int j = 0; j < 25; ++j) z[t + 256*j] = 0u;
  }
  __syncthreads();
  {
    const float* src = inB + (size_t)img*4096;
    #pragma unroll
    for (int j = 0; j < 16; ++j) {
      int f = t + 256*j;
      int ic = f >> 6, p = f & 63;
      int pl = ((p >> 3) + 1)*10 + (p & 7) + 1;
      float v = src[f];
      unsigned short h = f2bf(v);
      unsigned short l = f2bf(v - bf2f(h));
      int u = pl*64 + ic;
      int us = (((u >> 3) ^ (pl & 7)) << 3) | (u & 7);
      ish[0][us] = h; ish[1][us] = l;
    }
  }
  __syncthreads();

  const int lane = t & 63, wid = t >> 6;
  const int lr = lane & 15, lq = lane >> 4;
  const int mt0 = wid*2;
  const int yb = lr >> 3, xb = lr & 7;

  f32x4 acc[2][4];
  #pragma unroll
  for (int i = 0; i < 2; ++i)
    #pragma unroll
    for (int j = 0; j < 4; ++j) acc[i][j] = (f32x4){0.f,0.f,0.f,0.f};

  for (int tap = 0; tap < 9; ++tap) {
    const int dy = tap/3, dx = tap - dy*3;
    #pragma unroll
    for (int kc = 0; kc < 2; ++kc) {
      const int kb = kc*32 + lq*8;
      const int wbase = ((tap << 7) << 6) + kb;
      bf16x8 a0h = *(const bf16x8*)&wAh[wbase + ((mt0*16 + lr) << 6)];
      bf16x8 a0l = *(const bf16x8*)&wAl[wbase + ((mt0*16 + lr) << 6)];
      bf16x8 a1h = *(const bf16x8*)&wAh[wbase + (((mt0+1)*16 + lr) << 6)];
      bf16x8 a1l = *(const bf16x8*)&wAl[wbase + (((mt0+1)*16 + lr) << 6)];
      #pragma unroll
      for (int nt = 0; nt < 4; ++nt) {
        const int pl = (2*nt + yb + dy)*10 + xb + dx;
        const int u = pl*64 + kb;
        const int us = (((u >> 3) ^ (pl & 7)) << 3);
        bf16x8 bh = *(const bf16x8*)&ish[0][us];
        bf16x8 bl = *(const bf16x8*)&ish[1][us];
        acc[0][nt] = __builtin_amdgcn_mfma_f32_16x16x32_bf16(a0h, bh, acc[0][nt], 0, 0, 0);
        acc[0][nt] = __builtin_amdgcn_mfma_f32_16x16x32_bf16(a0h, bl, acc[0][nt], 0, 0, 0);
        acc[0][nt] = __builtin_amdgcn_mfma_f32_16x16x32_bf16(a0l, bh, acc[0][nt], 0, 0, 0);
        acc[0][nt] = __builtin_amdgcn_mfma_f32_16x16x32_bf16(a0l, bl, acc[0][nt], 0, 0, 0);
        acc[1][nt] = __builtin_amdgcn_mfma_f32_16x16x32_bf16(a1h, bh, acc[1][nt], 0, 0, 0);
        acc[1][nt] = __builtin_amdgcn_mfma_f32_16x16x32_bf16(a1h, bl, acc[1][nt], 0, 0, 0);
        acc[1][nt] = __builtin_amdgcn_mfma_f32_16x16x32_bf16(a1l, bh, acc[1][nt], 0, 0, 0);
        acc[1][nt] = __builtin_amdgcn_mfma_f32_16x16x32_bf16(a1l, bl, acc[1][nt], 0, 0, 0);
      }
    }
  }
  __syncthreads();
  float* stg = (float*)&ish[0][0];   // [128 oc][17]
  #pragma unroll
  for (int mtl = 0; mtl < 2; ++mtl)
    #pragma unroll
    for (int nt = 0; nt < 4; ++nt)
      #pragma unroll
      for (int r = 0; r < 4; ++r) {
        float v = acc[mtl][nt][r];
        v = fmaxf(v, __shfl_xor(v, 1, 64));
        v = fmaxf(v, __shfl_xor(v, 8, 64));
        if ((lane & 9) == 0) {
          int oc = (mt0 + mtl)*16 + lq*4 + r;
          int pix = nt*4 + (xb >> 1);
          stg[oc*17 + pix] = fmaxf(v + bias[oc], 0.f);
        }
      }
  __syncthreads();
  float* dst = outC + (size_t)img*2048;
  #pragma unroll
  for (int j = 0; j < 8; ++j) {
    int i = t + 256*j;
    dst[i] = stg[(i >> 4)*17 + (i & 15)];
  }
}

// ================= FC GEMM: [4096,2048] @ [2048,256], split-K=2, 64x64 tiles, 4x4 micro-tile
__global__ __launch_bounds__(256) void k_fc(const float* __restrict__ C,
    const float* __restrict__ fcw, float* __restrict__ P0, float* __restrict__ P1) {
  __shared__ float As[32][68];
  __shared__ float Bs[32][68];
  const int t = threadIdx.x;
  const int r0 = blockIdx.x * 64;
  const int nc = blockIdx.y * 64;
  const int kbase = blockIdx.z * 1024;
  float* __restrict__ P = blockIdx.z ? P1 : P0;
  const int tx = t & 15, ty = t >> 4;
  float acc[4][4];
  #pragma unroll
  for (int i = 0; i < 4; ++i)
    #pragma unroll
    for (int j = 0; j < 4; ++j) acc[i][j] = 0.f;
  const int ia0 = t*2, ia1 = t*2 + 1;
  for (int c = 0; c < 32; ++c) {
    const int k0 = kbase + c*32;
    __syncthreads();
    #pragma unroll
    for (int j = 0; j < 2; ++j) {
      int idx = (j ? ia1 : ia0);
      int row = idx >> 3, kq = idx & 7;
      float4 v = *(const float4*)&C[(size_t)(r0+row)*2048 + k0 + kq*4];
      As[kq*4+0][row] = v.x; As[kq*4+1][row] = v.y;
      As[kq*4+2][row] = v.z; As[kq*4+3][row] = v.w;
    }
    #pragma unroll
    for (int j = 0; j < 2; ++j) {
      int idx = (j ? ia1 : ia0);
      int krow = idx >> 4, c4 = idx & 15;
      float4 v = *(const float4*)&fcw[(size_t)(k0+krow)*256 + nc + c4*4];
      *(float4*)&Bs[krow][c4*4] = v;
    }
    __syncthreads();
    #pragma unroll 8
    for (int k = 0; k < 32; ++k) {
      float4 av = *(const float4*)&As[k][ty*4];
      float4 bv = *(const float4*)&Bs[k][tx*4];
      float a[4] = {av.x, av.y, av.z, av.w};
      float bbv[4] = {bv.x, bv.y, bv.z, bv.w};
      #pragma unroll
      for (int i = 0; i < 4; ++i)
        #pragma unroll
        for (int j = 0; j < 4; ++j)
          acc[i][j] = fmaf(a[i], bbv[j], acc[i][j]);
    }
  }
  #pragma unroll
  for (int i = 0; i < 4; ++i) {
    float4 v = make_float4(acc[i][0], acc[i][1], acc[i][2], acc[i][3]);
    *(float4*)&P[(size_t)(r0 + ty*4 + i)*256 + nc + tx*4] = v;
  }
}

// ================= gate: feat = P0+P1+fcb; logits; top-2 softmax; expert lists
__global__ __launch_bounds__(256) void k_gate(const float* __restrict__ P0,
    const float* __restrict__ P1, const float* __restrict__ fcb,
    const float* __restrict__ gw, const float* __restrict__ gb,
    float* __restrict__ feat, int* __restrict__ cnt, float* __restrict__ gsum,
    int* __restrict__ lrow, float* __restrict__ lg) {
  __shared__ float ft[16][256];
  __shared__ float lgs[16][16];
  __shared__ float gwl[4096];
  const int t = threadIdx.x;
  const int r0 = blockIdx.x * 16;
  for (int i = t; i < 4096; i += 256) gwl[i] = gw[i];
  float bb = fcb[t];
  #pragma unroll
  for (int r = 0; r < 16; ++r) {
    size_t off = (size_t)(r0+r)*256 + t;
    float v = P0[off] + P1[off] + bb;
    ft[r][t] = v;
    feat[off] = v;
  }
  __syncthreads();
  {
    int r = t >> 4, e = t & 15;
    float s = gb[e];
    for (int k = 0; k < 256; ++k) s = fmaf(ft[r][k], gwl[k*16 + e], s);
    lgs[r][e] = s;
  }
  __syncthreads();
  if (t < 16) {
    int r = t;
    float v1 = -3.402823e38f, v2 = -3.402823e38f;
    int i1 = 0, i2 = 0;
    for (int e = 0; e < 16; ++e) {
      float v = lgs[r][e];
      if (v > v1)      { v2 = v1; i2 = i1; v1 = v; i1 = e; }
      else if (v > v2) { v2 = v;  i2 = e; }
    }
    float ex = __expf(v2 - v1);
    float g1 = 1.f / (1.f + ex);
    float g2 = ex  / (1.f + ex);
    int row = r0 + r;
    int p1 = atomicAdd(&cnt[i1], 1); lrow[i1*4096 + p1] = row; lg[i1*4096 + p1] = g1;
    int p2 = atomicAdd(&cnt[i2], 1); lrow[i2*4096 + p2] = row; lg[i2*4096 + p2] = g2;
    atomicAdd(&gsum[i1], g1);
    atomicAdd(&gsum[i2], g2);
  }
}

// ================= MoE v2: 32-row tiles, bf16x2 split MFMA, both GEMMs on matrix cores
// Phase 1 per 128-h chunk: h1 = relu(feat@w1T + b1) -> swizzled LDS bf16 hi/lo.
// Phase 2: eo += h1@w2T. Epilogue: atomicAdd(gate*(eo+b2)).
__global__ __launch_bounds__(256) void k_moe(const float* __restrict__ feat,
    const unsigned short* __restrict__ w1th, const unsigned short* __restrict__ w1tl,
    const unsigned short* __restrict__ w2th, const unsigned short* __restrict__ w2tl,
    const float* __restrict__ eb1, const float* __restrict__ eb2,
    const int* __restrict__ cnt, const int* __restrict__ lrow, const float* __restrict__ lgw,
    float* __restrict__ moe) {
  const int e = blockIdx.y;
  const int n_e = cnt[e];
  const int start = blockIdx.x * 32;
  if (start >= n_e) return;
  const int n = min(32, n_e - start);
  __shared__ unsigned short fh[8192], fl[8192];   // [32 rows][256 k] swizzled
  __shared__ unsigned short h1h[4096], h1l[4096]; // [32 rows][128 h] swizzled
  __shared__ int   rws[32];
  __shared__ float gws[32];
  const int t = threadIdx.x;
  if (t < 32) {
    rws[t] = (t < n) ? lrow[e*4096 + start + t] : 0;
    gws[t] = (t < n) ? lgw[e*4096 + start + t] : 0.f;
  }
  __syncthreads();
  // stage feat rows -> bf16 hi/lo swizzled
  for (int j = 0; j < 32; ++j) {
    float v = (j < n) ? feat[(size_t)rws[j]*256 + t] : 0.f;
    unsigned short h = f2bf(v);
    int us = (j*32 + ((t >> 3) ^ (j & 7)))*8 + (t & 7);
    fh[us] = h; fl[us] = f2bf(v - bf2f(h));
  }
  const int lane = t & 63, wv = t >> 6;
  const int lr = lane & 15, lq = lane >> 4;
  const int rh = wv & 1, qh = wv >> 1;   // rows rh*16..+15; h-quarter/d-half = qh
  const int arow = rh*16 + lr;           // A-frag row this lane supplies
  const int rsw = arow & 7;
  const size_t ewb = (size_t)e << 18;

  f32x4 acc2[8];
  #pragma unroll
  for (int i = 0; i < 8; ++i) acc2[i] = (f32x4){0.f,0.f,0.f,0.f};

  __syncthreads();   // fA ready

  for (int c = 0; c < 8; ++c) {
    // ---- phase 1: h1[:, c*128 + qh*64 + ht*16 + lr], K=256 ----
    f32x4 acc1[4];
    #pragma unroll
    for (int i = 0; i < 4; ++i) acc1[i] = (f32x4){0.f,0.f,0.f,0.f};
    #pragma unroll
    for (int ks = 0; ks < 8; ++ks) {
      int aoff = (arow*32 + ((ks*4 + lq) ^ rsw))*8;
      bf16x8 ah = *(const bf16x8*)&fh[aoff];
      bf16x8 al = *(const bf16x8*)&fl[aoff];
      #pragma unroll
      for (int ht = 0; ht < 4; ++ht) {
        int h = c*128 + qh*64 + ht*16 + lr;
        size_t bo = ewb + (size_t)h*256 + ks*32 + lq*8;
        bf16x8 bh = *(const bf16x8*)&w1th[bo];
        bf16x8 bl = *(const bf16x8*)&w1tl[bo];
        acc1[ht] = __builtin_amdgcn_mfma_f32_16x16x32_bf16(ah, bh, acc1[ht], 0, 0, 0);
        acc1[ht] = __builtin_amdgcn_mfma_f32_16x16x32_bf16(ah, bl, acc1[ht], 0, 0, 0);
        acc1[ht] = __builtin_amdgcn_mfma_f32_16x16x32_bf16(al, bh, acc1[ht], 0, 0, 0);
        acc1[ht] = __builtin_amdgcn_mfma_f32_16x16x32_bf16(al, bl, acc1[ht], 0, 0, 0);
      }
    }
    __syncthreads();   // prev phase-2 readers done with h1
    #pragma unroll
    for (int ht = 0; ht < 4; ++ht) {
      int hloc = qh*64 + ht*16 + lr;
      float bb = eb1[e*1024 + c*128 + hloc];
      #pragma unroll
      for (int r = 0; r < 4; ++r) {
        int orow = rh*16 + lq*4 + r;     // D row = (lane>>4)*4+reg
        float v = fmaxf(acc1[ht][r] + bb, 0.f);
        unsigned short hh = f2bf(v);
        int us = (orow*16 + ((hloc >> 3) ^ (orow & 7)))*8 + (hloc & 7);
        h1h[us] = hh; h1l[us] = f2bf(v - bf2f(hh));
      }
    }
    __syncthreads();   // h1 chunk ready
    // ---- phase 2: eo += h1 @ w2T[:, chunk], K=128 ----
    #pragma unroll
    for (int ks = 0; ks < 4; ++ks) {
      int aoff = (arow*16 + ((ks*4 + lq) ^ rsw))*8;
      bf16x8 ah = *(const bf16x8*)&h1h[aoff];
      bf16x8 al = *(const bf16x8*)&h1l[aoff];
      #pragma unroll
      for (int dt = 0; dt < 8; ++dt) {
        int d = qh*128 + dt*16 + lr;
        size_t bo = ewb + (size_t)d*1024 + c*128 + ks*32 + lq*8;
        bf16x8 bh = *(const bf16x8*)&w2th[bo];
        bf16x8 bl = *(const bf16x8*)&w2tl[bo];
        acc2[dt] = __builtin_amdgcn_mfma_f32_16x16x32_bf16(ah, bh, acc2[dt], 0, 0, 0);
        acc2[dt] = __builtin_amdgcn_mfma_f32_16x16x32_bf16(ah, bl, acc2[dt], 0, 0, 0);
        acc2[dt] = __builtin_amdgcn_mfma_f32_16x16x32_bf16(al, bh, acc2[dt], 0, 0, 0);
        acc2[dt] = __builtin_amdgcn_mfma_f32_16x16x32_bf16(al, bl, acc2[dt], 0, 0, 0);
      }
    }
  }
  // epilogue: gate-weighted scatter
  #pragma unroll
  for (int dt = 0; dt < 8; ++dt) {
    int d = qh*128 + dt*16 + lr;
    float b2 = eb2[e*256 + d];
    #pragma unroll
    for (int r = 0; r < 4; ++r) {
      int orow = rh*16 + lq*4 + r;
      if (orow < n)
        atomicAdd(&moe[(size_t)rws[orow]*256 + d], gws[orow]*(acc2[dt][r] + b2));
    }
  }
}

// ================= load-balance loss
__global__ void k_lb(const float* __restrict__ gsum, float* __restrict__ out_lb) {
  int t = threadIdx.x;
  float term = 0.f;
  if (t < 16) {
    float D = gsum[t] * (1.f/4096.f);
    term = D * logf(D + 1e-8f);
  }
  #pragma unroll
  for (int o = 8; o > 0; o >>= 1) term += __shfl_down(term, o, 64);
  if (t == 0) *out_lb = term;
}

// ================= LayerNorm(moe + feat) in-place into moe
__global__ __launch_bounds__(256) void k_ln(const float* __restrict__ feat,
    float* __restrict__ moe, const float* __restrict__ g, const float* __restrict__ bp) {
  const int r = blockIdx.x, t = threadIdx.x;
  float v = moe[(size_t)r*256 + t] + feat[(size_t)r*256 + t];
  float s = v, q = v * v;
  #pragma unroll
  for (int o = 32; o > 0; o >>= 1) {
    s += __shfl_down(s, o, 64);
    q += __shfl_down(q, o, 64);
  }
  __shared__ float ss[4], qq[4];
  int wv = t >> 6;
  if ((t & 63) == 0) { ss[wv] = s; qq[wv] = q; }
  __syncthreads();
  float S = ss[0]+ss[1]+ss[2]+ss[3];
  float Q = qq[0]+qq[1]+qq[2]+qq[3];
  float mu  = S * (1.f/256.f);
  float var = Q * (1.f/256.f) - mu*mu;
  float inv = rsqrtf(var + 1e-5f);
  moe[(size_t)r*256 + t] = (v - mu) * inv * g[t] + bp[t];
}

// ================= output GEMM: [4096,256] @ [256,1000] + b
__global__ __launch_bounds__(256) void k_out(const float* __restrict__ y,
    const float* __restrict__ ow, const float* __restrict__ ob,
    float* __restrict__ out) {
  __shared__ float ys[32][256];
  const int t = threadIdx.x;
  const int r0 = blockIdx.x * 32;
  const int c = blockIdx.y * 256 + t;
  for (int i = t; i < 32*256; i += 256) {
    int r = i >> 8, k = i & 255;
    ys[r][k] = y[(size_t)(r0+r)*256 + k];
  }
  __syncthreads();
  if (c >= NCLS) return;
  float acc[32];
  {
    float bb = ob[c];
    #pragma unroll
    for (int r = 0; r < 32; ++r) acc[r] = bb;
  }
  #pragma unroll 4
  for (int k = 0; k < 256; ++k) {
    float wv = ow[(size_t)k*NCLS + c];
    #pragma unroll
    for (int r = 0; r < 32; ++r) acc[r] = fmaf(ys[r][k], wv, acc[r]);
  }
  for (int r = 0; r < 32; ++r) out[(size_t)(r0+r)*NCLS + c] = acc[r];
}

// ================= launch =================
extern "C" void kernel_launch(void* const* d_in, const int* in_sizes, int n_in,
                              void* d_out, int out_size, void* d_ws, size_t ws_size,
                              hipStream_t stream) {
  const float* x   = (const float*)d_in[0];
  const float* c1w = (const float*)d_in[1];
  const float* c1b = (const float*)d_in[2];
  const float* c2w = (const float*)d_in[3];
  const float* c2b = (const float*)d_in[4];
  const float* c3w = (const float*)d_in[5];
  const float* c3b = (const float*)d_in[6];
  const float* fcw = (const float*)d_in[7];
  const float* fcb = (const float*)d_in[8];
  const float* gw  = (const float*)d_in[9];
  const float* gb  = (const float*)d_in[10];
  const float* ew1 = (const float*)d_in[11];
  const float* eb1 = (const float*)d_in[12];
  const float* ew2 = (const float*)d_in[13];
  const float* eb2 = (const float*)d_in[14];
  const float* lng = (const float*)d_in[15];
  const float* lnb = (const float*)d_in[16];
  const float* ow  = (const float*)d_in[17];
  const float* ob  = (const float*)d_in[18];
  char* ws = (char*)d_ws;
  float* Bb   = (float*)(ws + OFF_B);
  float* P0   = (float*)(ws + OFF_P0);
  float* P1   = (float*)(ws + OFF_P1);
  float* C    = (float*)(ws + OFF_C);
  unsigned short* wBh = (unsigned short*)(ws + OFF_C);     // aliases C (C written after conv12)
  unsigned short* wBl = (unsigned short*)(ws + OFF_WBL);
  unsigned short* wAh = (unsigned short*)(ws + OFF_FEAT);  // aliases feat (written later)
  unsigned short* wAl = (unsigned short*)(ws + OFF_WAL);
  unsigned short* w1th = (unsigned short*)(ws + OFF_W1TH); // region dead after conv3
  unsigned short* w1tl = (unsigned short*)(ws + OFF_W1TL);
  unsigned short* w2th = (unsigned short*)(ws + OFF_W2TH);
  unsigned short* w2tl = (unsigned short*)(ws + OFF_W2TL);
  float* feat = (float*)(ws + OFF_FEAT);
  float* moe  = (float*)(ws + OFF_MOE);
  int*   cnt  = (int*)(ws + OFF_CNT);
  float* gsum = (float*)(ws + OFF_GSUM);
  int*   lrow = (int*)(ws + OFF_LROW);
  float* lgv  = (float*)(ws + OFF_LG);
  float* outp = (float*)d_out;

  hipMemsetAsync(ws + OFF_MOE, 0, 4194304 + 128, stream);

  hipLaunchKernelGGL(k_wt2b,   dim3(72),      dim3(256), 0, stream, c2w, wBh, wBl);
  hipLaunchKernelGGL(k_wt3b,   dim3(288),     dim3(256), 0, stream, c3w, wAh, wAl);
  hipLaunchKernelGGL(k_conv12, dim3(4096),    dim3(512), 0, stream, x, c1w, c1b, wBh, wBl, c2b, Bb);
  hipLaunchKernelGGL(k_conv3,  dim3(4096),    dim3(256), 0, stream, Bb, wAh, wAl, c3b, C);
  // Bb dead now -> build MoE transposed/split weights in its region
  hipLaunchKernelGGL(k_tsp,    dim3(16, 4, 16), dim3(256), 0, stream, ew1, w1th, w1tl, 256, 1024);
  hipLaunchKernelGGL(k_tsp,    dim3(4, 16, 16), dim3(256), 0, stream, ew2, w2th, w2tl, 1024, 256);
  hipLaunchKernelGGL(k_fc,     dim3(64, 4, 2),dim3(256), 0, stream, C, fcw, P0, P1);
  hipLaunchKernelGGL(k_gate,   dim3(256),     dim3(256), 0, stream, P0, P1, fcb, gw, gb,
                     feat, cnt, gsum, lrow, lgv);
  hipLaunchKernelGGL(k_moe,    dim3(128, 16), dim3(256), 0, stream, feat, w1th, w1tl, w2th, w2tl,
                     eb1, eb2, cnt, lrow, lgv, moe);
  hipLaunchKernelGGL(k_lb,     dim3(1),       dim3(64),  0, stream, gsum, outp + (size_t)NB*NCLS);
  hipLaunchKernelGGL(k_ln,     dim3(4096),    dim3(256), 0, stream, feat, moe, lng, lnb);
  hipLaunchKernelGGL(k_out,    dim3(128, 4),  dim3(256), 0, stream, moe, ow, ob, outp);
}

// Round 10
// 922.842 us; speedup vs baseline: 3.8153x; 1.0273x over previous
//
#include <hip/hip_runtime.h>
#include <hip/hip_bf16.h>

typedef short bf16x8 __attribute__((ext_vector_type(8)));
typedef float f32x4 __attribute__((ext_vector_type(4)));

// ---------------- problem sizes ----------------
#define NB   4096
#define NEXP 16
#define DDIM 256
#define HDIM 1024
#define NCLS 1000

// ---------------- workspace layout (bytes) ----------------
#define OFF_B    ((size_t)0)
#define OFF_P0   ((size_t)0)           // f32 [4096][256] FC partial (K half 0)
#define OFF_P1   ((size_t)4194304)     // f32 [4096][256] FC partial (K half 1)
// MoE packed/split weights (written after conv3, when Bb is dead; after P0/P1):
#define OFF_W1TH ((size_t)8388608)     // bf16 packed [16][64 ht][8 ks][64 lane][8]  8 MB
#define OFF_W1TL ((size_t)16777216)
#define OFF_W2TH ((size_t)25165824)    // bf16 packed [16][16 dt][32 ks][64 lane][8] 8 MB
#define OFF_W2TL ((size_t)33554432)
#define OFF_C    ((size_t)67108864)    // conv3 out f32 [4096][2048]; ALSO wBh/wBl (74 KB) before conv12
#define OFF_WBL  ((size_t)67145728)    // OFF_C + 36864
#define OFF_FEAT ((size_t)100663296)   // f32 [4096][256]; ALSO wAh/wAl (288 KB) before k_gate
#define OFF_WAL  ((size_t)100810752)   // OFF_FEAT + 147456
#define OFF_MOE  ((size_t)104857600)   // f32 [4096][256]
#define OFF_CNT  ((size_t)109051904)   // int [16]
#define OFF_GSUM ((size_t)109051968)   // f32 [16]
#define OFF_LROW ((size_t)109052032)   // int [16][4096]
#define OFF_LG   ((size_t)109314176)   // f32 [16][4096]

__device__ inline unsigned short f2bf(float v) {
  __hip_bfloat16 h = __float2bfloat16(v);
  return *(unsigned short*)&h;
}
__device__ inline float bf2f(unsigned short u) {
  union { unsigned int i; float f; } c; c.i = ((unsigned int)u) << 16; return c.f;
}

// ====== conv2 weight prep: c2w[oc][ic][tap] -> wBh/wBl[tap][oc][ic] bf16 hi/lo ======
__global__ __launch_bounds__(256) void k_wt2b(const float* __restrict__ w,
    unsigned short* __restrict__ wBh, unsigned short* __restrict__ wBl) {
  int i = blockIdx.x*256 + threadIdx.x;   // over 9*64*32 = 18432
  if (i >= 9*64*32) return;
  int ic = i & 31, rem = i >> 5;
  int oc = rem & 63, tap = rem >> 6;
  float v = w[(oc*32 + ic)*9 + tap];
  unsigned short h = f2bf(v);
  wBh[i] = h;
  wBl[i] = f2bf(v - bf2f(h));
}

// ====== MFMA-native weight pack: in[e][R=k][C=n] -> packed[e][n/16][R/32][64 lane][8] hi/lo
// packed element (ntile,ks,lane,j) = in[e][ks*32+(lane>>4)*8+j][ntile*16+(lane&15)]
__global__ __launch_bounds__(256) void k_pack(const float* __restrict__ in,
    unsigned short* __restrict__ oh, unsigned short* __restrict__ ol, int R, int C) {
  __shared__ float tile[64][65];
  const int t = threadIdx.x;
  const int e = blockIdx.z;
  const size_t eb = (size_t)e * R * C;
  const int c0 = blockIdx.x*64, r0 = blockIdx.y*64;
  const int cc = t & 63, r4 = t >> 6;
  #pragma unroll
  for (int j = 0; j < 16; ++j) {
    int rr = r4 + j*4;
    tile[rr][cc] = in[eb + (size_t)(r0+rr)*C + c0 + cc];
  }
  __syncthreads();
  const int K32 = R >> 5;
  #pragma unroll
  for (int j = 0; j < 16; ++j) {
    int idx = t + j*256;
    int jin = idx & 7, lane = (idx >> 3) & 63, ksl = (idx >> 9) & 1, ntl = idx >> 10;
    int kl = ksl*32 + ((lane >> 4) << 3) + jin;
    int nl = ntl*16 + (lane & 15);
    float v = tile[kl][nl];
    unsigned short h = f2bf(v);
    size_t o = eb + ((size_t)(((c0 >> 4) + ntl)*K32 + (r0 >> 5) + ksl)*64 + lane)*8 + jin;
    oh[o] = h;
    ol[o] = f2bf(v - bf2f(h));
  }
}

// ================= fused conv1(vector) + conv2(bf16x2 MFMA) per image =================
__global__ __launch_bounds__(512, 4) void k_conv12(const float* __restrict__ x,
    const float* __restrict__ w1, const float* __restrict__ b1,
    const unsigned short* __restrict__ wBh, const unsigned short* __restrict__ wBl,
    const float* __restrict__ b2, float* __restrict__ outB) {
  __shared__ float xs[3][34][36];           // padded input image (14.7 KB)
  __shared__ unsigned short ishB[2][10368]; // [hi/lo][pl*32+ic swizzled] (41.5 KB); reused for store stage
  __shared__ float ws1[864];
  __shared__ float bs1[32];
  __shared__ float bs2[64];
  const int t = threadIdx.x;
  const int img = blockIdx.x;
  for (int i = t; i < 3*34*36; i += 512) ((float*)xs)[i] = 0.f;
  {
    unsigned int* z = (unsigned int*)&ishB[0][0];
    for (int i = t; i < 10368; i += 512) z[i] = 0u;
  }
  __syncthreads();
  for (int i = t; i < 3072; i += 512) {
    int ic = i >> 10, rem = i & 1023, y = rem >> 5, xx = rem & 31;
    xs[ic][y+1][xx+1] = x[(size_t)img*3072 + i];
  }
  for (int i = t; i < 864; i += 512) ws1[i] = w1[i];
  if (t < 32) bs1[t] = b1[t];
  else if (t >= 64 && t < 128) bs2[t-64] = b2[t-64];
  __syncthreads();
  // ---- conv1 + pool + relu -> ishB hi/lo swizzled ----
  {
    const int p = t & 255, grp = t >> 8;
    const int px = p & 15, py = p >> 4;
    const int pl = (py+1)*18 + (px+1);
    float win[3][4][4];
    #pragma unroll
    for (int ic = 0; ic < 3; ++ic)
      #pragma unroll
      for (int r = 0; r < 4; ++r) {
        float2 a  = *(const float2*)&xs[ic][2*py+r][2*px];
        float2 c2 = *(const float2*)&xs[ic][2*py+r][2*px+2];
        win[ic][r][0]=a.x; win[ic][r][1]=a.y; win[ic][r][2]=c2.x; win[ic][r][3]=c2.y;
      }
    for (int occ = grp*16; occ < grp*16 + 16; occ += 8) {
      float acc[8][4];
      #pragma unroll
      for (int j = 0; j < 8; ++j) { float bb = bs1[occ+j]; acc[j][0]=bb;acc[j][1]=bb;acc[j][2]=bb;acc[j][3]=bb; }
      #pragma unroll
      for (int ic = 0; ic < 3; ++ic) {
        #pragma unroll
        for (int j = 0; j < 8; ++j) {
          const float* wp = &ws1[(occ+j)*27 + ic*9];
          float wv[9];
          #pragma unroll
          for (int q = 0; q < 9; ++q) wv[q] = wp[q];
          #pragma unroll
          for (int ry = 0; ry < 2; ++ry)
            #pragma unroll
            for (int rx = 0; rx < 2; ++rx) {
              float s = acc[j][ry*2+rx];
              #pragma unroll
              for (int ky = 0; ky < 3; ++ky)
                #pragma unroll
                for (int kx = 0; kx < 3; ++kx)
                  s = fmaf(wv[ky*3+kx], win[ic][ry+ky][rx+kx], s);
              acc[j][ry*2+rx] = s;
            }
        }
      }
      #pragma unroll
      for (int j = 0; j < 8; ++j) {
        float m = fmaxf(fmaxf(acc[j][0],acc[j][1]), fmaxf(acc[j][2],acc[j][3]));
        m = fmaxf(m, 0.f);
        unsigned short h = f2bf(m);
        unsigned short l = f2bf(m - bf2f(h));
        int ic2 = occ + j;
        int sl = pl*4 + ((ic2 >> 3) ^ ((pl >> 1) & 3));
        int us = (sl << 3) | (ic2 & 7);
        ishB[0][us] = h; ishB[1][us] = l;
      }
    }
  }
  __syncthreads();
  // ---- conv2 bf16x2 MFMA + fused pool + relu ----
  {
    const int lane = t & 63, wvv = t >> 6;
    const int lr = lane & 15, lq = lane >> 4;
    const int mtp = (wvv & 1)*2;
    const int rq = wvv >> 1;
    f32x4 acc[2][4];
    #pragma unroll
    for (int i = 0; i < 2; ++i)
      #pragma unroll
      for (int j = 0; j < 4; ++j) acc[i][j] = (f32x4){0.f,0.f,0.f,0.f};
    bf16x8 nAh[2], nAl[2];
    #pragma unroll
    for (int m = 0; m < 2; ++m) {
      int off = (((mtp+m)*16 + lr) << 5) + lq*8;
      nAh[m] = *(const bf16x8*)&wBh[off];
      nAl[m] = *(const bf16x8*)&wBl[off];
    }
    #pragma unroll
    for (int tap = 0; tap < 9; ++tap) {
      bf16x8 ah0 = nAh[0], al0 = nAl[0], ah1 = nAh[1], al1 = nAl[1];
      if (tap < 8) {
        #pragma unroll
        for (int m = 0; m < 2; ++m) {
          int off = (((tap+1)*64 + (mtp+m)*16 + lr) << 5) + lq*8;
          nAh[m] = *(const bf16x8*)&wBh[off];
          nAl[m] = *(const bf16x8*)&wBl[off];
        }
      }
      const int dy = tap/3, dx = tap - dy*3;
      #pragma unroll
      for (int j = 0; j < 4; ++j) {
        int pl = (rq*4 + j + dy)*18 + lr + dx;
        int sl = pl*4 + (lq ^ ((pl >> 1) & 3));
        bf16x8 bh = *(const bf16x8*)&ishB[0][sl << 3];
        bf16x8 bl = *(const bf16x8*)&ishB[1][sl << 3];
        acc[0][j] = __builtin_amdgcn_mfma_f32_16x16x32_bf16(ah0, bh, acc[0][j], 0, 0, 0);
        acc[1][j] = __builtin_amdgcn_mfma_f32_16x16x32_bf16(ah1, bh, acc[1][j], 0, 0, 0);
        acc[0][j] = __builtin_amdgcn_mfma_f32_16x16x32_bf16(ah0, bl, acc[0][j], 0, 0, 0);
        acc[1][j] = __builtin_amdgcn_mfma_f32_16x16x32_bf16(ah1, bl, acc[1][j], 0, 0, 0);
        acc[0][j] = __builtin_amdgcn_mfma_f32_16x16x32_bf16(al0, bh, acc[0][j], 0, 0, 0);
        acc[1][j] = __builtin_amdgcn_mfma_f32_16x16x32_bf16(al1, bh, acc[1][j], 0, 0, 0);
        acc[0][j] = __builtin_amdgcn_mfma_f32_16x16x32_bf16(al0, bl, acc[0][j], 0, 0, 0);
        acc[1][j] = __builtin_amdgcn_mfma_f32_16x16x32_bf16(al1, bl, acc[1][j], 0, 0, 0);
      }
    }
    __syncthreads();
    float* ps = (float*)&ishB[0][0];   // [64 oc][65] padded
    #pragma unroll
    for (int m = 0; m < 2; ++m)
      #pragma unroll
      for (int k = 0; k < 2; ++k)
        #pragma unroll
        for (int r = 0; r < 4; ++r) {
          float v = fmaxf(acc[m][2*k][r], acc[m][2*k+1][r]);
          v = fmaxf(v, __shfl_xor(v, 1, 64));
          if ((lr & 1) == 0) {
            int oc = (mtp + m)*16 + lq*4 + r;
            int Y = rq*2 + k, X = lr >> 1;
            ps[oc*65 + Y*8 + X] = fmaxf(v + bs2[oc], 0.f);
          }
        }
    __syncthreads();
    float* op = outB + (size_t)img*4096;
    #pragma unroll
    for (int jj = 0; jj < 8; ++jj) {
      int i = jj*512 + t;
      op[i] = ps[(i >> 6)*65 + (i & 63)];
    }
  }
}

// ================= conv3 weight prep: c3w[oc][ic][tap] -> wAh/wAl[tap][oc][ic] bf16 hi/lo
__global__ __launch_bounds__(256) void k_wt3b(const float* __restrict__ w,
    unsigned short* __restrict__ wAh, unsigned short* __restrict__ wAl) {
  int i = blockIdx.x*256 + threadIdx.x;   // over 9*128*64 = 73728
  if (i >= 9*128*64) return;
  int ic = i & 63, rem = i >> 6;
  int oc = rem & 127, tap = rem >> 7;
  float v = w[(oc*64 + ic)*9 + tap];
  unsigned short h = f2bf(v);
  wAh[i] = h;
  wAl[i] = f2bf(v - bf2f(h));
}

// ================= conv3 v4: bf16x2 split MFMA implicit GEMM ==================
__global__ __launch_bounds__(256) void k_conv3(const float* __restrict__ inB,
    const unsigned short* __restrict__ wAh, const unsigned short* __restrict__ wAl,
    const float* __restrict__ bias, float* __restrict__ outC) {
  __shared__ unsigned short ish[2][6400];
  const int t = threadIdx.x;
  const int img = blockIdx.x;
  {
    unsigned int* z = (unsigned int*)&ish[0][0];
    #pragma unroll
    for (int j = 0; j < 25; ++j) z[t + 256*j] = 0u;
  }
  __syncthreads();
  {
    const float* src = inB + (size_t)img*4096;
    #pragma unroll
    for (int j = 0; j < 16; ++j) {
      int f = t + 256*j;
      int ic = f >> 6, p = f & 63;
      int pl = ((p >> 3) + 1)*10 + (p & 7) + 1;
      float v = src[f];
      unsigned short h = f2bf(v);
      unsigned short l = f2bf(v - bf2f(h));
      int u = pl*64 + ic;
      int us = (((u >> 3) ^ (pl & 7)) << 3) | (u & 7);
      ish[0][us] = h; ish[1][us] = l;
    }
  }
  __syncthreads();

  const int lane = t & 63, wid = t >> 6;
  const int lr = lane & 15, lq = lane >> 4;
  const int mt0 = wid*2;
  const int yb = lr >> 3, xb = lr & 7;

  f32x4 acc[2][4];
  #pragma unroll
  for (int i = 0; i < 2; ++i)
    #pragma unroll
    for (int j = 0; j < 4; ++j) acc[i][j] = (f32x4){0.f,0.f,0.f,0.f};

  for (int tap = 0; tap < 9; ++tap) {
    const int dy = tap/3, dx = tap - dy*3;
    #pragma unroll
    for (int kc = 0; kc < 2; ++kc) {
      const int kb = kc*32 + lq*8;
      const int wbase = ((tap << 7) << 6) + kb;
      bf16x8 a0h = *(const bf16x8*)&wAh[wbase + ((mt0*16 + lr) << 6)];
      bf16x8 a0l = *(const bf16x8*)&wAl[wbase + ((mt0*16 + lr) << 6)];
      bf16x8 a1h = *(const bf16x8*)&wAh[wbase + (((mt0+1)*16 + lr) << 6)];
      bf16x8 a1l = *(const bf16x8*)&wAl[wbase + (((mt0+1)*16 + lr) << 6)];
      #pragma unroll
      for (int nt = 0; nt < 4; ++nt) {
        const int pl = (2*nt + yb + dy)*10 + xb + dx;
        const int u = pl*64 + kb;
        const int us = (((u >> 3) ^ (pl & 7)) << 3);
        bf16x8 bh = *(const bf16x8*)&ish[0][us];
        bf16x8 bl = *(const bf16x8*)&ish[1][us];
        acc[0][nt] = __builtin_amdgcn_mfma_f32_16x16x32_bf16(a0h, bh, acc[0][nt], 0, 0, 0);
        acc[0][nt] = __builtin_amdgcn_mfma_f32_16x16x32_bf16(a0h, bl, acc[0][nt], 0, 0, 0);
        acc[0][nt] = __builtin_amdgcn_mfma_f32_16x16x32_bf16(a0l, bh, acc[0][nt], 0, 0, 0);
        acc[0][nt] = __builtin_amdgcn_mfma_f32_16x16x32_bf16(a0l, bl, acc[0][nt], 0, 0, 0);
        acc[1][nt] = __builtin_amdgcn_mfma_f32_16x16x32_bf16(a1h, bh, acc[1][nt], 0, 0, 0);
        acc[1][nt] = __builtin_amdgcn_mfma_f32_16x16x32_bf16(a1h, bl, acc[1][nt], 0, 0, 0);
        acc[1][nt] = __builtin_amdgcn_mfma_f32_16x16x32_bf16(a1l, bh, acc[1][nt], 0, 0, 0);
        acc[1][nt] = __builtin_amdgcn_mfma_f32_16x16x32_bf16(a1l, bl, acc[1][nt], 0, 0, 0);
      }
    }
  }
  __syncthreads();
  float* stg = (float*)&ish[0][0];   // [128 oc][17]
  #pragma unroll
  for (int mtl = 0; mtl < 2; ++mtl)
    #pragma unroll
    for (int nt = 0; nt < 4; ++nt)
      #pragma unroll
      for (int r = 0; r < 4; ++r) {
        float v = acc[mtl][nt][r];
        v = fmaxf(v, __shfl_xor(v, 1, 64));
        v = fmaxf(v, __shfl_xor(v, 8, 64));
        if ((lane & 9) == 0) {
          int oc = (mt0 + mtl)*16 + lq*4 + r;
          int pix = nt*4 + (xb >> 1);
          stg[oc*17 + pix] = fmaxf(v + bias[oc], 0.f);
        }
      }
  __syncthreads();
  float* dst = outC + (size_t)img*2048;
  #pragma unroll
  for (int j = 0; j < 8; ++j) {
    int i = t + 256*j;
    dst[i] = stg[(i >> 4)*17 + (i & 15)];
  }
}

// ================= FC GEMM: [4096,2048] @ [2048,256], split-K=2, 64x64 tiles, 4x4 micro-tile
__global__ __launch_bounds__(256) void k_fc(const float* __restrict__ C,
    const float* __restrict__ fcw, float* __restrict__ P0, float* __restrict__ P1) {
  __shared__ float As[32][68];
  __shared__ float Bs[32][68];
  const int t = threadIdx.x;
  const int r0 = blockIdx.x * 64;
  const int nc = blockIdx.y * 64;
  const int kbase = blockIdx.z * 1024;
  float* __restrict__ P = blockIdx.z ? P1 : P0;
  const int tx = t & 15, ty = t >> 4;
  float acc[4][4];
  #pragma unroll
  for (int i = 0; i < 4; ++i)
    #pragma unroll
    for (int j = 0; j < 4; ++j) acc[i][j] = 0.f;
  const int ia0 = t*2, ia1 = t*2 + 1;
  for (int c = 0; c < 32; ++c) {
    const int k0 = kbase + c*32;
    __syncthreads();
    #pragma unroll
    for (int j = 0; j < 2; ++j) {
      int idx = (j ? ia1 : ia0);
      int row = idx >> 3, kq = idx & 7;
      float4 v = *(const float4*)&C[(size_t)(r0+row)*2048 + k0 + kq*4];
      As[kq*4+0][row] = v.x; As[kq*4+1][row] = v.y;
      As[kq*4+2][row] = v.z; As[kq*4+3][row] = v.w;
    }
    #pragma unroll
    for (int j = 0; j < 2; ++j) {
      int idx = (j ? ia1 : ia0);
      int krow = idx >> 4, c4 = idx & 15;
      float4 v = *(const float4*)&fcw[(size_t)(k0+krow)*256 + nc + c4*4];
      *(float4*)&Bs[krow][c4*4] = v;
    }
    __syncthreads();
    #pragma unroll 8
    for (int k = 0; k < 32; ++k) {
      float4 av = *(const float4*)&As[k][ty*4];
      float4 bv = *(const float4*)&Bs[k][tx*4];
      float a[4] = {av.x, av.y, av.z, av.w};
      float bbv[4] = {bv.x, bv.y, bv.z, bv.w};
      #pragma unroll
      for (int i = 0; i < 4; ++i)
        #pragma unroll
        for (int j = 0; j < 4; ++j)
          acc[i][j] = fmaf(a[i], bbv[j], acc[i][j]);
    }
  }
  #pragma unroll
  for (int i = 0; i < 4; ++i) {
    float4 v = make_float4(acc[i][0], acc[i][1], acc[i][2], acc[i][3]);
    *(float4*)&P[(size_t)(r0 + ty*4 + i)*256 + nc + tx*4] = v;
  }
}

// ================= gate: feat = P0+P1+fcb; logits; top-2 softmax; expert lists
__global__ __launch_bounds__(256) void k_gate(const float* __restrict__ P0,
    const float* __restrict__ P1, const float* __restrict__ fcb,
    const float* __restrict__ gw, const float* __restrict__ gb,
    float* __restrict__ feat, int* __restrict__ cnt, float* __restrict__ gsum,
    int* __restrict__ lrow, float* __restrict__ lg) {
  __shared__ float ft[16][256];
  __shared__ float lgs[16][16];
  __shared__ float gwl[4096];
  const int t = threadIdx.x;
  const int r0 = blockIdx.x * 16;
  for (int i = t; i < 4096; i += 256) gwl[i] = gw[i];
  float bb = fcb[t];
  #pragma unroll
  for (int r = 0; r < 16; ++r) {
    size_t off = (size_t)(r0+r)*256 + t;
    float v = P0[off] + P1[off] + bb;
    ft[r][t] = v;
    feat[off] = v;
  }
  __syncthreads();
  {
    int r = t >> 4, e = t & 15;
    float s = gb[e];
    for (int k = 0; k < 256; ++k) s = fmaf(ft[r][k], gwl[k*16 + e], s);
    lgs[r][e] = s;
  }
  __syncthreads();
  if (t < 16) {
    int r = t;
    float v1 = -3.402823e38f, v2 = -3.402823e38f;
    int i1 = 0, i2 = 0;
    for (int e = 0; e < 16; ++e) {
      float v = lgs[r][e];
      if (v > v1)      { v2 = v1; i2 = i1; v1 = v; i1 = e; }
      else if (v > v2) { v2 = v;  i2 = e; }
    }
    float ex = __expf(v2 - v1);
    float g1 = 1.f / (1.f + ex);
    float g2 = ex  / (1.f + ex);
    int row = r0 + r;
    int p1 = atomicAdd(&cnt[i1], 1); lrow[i1*4096 + p1] = row; lg[i1*4096 + p1] = g1;
    int p2 = atomicAdd(&cnt[i2], 1); lrow[i2*4096 + p2] = row; lg[i2*4096 + p2] = g2;
    atomicAdd(&gsum[i1], g1);
    atomicAdd(&gsum[i2], g2);
  }
}

// ================= MoE v3: 32-row tiles x split-K(4), bf16x2 MFMA, packed weights
// blockIdx.z = kgroup (2 h-chunks of 128 each). Partial g*eo atomicAdd; z==0 adds g*b2.
__global__ __launch_bounds__(256) void k_moe(const float* __restrict__ feat,
    const unsigned short* __restrict__ w1th, const unsigned short* __restrict__ w1tl,
    const unsigned short* __restrict__ w2th, const unsigned short* __restrict__ w2tl,
    const float* __restrict__ eb1, const float* __restrict__ eb2,
    const int* __restrict__ cnt, const int* __restrict__ lrow, const float* __restrict__ lgw,
    float* __restrict__ moe) {
  const int e = blockIdx.y;
  const int n_e = cnt[e];
  const int start = blockIdx.x * 32;
  if (start >= n_e) return;
  const int kg = blockIdx.z;
  const int n = min(32, n_e - start);
  __shared__ unsigned short fh[8192], fl[8192];   // [32 rows][256 k] swizzled
  __shared__ unsigned short h1h[4096], h1l[4096]; // [32 rows][128 h] swizzled
  __shared__ int   rws[32];
  __shared__ float gws[32];
  const int t = threadIdx.x;
  if (t < 32) {
    rws[t] = (t < n) ? lrow[e*4096 + start + t] : 0;
    gws[t] = (t < n) ? lgw[e*4096 + start + t] : 0.f;
  }
  __syncthreads();
  // stage feat rows -> bf16 hi/lo swizzled
  for (int j = 0; j < 32; ++j) {
    float v = (j < n) ? feat[(size_t)rws[j]*256 + t] : 0.f;
    unsigned short h = f2bf(v);
    int us = (j*32 + ((t >> 3) ^ (j & 7)))*8 + (t & 7);
    fh[us] = h; fl[us] = f2bf(v - bf2f(h));
  }
  const int lane = t & 63, wv = t >> 6;
  const int lr = lane & 15, lq = lane >> 4;
  const int rh = wv & 1, qh = wv >> 1;   // rows rh*16..+15; h-quarter/d-half = qh
  const int arow = rh*16 + lr;           // A-frag row this lane supplies
  const int rsw = arow & 7;
  const size_t ewb = (size_t)e << 18;

  f32x4 acc2[8];
  #pragma unroll
  for (int i = 0; i < 8; ++i) acc2[i] = (f32x4){0.f,0.f,0.f,0.f};

  __syncthreads();   // fA ready

  for (int c = kg*2; c < kg*2 + 2; ++c) {
    // ---- phase 1: h1[:, c*128 + qh*64 + ht*16 + lr], K=256 ----
    f32x4 acc1[4];
    #pragma unroll
    for (int i = 0; i < 4; ++i) acc1[i] = (f32x4){0.f,0.f,0.f,0.f};
    #pragma unroll
    for (int ks = 0; ks < 8; ++ks) {
      int aoff = (arow*32 + ((ks*4 + lq) ^ rsw))*8;
      bf16x8 ah = *(const bf16x8*)&fh[aoff];
      bf16x8 al = *(const bf16x8*)&fl[aoff];
      #pragma unroll
      for (int ht = 0; ht < 4; ++ht) {
        int htile = c*8 + qh*4 + ht;
        size_t bo = ewb + ((size_t)(htile*8 + ks)*64 + lane)*8;   // packed: contiguous 1KB/wave
        bf16x8 bh = *(const bf16x8*)&w1th[bo];
        bf16x8 bl = *(const bf16x8*)&w1tl[bo];
        acc1[ht] = __builtin_amdgcn_mfma_f32_16x16x32_bf16(ah, bh, acc1[ht], 0, 0, 0);
        acc1[ht] = __builtin_amdgcn_mfma_f32_16x16x32_bf16(ah, bl, acc1[ht], 0, 0, 0);
        acc1[ht] = __builtin_amdgcn_mfma_f32_16x16x32_bf16(al, bh, acc1[ht], 0, 0, 0);
        acc1[ht] = __builtin_amdgcn_mfma_f32_16x16x32_bf16(al, bl, acc1[ht], 0, 0, 0);
      }
    }
    __syncthreads();   // prev phase-2 readers done with h1
    #pragma unroll
    for (int ht = 0; ht < 4; ++ht) {
      int hloc = qh*64 + ht*16 + lr;
      float bb = eb1[e*1024 + c*128 + hloc];
      #pragma unroll
      for (int r = 0; r < 4; ++r) {
        int orow = rh*16 + lq*4 + r;     // D row = (lane>>4)*4+reg
        float v = fmaxf(acc1[ht][r] + bb, 0.f);
        unsigned short hh = f2bf(v);
        int us = (orow*16 + ((hloc >> 3) ^ (orow & 7)))*8 + (hloc & 7);
        h1h[us] = hh; h1l[us] = f2bf(v - bf2f(hh));
      }
    }
    __syncthreads();   // h1 chunk ready
    // ---- phase 2: eo += h1 @ w2T[:, chunk], K=128 ----
    #pragma unroll
    for (int ks = 0; ks < 4; ++ks) {
      int aoff = (arow*16 + ((ks*4 + lq) ^ rsw))*8;
      bf16x8 ah = *(const bf16x8*)&h1h[aoff];
      bf16x8 al = *(const bf16x8*)&h1l[aoff];
      #pragma unroll
      for (int dt = 0; dt < 8; ++dt) {
        int dtile = qh*8 + dt;
        size_t bo = ewb + ((size_t)(dtile*32 + c*4 + ks)*64 + lane)*8;  // packed
        bf16x8 bh = *(const bf16x8*)&w2th[bo];
        bf16x8 bl = *(const bf16x8*)&w2tl[bo];
        acc2[dt] = __builtin_amdgcn_mfma_f32_16x16x32_bf16(ah, bh, acc2[dt], 0, 0, 0);
        acc2[dt] = __builtin_amdgcn_mfma_f32_16x16x32_bf16(ah, bl, acc2[dt], 0, 0, 0);
        acc2[dt] = __builtin_amdgcn_mfma_f32_16x16x32_bf16(al, bh, acc2[dt], 0, 0, 0);
        acc2[dt] = __builtin_amdgcn_mfma_f32_16x16x32_bf16(al, bl, acc2[dt], 0, 0, 0);
      }
    }
  }
  // epilogue: gate-weighted scatter (bias added once, by kgroup 0)
  #pragma unroll
  for (int dt = 0; dt < 8; ++dt) {
    int d = qh*128 + dt*16 + lr;
    float b2 = (kg == 0) ? eb2[e*256 + d] : 0.f;
    #pragma unroll
    for (int r = 0; r < 4; ++r) {
      int orow = rh*16 + lq*4 + r;
      if (orow < n)
        atomicAdd(&moe[(size_t)rws[orow]*256 + d], gws[orow]*(acc2[dt][r] + b2));
    }
  }
}

// ================= load-balance loss
__global__ void k_lb(const float* __restrict__ gsum, float* __restrict__ out_lb) {
  int t = threadIdx.x;
  float term = 0.f;
  if (t < 16) {
    float D = gsum[t] * (1.f/4096.f);
    term = D * logf(D + 1e-8f);
  }
  #pragma unroll
  for (int o = 8; o > 0; o >>= 1) term += __shfl_down(term, o, 64);
  if (t == 0) *out_lb = term;
}

// ================= LayerNorm(moe + feat) in-place into moe
__global__ __launch_bounds__(256) void k_ln(const float* __restrict__ feat,
    float* __restrict__ moe, const float* __restrict__ g, const float* __restrict__ bp) {
  const int r = blockIdx.x, t = threadIdx.x;
  float v = moe[(size_t)r*256 + t] + feat[(size_t)r*256 + t];
  float s = v, q = v * v;
  #pragma unroll
  for (int o = 32; o > 0; o >>= 1) {
    s += __shfl_down(s, o, 64);
    q += __shfl_down(q, o, 64);
  }
  __shared__ float ss[4], qq[4];
  int wv = t >> 6;
  if ((t & 63) == 0) { ss[wv] = s; qq[wv] = q; }
  __syncthreads();
  float S = ss[0]+ss[1]+ss[2]+ss[3];
  float Q = qq[0]+qq[1]+qq[2]+qq[3];
  float mu  = S * (1.f/256.f);
  float var = Q * (1.f/256.f) - mu*mu;
  float inv = rsqrtf(var + 1e-5f);
  moe[(size_t)r*256 + t] = (v - mu) * inv * g[t] + bp[t];
}

// ================= output GEMM: [4096,256] @ [256,1000] + b
__global__ __launch_bounds__(256) void k_out(const float* __restrict__ y,
    const float* __restrict__ ow, const float* __restrict__ ob,
    float* __restrict__ out) {
  __shared__ float ys[32][256];
  const int t = threadIdx.x;
  const int r0 = blockIdx.x * 32;
  const int c = blockIdx.y * 256 + t;
  for (int i = t; i < 32*256; i += 256) {
    int r = i >> 8, k = i & 255;
    ys[r][k] = y[(size_t)(r0+r)*256 + k];
  }
  __syncthreads();
  if (c >= NCLS) return;
  float acc[32];
  {
    float bb = ob[c];
    #pragma unroll
    for (int r = 0; r < 32; ++r) acc[r] = bb;
  }
  #pragma unroll 4
  for (int k = 0; k < 256; ++k) {
    float wv = ow[(size_t)k*NCLS + c];
    #pragma unroll
    for (int r = 0; r < 32; ++r) acc[r] = fmaf(ys[r][k], wv, acc[r]);
  }
  for (int r = 0; r < 32; ++r) out[(size_t)(r0+r)*NCLS + c] = acc[r];
}

// ================= launch =================
extern "C" void kernel_launch(void* const* d_in, const int* in_sizes, int n_in,
                              void* d_out, int out_size, void* d_ws, size_t ws_size,
                              hipStream_t stream) {
  const float* x   = (const float*)d_in[0];
  const float* c1w = (const float*)d_in[1];
  const float* c1b = (const float*)d_in[2];
  const float* c2w = (const float*)d_in[3];
  const float* c2b = (const float*)d_in[4];
  const float* c3w = (const float*)d_in[5];
  const float* c3b = (const float*)d_in[6];
  const float* fcw = (const float*)d_in[7];
  const float* fcb = (const float*)d_in[8];
  const float* gw  = (const float*)d_in[9];
  const float* gb  = (const float*)d_in[10];
  const float* ew1 = (const float*)d_in[11];
  const float* eb1 = (const float*)d_in[12];
  const float* ew2 = (const float*)d_in[13];
  const float* eb2 = (const float*)d_in[14];
  const float* lng = (const float*)d_in[15];
  const float* lnb = (const float*)d_in[16];
  const float* ow  = (const float*)d_in[17];
  const float* ob  = (const float*)d_in[18];
  char* ws = (char*)d_ws;
  float* Bb   = (float*)(ws + OFF_B);
  float* P0   = (float*)(ws + OFF_P0);
  float* P1   = (float*)(ws + OFF_P1);
  float* C    = (float*)(ws + OFF_C);
  unsigned short* wBh = (unsigned short*)(ws + OFF_C);     // aliases C (C written after conv12)
  unsigned short* wBl = (unsigned short*)(ws + OFF_WBL);
  unsigned short* wAh = (unsigned short*)(ws + OFF_FEAT);  // aliases feat (written later)
  unsigned short* wAl = (unsigned short*)(ws + OFF_WAL);
  unsigned short* w1th = (unsigned short*)(ws + OFF_W1TH); // region dead after conv3
  unsigned short* w1tl = (unsigned short*)(ws + OFF_W1TL);
  unsigned short* w2th = (unsigned short*)(ws + OFF_W2TH);
  unsigned short* w2tl = (unsigned short*)(ws + OFF_W2TL);
  float* feat = (float*)(ws + OFF_FEAT);
  float* moe  = (float*)(ws + OFF_MOE);
  int*   cnt  = (int*)(ws + OFF_CNT);
  float* gsum = (float*)(ws + OFF_GSUM);
  int*   lrow = (int*)(ws + OFF_LROW);
  float* lgv  = (float*)(ws + OFF_LG);
  float* outp = (float*)d_out;

  hipMemsetAsync(ws + OFF_MOE, 0, 4194304 + 128, stream);

  hipLaunchKernelGGL(k_wt2b,   dim3(72),      dim3(256), 0, stream, c2w, wBh, wBl);
  hipLaunchKernelGGL(k_wt3b,   dim3(288),     dim3(256), 0, stream, c3w, wAh, wAl);
  hipLaunchKernelGGL(k_conv12, dim3(4096),    dim3(512), 0, stream, x, c1w, c1b, wBh, wBl, c2b, Bb);
  hipLaunchKernelGGL(k_conv3,  dim3(4096),    dim3(256), 0, stream, Bb, wAh, wAl, c3b, C);
  // Bb dead now -> build MoE packed/split weights in its region
  hipLaunchKernelGGL(k_pack,   dim3(16, 4, 16), dim3(256), 0, stream, ew1, w1th, w1tl, 256, 1024);
  hipLaunchKernelGGL(k_pack,   dim3(4, 16, 16), dim3(256), 0, stream, ew2, w2th, w2tl, 1024, 256);
  hipLaunchKernelGGL(k_fc,     dim3(64, 4, 2),dim3(256), 0, stream, C, fcw, P0, P1);
  hipLaunchKernelGGL(k_gate,   dim3(256),     dim3(256), 0, stream, P0, P1, fcb, gw, gb,
                     feat, cnt, gsum, lrow, lgv);
  hipLaunchKernelGGL(k_moe,    dim3(128, 16, 4), dim3(256), 0, stream, feat, w1th, w1tl, w2th, w2tl,
                     eb1, eb2, cnt, lrow, lgv, moe);
  hipLaunchKernelGGL(k_lb,     dim3(1),       dim3(64),  0, stream, gsum, outp + (size_t)NB*NCLS);
  hipLaunchKernelGGL(k_ln,     dim3(4096),    dim3(256), 0, stream, feat, moe, lng, lnb);
  hipLaunchKernelGGL(k_out,    dim3(128, 4),  dim3(256), 0, stream, moe, ow, ob, outp);
}

// Round 11
// 891.711 us; speedup vs baseline: 3.9485x; 1.0349x over previous
//
#include <hip/hip_runtime.h>
#include <hip/hip_bf16.h>

typedef short bf16x8 __attribute__((ext_vector_type(8)));
typedef float f32x4 __attribute__((ext_vector_type(4)));

// ---------------- problem sizes ----------------
#define NB   4096
#define NEXP 16
#define DDIM 256
#define HDIM 1024
#define NCLS 1000

// ---------------- workspace layout (bytes) ----------------
#define OFF_B    ((size_t)0)
#define OFF_P0   ((size_t)0)           // f32 [4096][256] FC partial (K half 0)
#define OFF_P1   ((size_t)4194304)     // f32 [4096][256] FC partial (K half 1)
// MoE packed/split weights (written after conv3, when Bb is dead; after P0/P1):
#define OFF_W1TH ((size_t)8388608)     // bf16 packed [16][64 ht][8 ks][64 lane][8]  8 MB
#define OFF_W1TL ((size_t)16777216)
#define OFF_W2TH ((size_t)25165824)    // bf16 packed [16][16 dt][32 ks][64 lane][8] 8 MB
#define OFF_W2TL ((size_t)33554432)
#define OFF_C    ((size_t)67108864)    // conv3 out f32 [4096][2048]; ALSO wBh/wBl (74 KB) before conv12
#define OFF_WBL  ((size_t)67145728)    // OFF_C + 36864
#define OFF_FEAT ((size_t)100663296)   // f32 [4096][256]; ALSO wAh/wAl (288 KB) before k_gate
#define OFF_WAL  ((size_t)100810752)   // OFF_FEAT + 147456
#define OFF_MOE  ((size_t)104857600)   // f32 [4096][256]
#define OFF_CNT  ((size_t)109051904)   // int [16]
#define OFF_GSUM ((size_t)109051968)   // f32 [16]
#define OFF_LROW ((size_t)109052032)   // int [16][4096]
#define OFF_LG   ((size_t)109314176)   // f32 [16][4096]

__device__ inline unsigned short f2bf(float v) {
  __hip_bfloat16 h = __float2bfloat16(v);
  return *(unsigned short*)&h;
}
__device__ inline float bf2f(unsigned short u) {
  union { unsigned int i; float f; } c; c.i = ((unsigned int)u) << 16; return c.f;
}

// ====== conv2 weight prep: c2w[oc][ic][tap] -> wBh/wBl[tap][oc][ic] bf16 hi/lo ======
__global__ __launch_bounds__(256) void k_wt2b(const float* __restrict__ w,
    unsigned short* __restrict__ wBh, unsigned short* __restrict__ wBl) {
  int i = blockIdx.x*256 + threadIdx.x;   // over 9*64*32 = 18432
  if (i >= 9*64*32) return;
  int ic = i & 31, rem = i >> 5;
  int oc = rem & 63, tap = rem >> 6;
  float v = w[(oc*32 + ic)*9 + tap];
  unsigned short h = f2bf(v);
  wBh[i] = h;
  wBl[i] = f2bf(v - bf2f(h));
}

// ====== MFMA-native weight pack: in[e][R=k][C=n] -> packed[e][n/16][R/32][64 lane][8] hi/lo
// packed element (ntile,ks,lane,j) = in[e][ks*32+(lane>>4)*8+j][ntile*16+(lane&15)]
__global__ __launch_bounds__(256) void k_pack(const float* __restrict__ in,
    unsigned short* __restrict__ oh, unsigned short* __restrict__ ol, int R, int C) {
  __shared__ float tile[64][65];
  const int t = threadIdx.x;
  const int e = blockIdx.z;
  const size_t eb = (size_t)e * R * C;
  const int c0 = blockIdx.x*64, r0 = blockIdx.y*64;
  const int cc = t & 63, r4 = t >> 6;
  #pragma unroll
  for (int j = 0; j < 16; ++j) {
    int rr = r4 + j*4;
    tile[rr][cc] = in[eb + (size_t)(r0+rr)*C + c0 + cc];
  }
  __syncthreads();
  const int K32 = R >> 5;
  #pragma unroll
  for (int j = 0; j < 16; ++j) {
    int idx = t + j*256;
    int jin = idx & 7, lane = (idx >> 3) & 63, ksl = (idx >> 9) & 1, ntl = idx >> 10;
    int kl = ksl*32 + ((lane >> 4) << 3) + jin;
    int nl = ntl*16 + (lane & 15);
    float v = tile[kl][nl];
    unsigned short h = f2bf(v);
    size_t o = eb + ((size_t)(((c0 >> 4) + ntl)*K32 + (r0 >> 5) + ksl)*64 + lane)*8 + jin;
    oh[o] = h;
    ol[o] = f2bf(v - bf2f(h));
  }
}

// ================= fused conv1(vector) + conv2(bf16x2 MFMA, 3-term) per image =============
__global__ __launch_bounds__(512, 4) void k_conv12(const float* __restrict__ x,
    const float* __restrict__ w1, const float* __restrict__ b1,
    const unsigned short* __restrict__ wBh, const unsigned short* __restrict__ wBl,
    const float* __restrict__ b2, float* __restrict__ outB) {
  __shared__ float xs[3][34][36];           // padded input image (14.7 KB)
  __shared__ unsigned short ishB[2][10368]; // [hi/lo][pl*32+ic swizzled] (41.5 KB); reused for store stage
  __shared__ float ws1[864];
  __shared__ float bs1[32];
  __shared__ float bs2[64];
  const int t = threadIdx.x;
  const int img = blockIdx.x;
  for (int i = t; i < 3*34*36; i += 512) ((float*)xs)[i] = 0.f;
  {
    unsigned int* z = (unsigned int*)&ishB[0][0];
    for (int i = t; i < 10368; i += 512) z[i] = 0u;
  }
  __syncthreads();
  for (int i = t; i < 3072; i += 512) {
    int ic = i >> 10, rem = i & 1023, y = rem >> 5, xx = rem & 31;
    xs[ic][y+1][xx+1] = x[(size_t)img*3072 + i];
  }
  for (int i = t; i < 864; i += 512) ws1[i] = w1[i];
  if (t < 32) bs1[t] = b1[t];
  else if (t >= 64 && t < 128) bs2[t-64] = b2[t-64];
  __syncthreads();
  // ---- conv1 + pool + relu -> ishB hi/lo swizzled ----
  {
    const int p = t & 255, grp = t >> 8;
    const int px = p & 15, py = p >> 4;
    const int pl = (py+1)*18 + (px+1);
    float win[3][4][4];
    #pragma unroll
    for (int ic = 0; ic < 3; ++ic)
      #pragma unroll
      for (int r = 0; r < 4; ++r) {
        float2 a  = *(const float2*)&xs[ic][2*py+r][2*px];
        float2 c2 = *(const float2*)&xs[ic][2*py+r][2*px+2];
        win[ic][r][0]=a.x; win[ic][r][1]=a.y; win[ic][r][2]=c2.x; win[ic][r][3]=c2.y;
      }
    for (int occ = grp*16; occ < grp*16 + 16; occ += 8) {
      float acc[8][4];
      #pragma unroll
      for (int j = 0; j < 8; ++j) { float bb = bs1[occ+j]; acc[j][0]=bb;acc[j][1]=bb;acc[j][2]=bb;acc[j][3]=bb; }
      #pragma unroll
      for (int ic = 0; ic < 3; ++ic) {
        #pragma unroll
        for (int j = 0; j < 8; ++j) {
          const float* wp = &ws1[(occ+j)*27 + ic*9];
          float wv[9];
          #pragma unroll
          for (int q = 0; q < 9; ++q) wv[q] = wp[q];
          #pragma unroll
          for (int ry = 0; ry < 2; ++ry)
            #pragma unroll
            for (int rx = 0; rx < 2; ++rx) {
              float s = acc[j][ry*2+rx];
              #pragma unroll
              for (int ky = 0; ky < 3; ++ky)
                #pragma unroll
                for (int kx = 0; kx < 3; ++kx)
                  s = fmaf(wv[ky*3+kx], win[ic][ry+ky][rx+kx], s);
              acc[j][ry*2+rx] = s;
            }
        }
      }
      #pragma unroll
      for (int j = 0; j < 8; ++j) {
        float m = fmaxf(fmaxf(acc[j][0],acc[j][1]), fmaxf(acc[j][2],acc[j][3]));
        m = fmaxf(m, 0.f);
        unsigned short h = f2bf(m);
        unsigned short l = f2bf(m - bf2f(h));
        int ic2 = occ + j;
        int sl = pl*4 + ((ic2 >> 3) ^ ((pl >> 1) & 3));
        int us = (sl << 3) | (ic2 & 7);
        ishB[0][us] = h; ishB[1][us] = l;
      }
    }
  }
  __syncthreads();
  // ---- conv2 bf16x2 MFMA (3-term: hh, hl, lh) + fused pool + relu ----
  {
    const int lane = t & 63, wvv = t >> 6;
    const int lr = lane & 15, lq = lane >> 4;
    const int mtp = (wvv & 1)*2;
    const int rq = wvv >> 1;
    f32x4 acc[2][4];
    #pragma unroll
    for (int i = 0; i < 2; ++i)
      #pragma unroll
      for (int j = 0; j < 4; ++j) acc[i][j] = (f32x4){0.f,0.f,0.f,0.f};
    bf16x8 nAh[2], nAl[2];
    #pragma unroll
    for (int m = 0; m < 2; ++m) {
      int off = (((mtp+m)*16 + lr) << 5) + lq*8;
      nAh[m] = *(const bf16x8*)&wBh[off];
      nAl[m] = *(const bf16x8*)&wBl[off];
    }
    #pragma unroll
    for (int tap = 0; tap < 9; ++tap) {
      bf16x8 ah0 = nAh[0], al0 = nAl[0], ah1 = nAh[1], al1 = nAl[1];
      if (tap < 8) {
        #pragma unroll
        for (int m = 0; m < 2; ++m) {
          int off = (((tap+1)*64 + (mtp+m)*16 + lr) << 5) + lq*8;
          nAh[m] = *(const bf16x8*)&wBh[off];
          nAl[m] = *(const bf16x8*)&wBl[off];
        }
      }
      const int dy = tap/3, dx = tap - dy*3;
      #pragma unroll
      for (int j = 0; j < 4; ++j) {
        int pl = (rq*4 + j + dy)*18 + lr + dx;
        int sl = pl*4 + (lq ^ ((pl >> 1) & 3));
        bf16x8 bh = *(const bf16x8*)&ishB[0][sl << 3];
        bf16x8 bl = *(const bf16x8*)&ishB[1][sl << 3];
        acc[0][j] = __builtin_amdgcn_mfma_f32_16x16x32_bf16(ah0, bh, acc[0][j], 0, 0, 0);
        acc[1][j] = __builtin_amdgcn_mfma_f32_16x16x32_bf16(ah1, bh, acc[1][j], 0, 0, 0);
        acc[0][j] = __builtin_amdgcn_mfma_f32_16x16x32_bf16(ah0, bl, acc[0][j], 0, 0, 0);
        acc[1][j] = __builtin_amdgcn_mfma_f32_16x16x32_bf16(ah1, bl, acc[1][j], 0, 0, 0);
        acc[0][j] = __builtin_amdgcn_mfma_f32_16x16x32_bf16(al0, bh, acc[0][j], 0, 0, 0);
        acc[1][j] = __builtin_amdgcn_mfma_f32_16x16x32_bf16(al1, bh, acc[1][j], 0, 0, 0);
      }
    }
    __syncthreads();
    float* ps = (float*)&ishB[0][0];   // [64 oc][65] padded
    #pragma unroll
    for (int m = 0; m < 2; ++m)
      #pragma unroll
      for (int k = 0; k < 2; ++k)
        #pragma unroll
        for (int r = 0; r < 4; ++r) {
          float v = fmaxf(acc[m][2*k][r], acc[m][2*k+1][r]);
          v = fmaxf(v, __shfl_xor(v, 1, 64));
          if ((lr & 1) == 0) {
            int oc = (mtp + m)*16 + lq*4 + r;
            int Y = rq*2 + k, X = lr >> 1;
            ps[oc*65 + Y*8 + X] = fmaxf(v + bs2[oc], 0.f);
          }
        }
    __syncthreads();
    float* op = outB + (size_t)img*4096;
    #pragma unroll
    for (int jj = 0; jj < 8; ++jj) {
      int i = jj*512 + t;
      op[i] = ps[(i >> 6)*65 + (i & 63)];
    }
  }
}

// ================= conv3 weight prep: c3w[oc][ic][tap] -> wAh/wAl[tap][oc][ic] bf16 hi/lo
__global__ __launch_bounds__(256) void k_wt3b(const float* __restrict__ w,
    unsigned short* __restrict__ wAh, unsigned short* __restrict__ wAl) {
  int i = blockIdx.x*256 + threadIdx.x;   // over 9*128*64 = 73728
  if (i >= 9*128*64) return;
  int ic = i & 63, rem = i >> 6;
  int oc = rem & 127, tap = rem >> 7;
  float v = w[(oc*64 + ic)*9 + tap];
  unsigned short h = f2bf(v);
  wAh[i] = h;
  wAl[i] = f2bf(v - bf2f(h));
}

// ================= conv3 v4: bf16x2 split MFMA (3-term) implicit GEMM ==================
__global__ __launch_bounds__(256) void k_conv3(const float* __restrict__ inB,
    const unsigned short* __restrict__ wAh, const unsigned short* __restrict__ wAl,
    const float* __restrict__ bias, float* __restrict__ outC) {
  __shared__ unsigned short ish[2][6400];
  const int t = threadIdx.x;
  const int img = blockIdx.x;
  {
    unsigned int* z = (unsigned int*)&ish[0][0];
    #pragma unroll
    for (int j = 0; j < 25; ++j) z[t + 256*j] = 0u;
  }
  __syncthreads();
  {
    const float* src = inB + (size_t)img*4096;
    #pragma unroll
    for (int j = 0; j < 16; ++j) {
      int f = t + 256*j;
      int ic = f >> 6, p = f & 63;
      int pl = ((p >> 3) + 1)*10 + (p & 7) + 1;
      float v = src[f];
      unsigned short h = f2bf(v);
      unsigned short l = f2bf(v - bf2f(h));
      int u = pl*64 + ic;
      int us = (((u >> 3) ^ (pl & 7)) << 3) | (u & 7);
      ish[0][us] = h; ish[1][us] = l;
    }
  }
  __syncthreads();

  const int lane = t & 63, wid = t >> 6;
  const int lr = lane & 15, lq = lane >> 4;
  const int mt0 = wid*2;
  const int yb = lr >> 3, xb = lr & 7;

  f32x4 acc[2][4];
  #pragma unroll
  for (int i = 0; i < 2; ++i)
    #pragma unroll
    for (int j = 0; j < 4; ++j) acc[i][j] = (f32x4){0.f,0.f,0.f,0.f};

  for (int tap = 0; tap < 9; ++tap) {
    const int dy = tap/3, dx = tap - dy*3;
    #pragma unroll
    for (int kc = 0; kc < 2; ++kc) {
      const int kb = kc*32 + lq*8;
      const int wbase = ((tap << 7) << 6) + kb;
      bf16x8 a0h = *(const bf16x8*)&wAh[wbase + ((mt0*16 + lr) << 6)];
      bf16x8 a0l = *(const bf16x8*)&wAl[wbase + ((mt0*16 + lr) << 6)];
      bf16x8 a1h = *(const bf16x8*)&wAh[wbase + (((mt0+1)*16 + lr) << 6)];
      bf16x8 a1l = *(const bf16x8*)&wAl[wbase + (((mt0+1)*16 + lr) << 6)];
      #pragma unroll
      for (int nt = 0; nt < 4; ++nt) {
        const int pl = (2*nt + yb + dy)*10 + xb + dx;
        const int u = pl*64 + kb;
        const int us = (((u >> 3) ^ (pl & 7)) << 3);
        bf16x8 bh = *(const bf16x8*)&ish[0][us];
        bf16x8 bl = *(const bf16x8*)&ish[1][us];
        acc[0][nt] = __builtin_amdgcn_mfma_f32_16x16x32_bf16(a0h, bh, acc[0][nt], 0, 0, 0);
        acc[0][nt] = __builtin_amdgcn_mfma_f32_16x16x32_bf16(a0h, bl, acc[0][nt], 0, 0, 0);
        acc[0][nt] = __builtin_amdgcn_mfma_f32_16x16x32_bf16(a0l, bh, acc[0][nt], 0, 0, 0);
        acc[1][nt] = __builtin_amdgcn_mfma_f32_16x16x32_bf16(a1h, bh, acc[1][nt], 0, 0, 0);
        acc[1][nt] = __builtin_amdgcn_mfma_f32_16x16x32_bf16(a1h, bl, acc[1][nt], 0, 0, 0);
        acc[1][nt] = __builtin_amdgcn_mfma_f32_16x16x32_bf16(a1l, bh, acc[1][nt], 0, 0, 0);
      }
    }
  }
  __syncthreads();
  float* stg = (float*)&ish[0][0];   // [128 oc][17]
  #pragma unroll
  for (int mtl = 0; mtl < 2; ++mtl)
    #pragma unroll
    for (int nt = 0; nt < 4; ++nt)
      #pragma unroll
      for (int r = 0; r < 4; ++r) {
        float v = acc[mtl][nt][r];
        v = fmaxf(v, __shfl_xor(v, 1, 64));
        v = fmaxf(v, __shfl_xor(v, 8, 64));
        if ((lane & 9) == 0) {
          int oc = (mt0 + mtl)*16 + lq*4 + r;
          int pix = nt*4 + (xb >> 1);
          stg[oc*17 + pix] = fmaxf(v + bias[oc], 0.f);
        }
      }
  __syncthreads();
  float* dst = outC + (size_t)img*2048;
  #pragma unroll
  for (int j = 0; j < 8; ++j) {
    int i = t + 256*j;
    dst[i] = stg[(i >> 4)*17 + (i & 15)];
  }
}

// ================= FC GEMM: [4096,2048] @ [2048,256], split-K=2, 64x64 tiles, 4x4 micro-tile
__global__ __launch_bounds__(256) void k_fc(const float* __restrict__ C,
    const float* __restrict__ fcw, float* __restrict__ P0, float* __restrict__ P1) {
  __shared__ float As[32][68];
  __shared__ float Bs[32][68];
  const int t = threadIdx.x;
  const int r0 = blockIdx.x * 64;
  const int nc = blockIdx.y * 64;
  const int kbase = blockIdx.z * 1024;
  float* __restrict__ P = blockIdx.z ? P1 : P0;
  const int tx = t & 15, ty = t >> 4;
  float acc[4][4];
  #pragma unroll
  for (int i = 0; i < 4; ++i)
    #pragma unroll
    for (int j = 0; j < 4; ++j) acc[i][j] = 0.f;
  const int ia0 = t*2, ia1 = t*2 + 1;
  for (int c = 0; c < 32; ++c) {
    const int k0 = kbase + c*32;
    __syncthreads();
    #pragma unroll
    for (int j = 0; j < 2; ++j) {
      int idx = (j ? ia1 : ia0);
      int row = idx >> 3, kq = idx & 7;
      float4 v = *(const float4*)&C[(size_t)(r0+row)*2048 + k0 + kq*4];
      As[kq*4+0][row] = v.x; As[kq*4+1][row] = v.y;
      As[kq*4+2][row] = v.z; As[kq*4+3][row] = v.w;
    }
    #pragma unroll
    for (int j = 0; j < 2; ++j) {
      int idx = (j ? ia1 : ia0);
      int krow = idx >> 4, c4 = idx & 15;
      float4 v = *(const float4*)&fcw[(size_t)(k0+krow)*256 + nc + c4*4];
      *(float4*)&Bs[krow][c4*4] = v;
    }
    __syncthreads();
    #pragma unroll 8
    for (int k = 0; k < 32; ++k) {
      float4 av = *(const float4*)&As[k][ty*4];
      float4 bv = *(const float4*)&Bs[k][tx*4];
      float a[4] = {av.x, av.y, av.z, av.w};
      float bbv[4] = {bv.x, bv.y, bv.z, bv.w};
      #pragma unroll
      for (int i = 0; i < 4; ++i)
        #pragma unroll
        for (int j = 0; j < 4; ++j)
          acc[i][j] = fmaf(a[i], bbv[j], acc[i][j]);
    }
  }
  #pragma unroll
  for (int i = 0; i < 4; ++i) {
    float4 v = make_float4(acc[i][0], acc[i][1], acc[i][2], acc[i][3]);
    *(float4*)&P[(size_t)(r0 + ty*4 + i)*256 + nc + tx*4] = v;
  }
}

// ================= gate: feat = P0+P1+fcb; logits; top-2 softmax; expert lists
__global__ __launch_bounds__(256) void k_gate(const float* __restrict__ P0,
    const float* __restrict__ P1, const float* __restrict__ fcb,
    const float* __restrict__ gw, const float* __restrict__ gb,
    float* __restrict__ feat, int* __restrict__ cnt, float* __restrict__ gsum,
    int* __restrict__ lrow, float* __restrict__ lg) {
  __shared__ float ft[16][256];
  __shared__ float lgs[16][16];
  __shared__ float gwl[4096];
  const int t = threadIdx.x;
  const int r0 = blockIdx.x * 16;
  for (int i = t; i < 4096; i += 256) gwl[i] = gw[i];
  float bb = fcb[t];
  #pragma unroll
  for (int r = 0; r < 16; ++r) {
    size_t off = (size_t)(r0+r)*256 + t;
    float v = P0[off] + P1[off] + bb;
    ft[r][t] = v;
    feat[off] = v;
  }
  __syncthreads();
  {
    int r = t >> 4, e = t & 15;
    float s = gb[e];
    for (int k = 0; k < 256; ++k) s = fmaf(ft[r][k], gwl[k*16 + e], s);
    lgs[r][e] = s;
  }
  __syncthreads();
  if (t < 16) {
    int r = t;
    float v1 = -3.402823e38f, v2 = -3.402823e38f;
    int i1 = 0, i2 = 0;
    for (int e = 0; e < 16; ++e) {
      float v = lgs[r][e];
      if (v > v1)      { v2 = v1; i2 = i1; v1 = v; i1 = e; }
      else if (v > v2) { v2 = v;  i2 = e; }
    }
    float ex = __expf(v2 - v1);
    float g1 = 1.f / (1.f + ex);
    float g2 = ex  / (1.f + ex);
    int row = r0 + r;
    int p1 = atomicAdd(&cnt[i1], 1); lrow[i1*4096 + p1] = row; lg[i1*4096 + p1] = g1;
    int p2 = atomicAdd(&cnt[i2], 1); lrow[i2*4096 + p2] = row; lg[i2*4096 + p2] = g2;
    atomicAdd(&gsum[i1], g1);
    atomicAdd(&gsum[i2], g2);
  }
}

// ================= MoE v4: 32-row tiles x split-K(8), bf16x2 MFMA 3-term, packed weights
// blockIdx.z = chunk c (128 h each). Partial g*eo atomicAdd; z==0 adds g*b2.
__global__ __launch_bounds__(256) void k_moe(const float* __restrict__ feat,
    const unsigned short* __restrict__ w1th, const unsigned short* __restrict__ w1tl,
    const unsigned short* __restrict__ w2th, const unsigned short* __restrict__ w2tl,
    const float* __restrict__ eb1, const float* __restrict__ eb2,
    const int* __restrict__ cnt, const int* __restrict__ lrow, const float* __restrict__ lgw,
    float* __restrict__ moe) {
  const int e = blockIdx.y;
  const int n_e = cnt[e];
  const int start = blockIdx.x * 32;
  if (start >= n_e) return;
  const int c = blockIdx.z;        // h-chunk this block owns
  const int n = min(32, n_e - start);
  __shared__ unsigned short fh[8192], fl[8192];   // [32 rows][256 k] swizzled
  __shared__ unsigned short h1h[4096], h1l[4096]; // [32 rows][128 h] swizzled
  __shared__ int   rws[32];
  __shared__ float gws[32];
  const int t = threadIdx.x;
  if (t < 32) {
    rws[t] = (t < n) ? lrow[e*4096 + start + t] : 0;
    gws[t] = (t < n) ? lgw[e*4096 + start + t] : 0.f;
  }
  __syncthreads();
  // stage feat rows -> bf16 hi/lo swizzled
  for (int j = 0; j < 32; ++j) {
    float v = (j < n) ? feat[(size_t)rws[j]*256 + t] : 0.f;
    unsigned short h = f2bf(v);
    int us = (j*32 + ((t >> 3) ^ (j & 7)))*8 + (t & 7);
    fh[us] = h; fl[us] = f2bf(v - bf2f(h));
  }
  const int lane = t & 63, wv = t >> 6;
  const int lr = lane & 15, lq = lane >> 4;
  const int rh = wv & 1, qh = wv >> 1;   // rows rh*16..+15; h-quarter/d-half = qh
  const int arow = rh*16 + lr;           // A-frag row this lane supplies
  const int rsw = arow & 7;
  const size_t ewb = (size_t)e << 18;

  f32x4 acc2[8];
  #pragma unroll
  for (int i = 0; i < 8; ++i) acc2[i] = (f32x4){0.f,0.f,0.f,0.f};

  __syncthreads();   // fA ready

  {
    // ---- phase 1: h1[:, c*128 + qh*64 + ht*16 + lr], K=256 ----
    f32x4 acc1[4];
    #pragma unroll
    for (int i = 0; i < 4; ++i) acc1[i] = (f32x4){0.f,0.f,0.f,0.f};
    #pragma unroll
    for (int ks = 0; ks < 8; ++ks) {
      int aoff = (arow*32 + ((ks*4 + lq) ^ rsw))*8;
      bf16x8 ah = *(const bf16x8*)&fh[aoff];
      bf16x8 al = *(const bf16x8*)&fl[aoff];
      #pragma unroll
      for (int ht = 0; ht < 4; ++ht) {
        int htile = c*8 + qh*4 + ht;
        size_t bo = ewb + ((size_t)(htile*8 + ks)*64 + lane)*8;   // packed: contiguous 1KB/wave
        bf16x8 bh = *(const bf16x8*)&w1th[bo];
        bf16x8 bl = *(const bf16x8*)&w1tl[bo];
        acc1[ht] = __builtin_amdgcn_mfma_f32_16x16x32_bf16(ah, bh, acc1[ht], 0, 0, 0);
        acc1[ht] = __builtin_amdgcn_mfma_f32_16x16x32_bf16(ah, bl, acc1[ht], 0, 0, 0);
        acc1[ht] = __builtin_amdgcn_mfma_f32_16x16x32_bf16(al, bh, acc1[ht], 0, 0, 0);
      }
    }
    __syncthreads();
    #pragma unroll
    for (int ht = 0; ht < 4; ++ht) {
      int hloc = qh*64 + ht*16 + lr;
      float bb = eb1[e*1024 + c*128 + hloc];
      #pragma unroll
      for (int r = 0; r < 4; ++r) {
        int orow = rh*16 + lq*4 + r;     // D row = (lane>>4)*4+reg
        float v = fmaxf(acc1[ht][r] + bb, 0.f);
        unsigned short hh = f2bf(v);
        int us = (orow*16 + ((hloc >> 3) ^ (orow & 7)))*8 + (hloc & 7);
        h1h[us] = hh; h1l[us] = f2bf(v - bf2f(hh));
      }
    }
    __syncthreads();   // h1 chunk ready
    // ---- phase 2: eo += h1 @ w2T[:, chunk], K=128 ----
    #pragma unroll
    for (int ks = 0; ks < 4; ++ks) {
      int aoff = (arow*16 + ((ks*4 + lq) ^ rsw))*8;
      bf16x8 ah = *(const bf16x8*)&h1h[aoff];
      bf16x8 al = *(const bf16x8*)&h1l[aoff];
      #pragma unroll
      for (int dt = 0; dt < 8; ++dt) {
        int dtile = qh*8 + dt;
        size_t bo = ewb + ((size_t)(dtile*32 + c*4 + ks)*64 + lane)*8;  // packed
        bf16x8 bh = *(const bf16x8*)&w2th[bo];
        bf16x8 bl = *(const bf16x8*)&w2tl[bo];
        acc2[dt] = __builtin_amdgcn_mfma_f32_16x16x32_bf16(ah, bh, acc2[dt], 0, 0, 0);
        acc2[dt] = __builtin_amdgcn_mfma_f32_16x16x32_bf16(ah, bl, acc2[dt], 0, 0, 0);
        acc2[dt] = __builtin_amdgcn_mfma_f32_16x16x32_bf16(al, bh, acc2[dt], 0, 0, 0);
      }
    }
  }
  // epilogue: gate-weighted scatter (bias added once, by chunk 0)
  #pragma unroll
  for (int dt = 0; dt < 8; ++dt) {
    int d = qh*128 + dt*16 + lr;
    float b2 = (c == 0) ? eb2[e*256 + d] : 0.f;
    #pragma unroll
    for (int r = 0; r < 4; ++r) {
      int orow = rh*16 + lq*4 + r;
      if (orow < n)
        atomicAdd(&moe[(size_t)rws[orow]*256 + d], gws[orow]*(acc2[dt][r] + b2));
    }
  }
}

// ================= load-balance loss
__global__ void k_lb(const float* __restrict__ gsum, float* __restrict__ out_lb) {
  int t = threadIdx.x;
  float term = 0.f;
  if (t < 16) {
    float D = gsum[t] * (1.f/4096.f);
    term = D * logf(D + 1e-8f);
  }
  #pragma unroll
  for (int o = 8; o > 0; o >>= 1) term += __shfl_down(term, o, 64);
  if (t == 0) *out_lb = term;
}

// ================= LayerNorm(moe + feat) in-place into moe
__global__ __launch_bounds__(256) void k_ln(const float* __restrict__ feat,
    float* __restrict__ moe, const float* __restrict__ g, const float* __restrict__ bp) {
  const int r = blockIdx.x, t = threadIdx.x;
  float v = moe[(size_t)r*256 + t] + feat[(size_t)r*256 + t];
  float s = v, q = v * v;
  #pragma unroll
  for (int o = 32; o > 0; o >>= 1) {
    s += __shfl_down(s, o, 64);
    q += __shfl_down(q, o, 64);
  }
  __shared__ float ss[4], qq[4];
  int wv = t >> 6;
  if ((t & 63) == 0) { ss[wv] = s; qq[wv] = q; }
  __syncthreads();
  float S = ss[0]+ss[1]+ss[2]+ss[3];
  float Q = qq[0]+qq[1]+qq[2]+qq[3];
  float mu  = S * (1.f/256.f);
  float var = Q * (1.f/256.f) - mu*mu;
  float inv = rsqrtf(var + 1e-5f);
  moe[(size_t)r*256 + t] = (v - mu) * inv * g[t] + bp[t];
}

// ================= output GEMM: [4096,256] @ [256,1000] + b
__global__ __launch_bounds__(256) void k_out(const float* __restrict__ y,
    const float* __restrict__ ow, const float* __restrict__ ob,
    float* __restrict__ out) {
  __shared__ float ys[32][256];
  const int t = threadIdx.x;
  const int r0 = blockIdx.x * 32;
  const int c = blockIdx.y * 256 + t;
  for (int i = t; i < 32*256; i += 256) {
    int r = i >> 8, k = i & 255;
    ys[r][k] = y[(size_t)(r0+r)*256 + k];
  }
  __syncthreads();
  if (c >= NCLS) return;
  float acc[32];
  {
    float bb = ob[c];
    #pragma unroll
    for (int r = 0; r < 32; ++r) acc[r] = bb;
  }
  #pragma unroll 4
  for (int k = 0; k < 256; ++k) {
    float wv = ow[(size_t)k*NCLS + c];
    #pragma unroll
    for (int r = 0; r < 32; ++r) acc[r] = fmaf(ys[r][k], wv, acc[r]);
  }
  for (int r = 0; r < 32; ++r) out[(size_t)(r0+r)*NCLS + c] = acc[r];
}

// ================= launch =================
extern "C" void kernel_launch(void* const* d_in, const int* in_sizes, int n_in,
                              void* d_out, int out_size, void* d_ws, size_t ws_size,
                              hipStream_t stream) {
  const float* x   = (const float*)d_in[0];
  const float* c1w = (const float*)d_in[1];
  const float* c1b = (const float*)d_in[2];
  const float* c2w = (const float*)d_in[3];
  const float* c2b = (const float*)d_in[4];
  const float* c3w = (const float*)d_in[5];
  const float* c3b = (const float*)d_in[6];
  const float* fcw = (const float*)d_in[7];
  const float* fcb = (const float*)d_in[8];
  const float* gw  = (const float*)d_in[9];
  const float* gb  = (const float*)d_in[10];
  const float* ew1 = (const float*)d_in[11];
  const float* eb1 = (const float*)d_in[12];
  const float* ew2 = (const float*)d_in[13];
  const float* eb2 = (const float*)d_in[14];
  const float* lng = (const float*)d_in[15];
  const float* lnb = (const float*)d_in[16];
  const float* ow  = (const float*)d_in[17];
  const float* ob  = (const float*)d_in[18];
  char* ws = (char*)d_ws;
  float* Bb   = (float*)(ws + OFF_B);
  float* P0   = (float*)(ws + OFF_P0);
  float* P1   = (float*)(ws + OFF_P1);
  float* C    = (float*)(ws + OFF_C);
  unsigned short* wBh = (unsigned short*)(ws + OFF_C);     // aliases C (C written after conv12)
  unsigned short* wBl = (unsigned short*)(ws + OFF_WBL);
  unsigned short* wAh = (unsigned short*)(ws + OFF_FEAT);  // aliases feat (written later)
  unsigned short* wAl = (unsigned short*)(ws + OFF_WAL);
  unsigned short* w1th = (unsigned short*)(ws + OFF_W1TH); // region dead after conv3
  unsigned short* w1tl = (unsigned short*)(ws + OFF_W1TL);
  unsigned short* w2th = (unsigned short*)(ws + OFF_W2TH);
  unsigned short* w2tl = (unsigned short*)(ws + OFF_W2TL);
  float* feat = (float*)(ws + OFF_FEAT);
  float* moe  = (float*)(ws + OFF_MOE);
  int*   cnt  = (int*)(ws + OFF_CNT);
  float* gsum = (float*)(ws + OFF_GSUM);
  int*   lrow = (int*)(ws + OFF_LROW);
  float* lgv  = (float*)(ws + OFF_LG);
  float* outp = (float*)d_out;

  hipMemsetAsync(ws + OFF_MOE, 0, 4194304 + 128, stream);

  hipLaunchKernelGGL(k_wt2b,   dim3(72),      dim3(256), 0, stream, c2w, wBh, wBl);
  hipLaunchKernelGGL(k_wt3b,   dim3(288),     dim3(256), 0, stream, c3w, wAh, wAl);
  hipLaunchKernelGGL(k_conv12, dim3(4096),    dim3(512), 0, stream, x, c1w, c1b, wBh, wBl, c2b, Bb);
  hipLaunchKernelGGL(k_conv3,  dim3(4096),    dim3(256), 0, stream, Bb, wAh, wAl, c3b, C);
  // Bb dead now -> build MoE packed/split weights in its region
  hipLaunchKernelGGL(k_pack,   dim3(16, 4, 16), dim3(256), 0, stream, ew1, w1th, w1tl, 256, 1024);
  hipLaunchKernelGGL(k_pack,   dim3(4, 16, 16), dim3(256), 0, stream, ew2, w2th, w2tl, 1024, 256);
  hipLaunchKernelGGL(k_fc,     dim3(64, 4, 2),dim3(256), 0, stream, C, fcw, P0, P1);
  hipLaunchKernelGGL(k_gate,   dim3(256),     dim3(256), 0, stream, P0, P1, fcb, gw, gb,
                     feat, cnt, gsum, lrow, lgv);
  hipLaunchKernelGGL(k_moe,    dim3(128, 16, 8), dim3(256), 0, stream, feat, w1th, w1tl, w2th, w2tl,
                     eb1, eb2, cnt, lrow, lgv, moe);
  hipLaunchKernelGGL(k_lb,     dim3(1),       dim3(64),  0, stream, gsum, outp + (size_t)NB*NCLS);
  hipLaunchKernelGGL(k_ln,     dim3(4096),    dim3(256), 0, stream, feat, moe, lng, lnb);
  hipLaunchKernelGGL(k_out,    dim3(128, 4),  dim3(256), 0, stream, moe, ow, ob, outp);
}